// Round 9
// baseline (870.266 us; speedup 1.0000x reference)
//
#include <hip/hip_runtime.h>
#include <hip/hip_bf16.h>

// TriangleMultiplication (outgoing), N=512, C=C_Z=128. Inputs/out fp32
// (runtime-detected; bf16 fallback kept). Internal: bf16 MFMA with hi/lo
// splitting for precision. Tiers by ws_size:
//  A (>=256.5Mi): A hi/lo + B hi/lo + T fp32 + split stage3
//  B (>=192.5Mi): A single + B hi/lo + T fp32 + split stage3
//  C (>=128.25Mi): bf16 T, proven-safe layout
//  else: zero-fill diagnostic.
//
// R1: weights read direct from global (L2-hot) in stage1/stage3ab.
// R2 FAILED (absmax 0.24): LN restructure was the culprit (isolated by R5).
// R5: occupancy-only changes PASS 867.7us (stage1 306us, occ 42%).
// R6 FAILED (1003us): stage1 group-fusion spilled av[64] VGPRs to scratch.
// R7: stage2 XCD swizzle = NULL (kept, harmless).
// R8: stage2 K-tile 32, 3 blk/CU: +10us (857.2).
// R9: T layout [c][p] -> [i][c][j] (idx = (i*128+c)*512+j). stage3ab's T read
//     becomes one contiguous 256KB region per block (was 128x 1MB-strided
//     streams). Pure index bijection: stage2-store + stage3ab/stage3c-read
//     changed consistently; values bit-identical.

#define NSEQ 512
#define NPOS 262144

typedef short bf16x8 __attribute__((ext_vector_type(8)));
typedef float f32x4 __attribute__((ext_vector_type(4)));

__device__ __forceinline__ float bf2f(ushort h) {
    union { uint u; float f; } x; x.u = ((uint)h) << 16; return x.f;
}
__device__ __forceinline__ ushort f2bf(float f) {
    union { float f; uint u; } x; x.f = f;
    uint r = x.u + 0x7fffu + ((x.u >> 16) & 1u);
    return (ushort)(r >> 16);
}
__device__ __forceinline__ float sigm(float x) { return 1.f / (1.f + __expf(-x)); }

__device__ __forceinline__ float loadIn(const void* p, size_t idx, int isbf) {
    return isbf ? bf2f(((const ushort*)p)[idx]) : ((const float*)p)[idx];
}
__device__ __forceinline__ float2 loadIn2(const void* p, size_t base, int col2, int isbf) {
    if (isbf) {
        uint zz = *(const uint*)((const ushort*)p + base + col2);
        float2 r; r.x = bf2f((ushort)(zz & 0xffff)); r.y = bf2f((ushort)(zz >> 16)); return r;
    }
    return *(const float2*)((const float*)p + base + col2);
}

// ---------------------------------------------------------------------------
__global__ void detect_kernel(const uint* __restrict__ z32, int* __restrict__ flag)
{
    int t = threadIdx.x;
    int votes = 0;
    #pragma unroll
    for (int i = 0; i < 4; ++i) {
        uint wv = z32[t * 4 + i];
        uint ex = (wv >> 7) & 0xff;
        votes += (ex >= 118 && ex <= 132) ? 1 : 0;
    }
    #pragma unroll
    for (int m = 32; m >= 1; m >>= 1) votes += __shfl_xor(votes, m);
    if (t == 0) flag[0] = (votes >= 128) ? 1 : 0;
}

__global__ void fill_zero_kernel(ushort* __restrict__ out)
{
    size_t i = ((size_t)blockIdx.x * 256 + threadIdx.x) * 16;
    uint4 z4 = {0u, 0u, 0u, 0u};
    *(uint4*)(out + i) = z4;
    *(uint4*)(out + i + 8) = z4;
}

// ---------------------------------------------------------------------------
// prep: wt5_h/_l[g][co][ci] (transposed, hi/lo bf16); wzt_h/_l[co][c] of
// W' = ln_ow*w_z; u,v fp32 affine-fold vectors.
// ---------------------------------------------------------------------------
__global__ void prep_kernel(const void* __restrict__ w_ap, const void* __restrict__ w_ag,
                            const void* __restrict__ w_bp, const void* __restrict__ w_bg,
                            const void* __restrict__ w_g,  const void* __restrict__ w_z,
                            const void* __restrict__ ln_ow, const void* __restrict__ ln_ob,
                            const void* __restrict__ b_z,  const int* __restrict__ dflag,
                            ushort* __restrict__ wt5_h, ushort* __restrict__ wt5_l,
                            ushort* __restrict__ wzt_h, ushort* __restrict__ wzt_l,
                            float* __restrict__ u, float* __restrict__ v, int store_lo)
{
    const int b = blockIdx.x, t = threadIdx.x;
    const int isbf = dflag[0];
    if (b < 5) {
        const void* src = (b == 0) ? w_ap : (b == 1) ? w_ag : (b == 2) ? w_bp : (b == 3) ? w_bg : w_g;
        for (int k = 0; k < 64; ++k) {
            int o = t + k * 256;
            int co = o >> 7, ci = o & 127;
            float wv = loadIn(src, ci * 128 + co, isbf);
            ushort hi = f2bf(wv);
            wt5_h[b * 16384 + o] = hi;
            if (store_lo) wt5_l[b * 16384 + o] = f2bf(wv - bf2f(hi));
        }
    } else if (b == 5) {
        for (int k = 0; k < 64; ++k) {
            int o = t + k * 256;
            int co = o >> 7, c = o & 127;
            float wv = loadIn(ln_ow, c, isbf) * loadIn(w_z, c * 128 + co, isbf);
            ushort hi = f2bf(wv);
            wzt_h[o] = hi;
            if (store_lo) wzt_l[o] = f2bf(wv - bf2f(hi));
        }
    } else {
        if (t < 128) {
            float su = 0.f, sv = 0.f;
            for (int c = 0; c < 128; ++c) {
                float wzv = loadIn(w_z, c * 128 + t, isbf);
                su += loadIn(ln_ow, c, isbf) * wzv;
                sv += loadIn(ln_ob, c, isbf) * wzv;
            }
            u[t] = su;
            v[t] = sv + loadIn(b_z, t, isbf);
        }
    }
}

// ---------------------------------------------------------------------------
// stage1: grid (4096, 2). grp0 -> a (A_hi[/A_lo]), grp1 -> b (B_hi,B_lo in d_out).
// zn kept as hi+lo bf16 in LDS; gate+proj GEMMs fused (shared A-fragment reads),
// weight fragments read directly from global (L2-hot, layout matches).
// tb (output transpose buf) aliases zn LDS after the K-loop (barrier-guarded).
// Outputs channel-major [c][p].
// ---------------------------------------------------------------------------
__global__ __launch_bounds__(256, 4)
void stage1_kernel(const void* __restrict__ z,
                   const void* __restrict__ ln_iw, const void* __restrict__ ln_ib,
                   const ushort* __restrict__ wt5_h,
                   const void* __restrict__ b_ap, const void* __restrict__ b_ag,
                   const void* __restrict__ b_bp, const void* __restrict__ b_bg,
                   const int* __restrict__ dflag,
                   ushort* __restrict__ Ahi, ushort* __restrict__ Alo,
                   ushort* __restrict__ Bhi, int walo)
{
    __shared__ ushort sm[2 * 64 * 136];
    ushort* lAh = sm;                    // [64][136] zn hi
    ushort* lAl = sm + 64 * 136;         // [64][136] zn lo
    const int tid = threadIdx.x, lane = tid & 63, w = tid >> 6;
    const int l15 = lane & 15, quad = lane >> 4;
    const int grp = blockIdx.y;
    const int p0 = blockIdx.x * 64;
    const int isbf = dflag[0];

    float lw0 = loadIn(ln_iw, 2 * lane, isbf), lw1 = loadIn(ln_iw, 2 * lane + 1, isbf);
    float lb0 = loadIn(ln_ib, 2 * lane, isbf), lb1 = loadIn(ln_ib, 2 * lane + 1, isbf);
    for (int it = 0; it < 16; ++it) {
        int pl = w * 16 + it;
        float2 xv = loadIn2(z, (size_t)(p0 + pl) * 128, 2 * lane, isbf);
        float x0 = xv.x, x1 = xv.y;
        float s = x0 + x1, s2 = x0 * x0 + x1 * x1;
        #pragma unroll
        for (int m = 32; m >= 1; m >>= 1) { s += __shfl_xor(s, m); s2 += __shfl_xor(s2, m); }
        float mean = s * 0.0078125f;
        float var = s2 * 0.0078125f - mean * mean;
        float rs = rsqrtf(var + 1e-5f);
        float zn0 = (x0 - mean) * rs * lw0 + lb0;
        float zn1 = (x1 - mean) * rs * lw1 + lb1;
        ushort h0 = f2bf(zn0), h1 = f2bf(zn1);
        ushort o0 = f2bf(zn0 - bf2f(h0)), o1 = f2bf(zn1 - bf2f(h1));
        *(uint*)(lAh + pl * 136 + 2 * lane) = (uint)h0 | ((uint)h1 << 16);
        *(uint*)(lAl + pl * 136 + 2 * lane) = (uint)o0 | ((uint)o1 << 16);
    }
    __syncthreads();

    const ushort* wG = wt5_h + ((grp == 0) ? 1 : 3) * 16384;
    const ushort* wP = wt5_h + ((grp == 0) ? 0 : 2) * 16384;

    const int wm = w >> 1, wn = w & 1;
    const f32x4 zero4 = {0.f, 0.f, 0.f, 0.f};
    f32x4 accG[2][4], accP[2][4];
    #pragma unroll
    for (int i = 0; i < 2; ++i)
        #pragma unroll
        for (int j = 0; j < 4; ++j) { accG[i][j] = zero4; accP[i][j] = zero4; }

    #pragma unroll
    for (int ks = 0; ks < 4; ++ks) {
        bf16x8 afh[2], afl[2];
        #pragma unroll
        for (int i = 0; i < 2; ++i) {
            afh[i] = *(const bf16x8*)(lAh + (wm * 32 + i * 16 + l15) * 136 + ks * 32 + quad * 8);
            afl[i] = *(const bf16x8*)(lAl + (wm * 32 + i * 16 + l15) * 136 + ks * 32 + quad * 8);
        }
        {
            bf16x8 bG[4];
            #pragma unroll
            for (int j = 0; j < 4; ++j)
                bG[j] = *(const bf16x8*)(wG + (wn * 64 + j * 16 + l15) * 128 + ks * 32 + quad * 8);
            #pragma unroll
            for (int i = 0; i < 2; ++i)
                #pragma unroll
                for (int j = 0; j < 4; ++j) {
                    accG[i][j] = __builtin_amdgcn_mfma_f32_16x16x32_bf16(afh[i], bG[j], accG[i][j], 0, 0, 0);
                    accG[i][j] = __builtin_amdgcn_mfma_f32_16x16x32_bf16(afl[i], bG[j], accG[i][j], 0, 0, 0);
                }
        }
        {
            bf16x8 bP[4];
            #pragma unroll
            for (int j = 0; j < 4; ++j)
                bP[j] = *(const bf16x8*)(wP + (wn * 64 + j * 16 + l15) * 128 + ks * 32 + quad * 8);
            #pragma unroll
            for (int i = 0; i < 2; ++i)
                #pragma unroll
                for (int j = 0; j < 4; ++j) {
                    accP[i][j] = __builtin_amdgcn_mfma_f32_16x16x32_bf16(afh[i], bP[j], accP[i][j], 0, 0, 0);
                    accP[i][j] = __builtin_amdgcn_mfma_f32_16x16x32_bf16(afl[i], bP[j], accP[i][j], 0, 0, 0);
                }
        }
    }

    const void* bgp = (grp == 0) ? b_ag : b_bg;
    const void* bpp = (grp == 0) ? b_ap : b_bp;
    float av[2][4][4];
    #pragma unroll
    for (int i = 0; i < 2; ++i)
        #pragma unroll
        for (int j = 0; j < 4; ++j) {
            int co = wn * 64 + j * 16 + l15;
            float gv = loadIn(bgp, co, isbf);
            float pv = loadIn(bpp, co, isbf);
            #pragma unroll
            for (int r = 0; r < 4; ++r)
                av[i][j][r] = sigm(accG[i][j][r] + gv) * (accP[i][j][r] + pv);
        }

    ushort* dst_hi = (grp == 0) ? Ahi : Bhi;
    ushort* dst_lo = (grp == 0) ? Alo : (Bhi + 33554432);
    int do_lo = (grp == 0) ? walo : (!isbf);

    // tb aliases sm: all MFMA ds_reads are drained by this barrier
    __syncthreads();
    ushort* tb = sm;   // [128][72]
    #pragma unroll
    for (int i = 0; i < 2; ++i)
        #pragma unroll
        for (int j = 0; j < 4; ++j) {
            int co = wn * 64 + j * 16 + l15;
            int pb = wm * 32 + i * 16 + quad * 4;
            uint2 pk;
            pk.x = (uint)f2bf(av[i][j][0]) | ((uint)f2bf(av[i][j][1]) << 16);
            pk.y = (uint)f2bf(av[i][j][2]) | ((uint)f2bf(av[i][j][3]) << 16);
            *(uint2*)(tb + co * 72 + pb) = pk;
        }
    __syncthreads();
    #pragma unroll
    for (int q = 0; q < 4; ++q) {
        int vv = q * 256 + tid;
        int co = vv >> 3, off = vv & 7;
        *(uint4*)(dst_hi + (size_t)co * NPOS + p0 + off * 8) = *(const uint4*)(tb + co * 72 + off * 8);
    }
    if (do_lo) {
        __syncthreads();
        #pragma unroll
        for (int i = 0; i < 2; ++i)
            #pragma unroll
            for (int j = 0; j < 4; ++j) {
                int co = wn * 64 + j * 16 + l15;
                int pb = wm * 32 + i * 16 + quad * 4;
                ushort lo0 = f2bf(av[i][j][0] - bf2f(f2bf(av[i][j][0])));
                ushort lo1 = f2bf(av[i][j][1] - bf2f(f2bf(av[i][j][1])));
                ushort lo2 = f2bf(av[i][j][2] - bf2f(f2bf(av[i][j][2])));
                ushort lo3 = f2bf(av[i][j][3] - bf2f(f2bf(av[i][j][3])));
                uint2 pk;
                pk.x = (uint)lo0 | ((uint)lo1 << 16);
                pk.y = (uint)lo2 | ((uint)lo3 << 16);
                *(uint2*)(tb + co * 72 + pb) = pk;
            }
        __syncthreads();
        #pragma unroll
        for (int q = 0; q < 4; ++q) {
            int vv = q * 256 + tid;
            int co = vv >> 3, off = vv & 7;
            *(uint4*)(dst_lo + (size_t)co * NPOS + p0 + off * 8) = *(const uint4*)(tb + co * 72 + off * 8);
        }
    }
}

// ---------------------------------------------------------------------------
// stage2: grid (16, 128). T_c = A_c * B_c^T. Terms: Ah*Bh [+ Ah*Bl] [+ Al*Bh].
// T written fp32 (tfp32) or bf16 in [i][c][j] layout: idx = (i*128+c)*512+j.
// R7: XCD swizzle (null, kept). R8: K-tile 32, 3 blk/CU.
// ---------------------------------------------------------------------------
__global__ __launch_bounds__(256, 3)
void stage2_kernel(const ushort* __restrict__ Ahi, const ushort* __restrict__ Alo,
                   const ushort* __restrict__ Bhi, const int* __restrict__ dflag,
                   void* __restrict__ Tbuf, int alo, int tfp32)
{
    __shared__ ushort sm[4 * 128 * 40];   // 40960 B
    ushort* lAh = sm;
    ushort* lAl = sm + 128 * 40;
    ushort* lBh = sm + 2 * 128 * 40;
    ushort* lBl = sm + 3 * 128 * 40;
    const int tid = threadIdx.x, lane = tid & 63, w = tid >> 6;
    const int l15 = lane & 15, quad = lane >> 4;
    const int wm = w >> 1, wn = w & 1;
    const int bid = blockIdx.y * 16 + blockIdx.x;          // 0..2047
    const int swz = (bid & 7) * 256 + (bid >> 3);          // bijective
    const int c = swz >> 4;
    const int ti = (swz & 15) >> 2, tj = swz & 3;
    const int blo = !dflag[0];
    const ushort* Blo = Bhi + 33554432;
    const ushort* Aph = Ahi + (size_t)c * NPOS + (size_t)ti * 128 * NSEQ;
    const ushort* Apl = Alo + (size_t)c * NPOS + (size_t)ti * 128 * NSEQ;
    const ushort* Bph = Bhi + (size_t)c * NPOS + (size_t)tj * 128 * NSEQ;
    const ushort* Bpl = Blo + (size_t)c * NPOS + (size_t)tj * 128 * NSEQ;

    const f32x4 zero4 = {0.f, 0.f, 0.f, 0.f};
    f32x4 acc[4][4];
    #pragma unroll
    for (int i = 0; i < 4; ++i)
        #pragma unroll
        for (int j = 0; j < 4; ++j) acc[i][j] = zero4;

    for (int kt = 0; kt < 16; ++kt) {
        // stage [128][32] ushorts per tile = 512 uint4; 2 per thread
        #pragma unroll
        for (int q = 0; q < 2; ++q) {
            int vv = q * 256 + tid;
            int row = vv >> 2, off = vv & 3;
            *(uint4*)(lAh + row * 40 + off * 8) = *(const uint4*)(Aph + (size_t)row * NSEQ + kt * 32 + off * 8);
            *(uint4*)(lBh + row * 40 + off * 8) = *(const uint4*)(Bph + (size_t)row * NSEQ + kt * 32 + off * 8);
        }
        if (alo) {
            #pragma unroll
            for (int q = 0; q < 2; ++q) {
                int vv = q * 256 + tid;
                int row = vv >> 2, off = vv & 3;
                *(uint4*)(lAl + row * 40 + off * 8) = *(const uint4*)(Apl + (size_t)row * NSEQ + kt * 32 + off * 8);
            }
        }
        if (blo) {
            #pragma unroll
            for (int q = 0; q < 2; ++q) {
                int vv = q * 256 + tid;
                int row = vv >> 2, off = vv & 3;
                *(uint4*)(lBl + row * 40 + off * 8) = *(const uint4*)(Bpl + (size_t)row * NSEQ + kt * 32 + off * 8);
            }
        }
        __syncthreads();
        {
            bf16x8 afh[4], bfh[4];
            #pragma unroll
            for (int i = 0; i < 4; ++i)
                afh[i] = *(const bf16x8*)(lAh + (wm * 64 + i * 16 + l15) * 40 + quad * 8);
            #pragma unroll
            for (int j = 0; j < 4; ++j)
                bfh[j] = *(const bf16x8*)(lBh + (wn * 64 + j * 16 + l15) * 40 + quad * 8);
            #pragma unroll
            for (int i = 0; i < 4; ++i)
                #pragma unroll
                for (int j = 0; j < 4; ++j)
                    acc[i][j] = __builtin_amdgcn_mfma_f32_16x16x32_bf16(afh[i], bfh[j], acc[i][j], 0, 0, 0);
            if (blo) {
                bf16x8 bfl[4];
                #pragma unroll
                for (int j = 0; j < 4; ++j)
                    bfl[j] = *(const bf16x8*)(lBl + (wn * 64 + j * 16 + l15) * 40 + quad * 8);
                #pragma unroll
                for (int i = 0; i < 4; ++i)
                    #pragma unroll
                    for (int j = 0; j < 4; ++j)
                        acc[i][j] = __builtin_amdgcn_mfma_f32_16x16x32_bf16(afh[i], bfl[j], acc[i][j], 0, 0, 0);
            }
            if (alo) {
                bf16x8 afl[4];
                #pragma unroll
                for (int i = 0; i < 4; ++i)
                    afl[i] = *(const bf16x8*)(lAl + (wm * 64 + i * 16 + l15) * 40 + quad * 8);
                #pragma unroll
                for (int i = 0; i < 4; ++i)
                    #pragma unroll
                    for (int j = 0; j < 4; ++j)
                        acc[i][j] = __builtin_amdgcn_mfma_f32_16x16x32_bf16(afl[i], bfh[j], acc[i][j], 0, 0, 0);
            }
        }
        __syncthreads();
    }

    // [i][c][j] layout: idx = ((i)*128 + c)*512 + j, i = ti*128+ib+r, j = tj*128+jl
    if (tfp32) {
        float* Tp = (float*)Tbuf + ((size_t)(ti * 128) * 128 + c) * 512 + tj * 128;
        #pragma unroll
        for (int i = 0; i < 4; ++i)
            #pragma unroll
            for (int j = 0; j < 4; ++j) {
                int jl = wn * 64 + j * 16 + l15;
                int ib = wm * 64 + i * 16 + quad * 4;
                #pragma unroll
                for (int r = 0; r < 4; ++r)
                    Tp[(size_t)(ib + r) * 65536 + jl] = acc[i][j][r];
            }
    } else {
        ushort* Tp = (ushort*)Tbuf + ((size_t)(ti * 128) * 128 + c) * 512 + tj * 128;
        #pragma unroll
        for (int i = 0; i < 4; ++i)
            #pragma unroll
            for (int j = 0; j < 4; ++j) {
                int jl = wn * 64 + j * 16 + l15;
                int ib = wm * 64 + i * 16 + quad * 4;
                #pragma unroll
                for (int r = 0; r < 4; ++r)
                    Tp[(size_t)(ib + r) * 65536 + jl] = f2bf(acc[i][j][r]);
            }
    }
}

// ---------------------------------------------------------------------------
// stage3AB: fp32 T ([i][c][j] layout). Gate 3-term; LN stats from hi+lo t;
// output GEMM 3-term. Weights from global; LDS only for zn/T hi+lo.
// ---------------------------------------------------------------------------
__global__ __launch_bounds__(256, 4)
void stage3ab_kernel(const void* __restrict__ z,
                     const void* __restrict__ ln_iw, const void* __restrict__ ln_ib,
                     const ushort* __restrict__ wt5_h, const ushort* __restrict__ wt5_l,
                     const void* __restrict__ b_g,
                     const float* __restrict__ Tf, const ushort* __restrict__ wzt_h,
                     const ushort* __restrict__ wzt_l,
                     const float* __restrict__ uvec, const float* __restrict__ vvec,
                     const int* __restrict__ dflag, void* __restrict__ out)
{
    __shared__ ushort sm[2 * 64 * 136];
    __shared__ float sMean[64], sRs[64];
    ushort* lAh = sm;
    ushort* lAl = sm + 64 * 136;
    const int tid = threadIdx.x, lane = tid & 63, w = tid >> 6;
    const int l15 = lane & 15, quad = lane >> 4;
    const int wm = w >> 1, wn = w & 1;
    const int p0 = blockIdx.x * 64;
    const int isbf = dflag[0];
    const f32x4 zero4 = {0.f, 0.f, 0.f, 0.f};

    // phase A: zn hi/lo
    float lw0 = loadIn(ln_iw, 2 * lane, isbf), lw1 = loadIn(ln_iw, 2 * lane + 1, isbf);
    float lb0 = loadIn(ln_ib, 2 * lane, isbf), lb1 = loadIn(ln_ib, 2 * lane + 1, isbf);
    for (int it = 0; it < 16; ++it) {
        int pl = w * 16 + it;
        float2 xv = loadIn2(z, (size_t)(p0 + pl) * 128, 2 * lane, isbf);
        float x0 = xv.x, x1 = xv.y;
        float s = x0 + x1, s2 = x0 * x0 + x1 * x1;
        #pragma unroll
        for (int m = 32; m >= 1; m >>= 1) { s += __shfl_xor(s, m); s2 += __shfl_xor(s2, m); }
        float mean = s * 0.0078125f;
        float var = s2 * 0.0078125f - mean * mean;
        float rs = rsqrtf(var + 1e-5f);
        float zn0 = (x0 - mean) * rs * lw0 + lb0;
        float zn1 = (x1 - mean) * rs * lw1 + lb1;
        ushort h0 = f2bf(zn0), h1 = f2bf(zn1);
        ushort o0 = f2bf(zn0 - bf2f(h0)), o1 = f2bf(zn1 - bf2f(h1));
        *(uint*)(lAh + pl * 136 + 2 * lane) = (uint)h0 | ((uint)h1 << 16);
        *(uint*)(lAl + pl * 136 + 2 * lane) = (uint)o0 | ((uint)o1 << 16);
    }
    __syncthreads();

    // gate GEMM, weights from global
    const ushort* wgh = wt5_h + 4 * 16384;
    const ushort* wgl = wt5_l + 4 * 16384;
    f32x4 accG[2][4];
    #pragma unroll
    for (int i = 0; i < 2; ++i)
        #pragma unroll
        for (int j = 0; j < 4; ++j) accG[i][j] = zero4;
    #pragma unroll
    for (int ks = 0; ks < 4; ++ks) {
        bf16x8 afh[2], afl[2], bh[4], bl[4];
        #pragma unroll
        for (int i = 0; i < 2; ++i) {
            afh[i] = *(const bf16x8*)(lAh + (wm * 32 + i * 16 + l15) * 136 + ks * 32 + quad * 8);
            afl[i] = *(const bf16x8*)(lAl + (wm * 32 + i * 16 + l15) * 136 + ks * 32 + quad * 8);
        }
        #pragma unroll
        for (int j = 0; j < 4; ++j) {
            bh[j] = *(const bf16x8*)(wgh + (wn * 64 + j * 16 + l15) * 128 + ks * 32 + quad * 8);
            bl[j] = *(const bf16x8*)(wgl + (wn * 64 + j * 16 + l15) * 128 + ks * 32 + quad * 8);
        }
        #pragma unroll
        for (int i = 0; i < 2; ++i)
            #pragma unroll
            for (int j = 0; j < 4; ++j) {
                accG[i][j] = __builtin_amdgcn_mfma_f32_16x16x32_bf16(afh[i], bh[j], accG[i][j], 0, 0, 0);
                accG[i][j] = __builtin_amdgcn_mfma_f32_16x16x32_bf16(afl[i], bh[j], accG[i][j], 0, 0, 0);
                accG[i][j] = __builtin_amdgcn_mfma_f32_16x16x32_bf16(afh[i], bl[j], accG[i][j], 0, 0, 0);
            }
    }
    #pragma unroll
    for (int i = 0; i < 2; ++i)
        #pragma unroll
        for (int j = 0; j < 4; ++j) {
            int co = wn * 64 + j * 16 + l15;
            float bgv = loadIn(b_g, co, isbf);
            #pragma unroll
            for (int r = 0; r < 4; ++r)
                accG[i][j][r] = sigm(accG[i][j][r] + bgv);
        }
    __syncthreads();

    // phase B: fp32 T ([i][c][j]) -> hi/lo LDS
    {
        int c = tid >> 1, h = tid & 1;
        const float* src = Tf + ((size_t)(p0 >> 9) * 128 + c) * 512 + (p0 & 511) + h * 32;
        float tv[32];
        #pragma unroll
        for (int q8 = 0; q8 < 8; ++q8) {
            float4 f4 = ((const float4*)src)[q8];
            tv[q8 * 4 + 0] = f4.x; tv[q8 * 4 + 1] = f4.y;
            tv[q8 * 4 + 2] = f4.z; tv[q8 * 4 + 3] = f4.w;
        }
        #pragma unroll
        for (int jj = 0; jj < 32; ++jj) {
            ushort hi = f2bf(tv[jj]);
            lAh[(h * 32 + jj) * 136 + c] = hi;
            lAl[(h * 32 + jj) * 136 + c] = f2bf(tv[jj] - bf2f(hi));
        }
    }
    __syncthreads();

    for (int it = 0; it < 16; ++it) {
        int pl = w * 16 + it;
        uint zh = *(const uint*)(lAh + pl * 136 + 2 * lane);
        uint zl = *(const uint*)(lAl + pl * 136 + 2 * lane);
        float x0 = bf2f((ushort)(zh & 0xffff)) + bf2f((ushort)(zl & 0xffff));
        float x1 = bf2f((ushort)(zh >> 16)) + bf2f((ushort)(zl >> 16));
        float s = x0 + x1, s2 = x0 * x0 + x1 * x1;
        #pragma unroll
        for (int m = 32; m >= 1; m >>= 1) { s += __shfl_xor(s, m); s2 += __shfl_xor(s2, m); }
        if (lane == 0) {
            float mean = s * 0.0078125f;
            float var = s2 * 0.0078125f - mean * mean;
            sMean[pl] = mean;
            sRs[pl] = rsqrtf(var + 1e-5f);
        }
    }
    __syncthreads();

    // output GEMM, W' from global
    f32x4 acc[2][4];
    #pragma unroll
    for (int i = 0; i < 2; ++i)
        #pragma unroll
        for (int j = 0; j < 4; ++j) acc[i][j] = zero4;
    #pragma unroll
    for (int ks = 0; ks < 4; ++ks) {
        bf16x8 afh[2], afl[2], bh[4], bl[4];
        #pragma unroll
        for (int i = 0; i < 2; ++i) {
            afh[i] = *(const bf16x8*)(lAh + (wm * 32 + i * 16 + l15) * 136 + ks * 32 + quad * 8);
            afl[i] = *(const bf16x8*)(lAl + (wm * 32 + i * 16 + l15) * 136 + ks * 32 + quad * 8);
        }
        #pragma unroll
        for (int j = 0; j < 4; ++j) {
            bh[j] = *(const bf16x8*)(wzt_h + (wn * 64 + j * 16 + l15) * 128 + ks * 32 + quad * 8);
            bl[j] = *(const bf16x8*)(wzt_l + (wn * 64 + j * 16 + l15) * 128 + ks * 32 + quad * 8);
        }
        #pragma unroll
        for (int i = 0; i < 2; ++i)
            #pragma unroll
            for (int j = 0; j < 4; ++j) {
                acc[i][j] = __builtin_amdgcn_mfma_f32_16x16x32_bf16(afh[i], bh[j], acc[i][j], 0, 0, 0);
                acc[i][j] = __builtin_amdgcn_mfma_f32_16x16x32_bf16(afl[i], bh[j], acc[i][j], 0, 0, 0);
                acc[i][j] = __builtin_amdgcn_mfma_f32_16x16x32_bf16(afh[i], bl[j], acc[i][j], 0, 0, 0);
            }
    }

    ushort* outb = (ushort*)out;
    float*  outf = (float*)out;
    #pragma unroll
    for (int i = 0; i < 2; ++i)
        #pragma unroll
        for (int j = 0; j < 4; ++j) {
            int co = wn * 64 + j * 16 + l15;
            float uj = uvec[co], vj = vvec[co];
            int pb = wm * 32 + i * 16 + quad * 4;
            #pragma unroll
            for (int r = 0; r < 4; ++r) {
                int p = pb + r;
                float pre = sRs[p] * (acc[i][j][r] - sMean[p] * uj) + vj;
                float val = accG[i][j][r] * pre;
                size_t oidx = (size_t)(p0 + p) * 128 + co;
                if (isbf) outb[oidx] = f2bf(val);
                else      outf[oidx] = val;
            }
        }
}

// ---------------------------------------------------------------------------
// stage3C: bf16 T fallback ([i][c][j] layout). Gate 2-term zn split.
// ---------------------------------------------------------------------------
__global__ __launch_bounds__(256, 2)
void stage3c_kernel(const void* __restrict__ z,
                    const void* __restrict__ ln_iw, const void* __restrict__ ln_ib,
                    const ushort* __restrict__ wt5_h, const void* __restrict__ b_g,
                    const ushort* __restrict__ Tb, const ushort* __restrict__ wzt_h,
                    const float* __restrict__ uvec, const float* __restrict__ vvec,
                    const int* __restrict__ dflag, void* __restrict__ out)
{
    __shared__ ushort sm[2 * 64 * 136 + 128 * 136];
    __shared__ float sMean[64], sRs[64];
    ushort* lAh = sm;
    ushort* lAl = sm + 64 * 136;
    ushort* lB  = sm + 2 * 64 * 136;
    const int tid = threadIdx.x, lane = tid & 63, w = tid >> 6;
    const int l15 = lane & 15, quad = lane >> 4;
    const int wm = w >> 1, wn = w & 1;
    const int p0 = blockIdx.x * 64;
    const int isbf = dflag[0];
    const f32x4 zero4 = {0.f, 0.f, 0.f, 0.f};

    float lw0 = loadIn(ln_iw, 2 * lane, isbf), lw1 = loadIn(ln_iw, 2 * lane + 1, isbf);
    float lb0 = loadIn(ln_ib, 2 * lane, isbf), lb1 = loadIn(ln_ib, 2 * lane + 1, isbf);
    for (int it = 0; it < 16; ++it) {
        int pl = w * 16 + it;
        float2 xv = loadIn2(z, (size_t)(p0 + pl) * 128, 2 * lane, isbf);
        float x0 = xv.x, x1 = xv.y;
        float s = x0 + x1, s2 = x0 * x0 + x1 * x1;
        #pragma unroll
        for (int m = 32; m >= 1; m >>= 1) { s += __shfl_xor(s, m); s2 += __shfl_xor(s2, m); }
        float mean = s * 0.0078125f;
        float var = s2 * 0.0078125f - mean * mean;
        float rs = rsqrtf(var + 1e-5f);
        float zn0 = (x0 - mean) * rs * lw0 + lb0;
        float zn1 = (x1 - mean) * rs * lw1 + lb1;
        ushort h0 = f2bf(zn0), h1 = f2bf(zn1);
        ushort o0 = f2bf(zn0 - bf2f(h0)), o1 = f2bf(zn1 - bf2f(h1));
        *(uint*)(lAh + pl * 136 + 2 * lane) = (uint)h0 | ((uint)h1 << 16);
        *(uint*)(lAl + pl * 136 + 2 * lane) = (uint)o0 | ((uint)o1 << 16);
    }
    {
        const ushort* src = wt5_h + 4 * 16384;
        #pragma unroll
        for (int q = 0; q < 8; ++q) {
            int vv = q * 256 + tid;
            int co = vv >> 4, off = vv & 15;
            *(uint4*)(lB + co * 136 + off * 8) = *(const uint4*)(src + co * 128 + off * 8);
        }
    }
    __syncthreads();

    f32x4 accG[2][4];
    #pragma unroll
    for (int i = 0; i < 2; ++i)
        #pragma unroll
        for (int j = 0; j < 4; ++j) accG[i][j] = zero4;
    #pragma unroll
    for (int ks = 0; ks < 4; ++ks) {
        bf16x8 afh[2], afl[2], bfr[4];
        #pragma unroll
        for (int i = 0; i < 2; ++i) {
            afh[i] = *(const bf16x8*)(lAh + (wm * 32 + i * 16 + l15) * 136 + ks * 32 + quad * 8);
            afl[i] = *(const bf16x8*)(lAl + (wm * 32 + i * 16 + l15) * 136 + ks * 32 + quad * 8);
        }
        #pragma unroll
        for (int j = 0; j < 4; ++j)
            bfr[j] = *(const bf16x8*)(lB + (wn * 64 + j * 16 + l15) * 136 + ks * 32 + quad * 8);
        #pragma unroll
        for (int i = 0; i < 2; ++i)
            #pragma unroll
            for (int j = 0; j < 4; ++j) {
                accG[i][j] = __builtin_amdgcn_mfma_f32_16x16x32_bf16(afh[i], bfr[j], accG[i][j], 0, 0, 0);
                accG[i][j] = __builtin_amdgcn_mfma_f32_16x16x32_bf16(afl[i], bfr[j], accG[i][j], 0, 0, 0);
            }
    }
    #pragma unroll
    for (int i = 0; i < 2; ++i)
        #pragma unroll
        for (int j = 0; j < 4; ++j) {
            int co = wn * 64 + j * 16 + l15;
            float bgv = loadIn(b_g, co, isbf);
            #pragma unroll
            for (int r = 0; r < 4; ++r)
                accG[i][j][r] = sigm(accG[i][j][r] + bgv);
        }
    __syncthreads();

    {
        int c = tid >> 1, h = tid & 1;
        const ushort* src = Tb + ((size_t)(p0 >> 9) * 128 + c) * 512 + (p0 & 511) + h * 32;
        union { uint4 q[4]; ushort u[32]; } tmp;
        tmp.q[0] = ((const uint4*)src)[0];
        tmp.q[1] = ((const uint4*)src)[1];
        tmp.q[2] = ((const uint4*)src)[2];
        tmp.q[3] = ((const uint4*)src)[3];
        #pragma unroll
        for (int jj = 0; jj < 32; ++jj)
            lAh[(h * 32 + jj) * 136 + c] = tmp.u[jj];
    }
    #pragma unroll
    for (int q = 0; q < 8; ++q) {
        int vv = q * 256 + tid;
        int co = vv >> 4, off = vv & 15;
        *(uint4*)(lB + co * 136 + off * 8) = *(const uint4*)(wzt_h + co * 128 + off * 8);
    }
    __syncthreads();

    for (int it = 0; it < 16; ++it) {
        int pl = w * 16 + it;
        uint zz = *(const uint*)(lAh + pl * 136 + 2 * lane);
        float x0 = bf2f((ushort)(zz & 0xffff)), x1 = bf2f((ushort)(zz >> 16));
        float s = x0 + x1, s2 = x0 * x0 + x1 * x1;
        #pragma unroll
        for (int m = 32; m >= 1; m >>= 1) { s += __shfl_xor(s, m); s2 += __shfl_xor(s2, m); }
        if (lane == 0) {
            float mean = s * 0.0078125f;
            float var = s2 * 0.0078125f - mean * mean;
            sMean[pl] = mean;
            sRs[pl] = rsqrtf(var + 1e-5f);
        }
    }
    __syncthreads();

    f32x4 acc[2][4];
    #pragma unroll
    for (int i = 0; i < 2; ++i)
        #pragma unroll
        for (int j = 0; j < 4; ++j) acc[i][j] = zero4;
    #pragma unroll
    for (int ks = 0; ks < 4; ++ks) {
        bf16x8 af[2], bfr[4];
        #pragma unroll
        for (int i = 0; i < 2; ++i)
            af[i] = *(const bf16x8*)(lAh + (wm * 32 + i * 16 + l15) * 136 + ks * 32 + quad * 8);
        #pragma unroll
        for (int j = 0; j < 4; ++j)
            bfr[j] = *(const bf16x8*)(lB + (wn * 64 + j * 16 + l15) * 136 + ks * 32 + quad * 8);
        #pragma unroll
        for (int i = 0; i < 2; ++i)
            #pragma unroll
            for (int j = 0; j < 4; ++j)
                acc[i][j] = __builtin_amdgcn_mfma_f32_16x16x32_bf16(af[i], bfr[j], acc[i][j], 0, 0, 0);
    }

    ushort* outb = (ushort*)out;
    float*  outf = (float*)out;
    #pragma unroll
    for (int i = 0; i < 2; ++i)
        #pragma unroll
        for (int j = 0; j < 4; ++j) {
            int co = wn * 64 + j * 16 + l15;
            float uj = uvec[co], vj = vvec[co];
            int pb = wm * 32 + i * 16 + quad * 4;
            #pragma unroll
            for (int r = 0; r < 4; ++r) {
                int p = pb + r;
                float pre = sRs[p] * (acc[i][j][r] - sMean[p] * uj) + vj;
                float val = accG[i][j][r] * pre;
                size_t oidx = (size_t)(p0 + p) * 128 + co;
                if (isbf) outb[oidx] = f2bf(val);
                else      outf[oidx] = val;
            }
        }
}

// ---------------------------------------------------------------------------
extern "C" void kernel_launch(void* const* d_in, const int* in_sizes, int n_in,
                              void* d_out, int out_size, void* d_ws, size_t ws_size,
                              hipStream_t stream)
{
    const void* z     = d_in[0];
    const void* ln_iw = d_in[1];
    const void* ln_ib = d_in[2];
    const void* ln_ow = d_in[3];
    const void* ln_ob = d_in[4];
    const void* w_ap  = d_in[5];
    const void* b_ap  = d_in[6];
    const void* w_ag  = d_in[7];
    const void* b_ag  = d_in[8];
    const void* w_bp  = d_in[9];
    const void* b_bp  = d_in[10];
    const void* w_bg  = d_in[11];
    const void* b_bg  = d_in[12];
    const void* w_g   = d_in[13];
    const void* b_g   = d_in[14];
    const void* w_z   = d_in[15];
    const void* b_z   = d_in[16];

    const size_t MB64 = 67108864;
    const size_t REQ_C = 262144 + 2 * MB64;                    // 134,479,872 (proven-safe)
    const size_t REQ_B = 524288 + MB64 + 2 * MB64;             // 201,850,880
    const size_t REQ_A = REQ_B + MB64;                         // 268,959,744

    char* ws = (char*)d_ws;
    if (ws_size < REQ_C) {
        fill_zero_kernel<<<8192, 256, 0, stream>>>((ushort*)d_out);
        return;
    }

    int tier = (ws_size >= REQ_A) ? 0 : (ws_size >= REQ_B) ? 1 : 2;  // 0=A,1=B,2=C

    // hi prep area (common offsets)
    ushort* wt5_h = (ushort*)(ws);
    ushort* wzt_h = (ushort*)(ws + 163840);
    float*  uvec  = (float*)(ws + 196608);
    float*  vvec  = (float*)(ws + 197120);
    int*    dflag = (int*)(ws + 198144);
    // lo prep area (tiers A/B)
    ushort* wt5_l = (ushort*)(ws + 262144);
    ushort* wzt_l = (ushort*)(ws + 262144 + 163840);
    int store_lo = (tier <= 1) ? 1 : 0;
    if (tier == 2) { wt5_l = wt5_h; wzt_l = wzt_h; }

    ushort* Ahi; ushort* Alo; void* Tbuf;
    int walo = 0, tfp32 = 0;
    if (tier == 0) {
        Ahi = (ushort*)(ws + 524288);
        Alo = (ushort*)(ws + 524288 + MB64);
        Tbuf = (void*)(ws + 524288 + 2 * MB64);
        walo = 1; tfp32 = 1;
    } else if (tier == 1) {
        Ahi = (ushort*)(ws + 524288);
        Alo = Ahi;
        Tbuf = (void*)(ws + 524288 + MB64);
        walo = 0; tfp32 = 1;
    } else {
        Ahi = (ushort*)(ws + 262144);
        Alo = Ahi;
        Tbuf = (void*)(ws + 262144 + MB64);
        walo = 0; tfp32 = 0;
    }
    ushort* Bhi = (ushort*)d_out;

    detect_kernel<<<1, 64, 0, stream>>>((const uint*)z, dflag);
    prep_kernel<<<7, 256, 0, stream>>>(w_ap, w_ag, w_bp, w_bg, w_g, w_z, ln_ow, ln_ob, b_z,
                                       dflag, wt5_h, wt5_l, wzt_h, wzt_l, uvec, vvec, store_lo);
    stage1_kernel<<<dim3(4096, 2), 256, 0, stream>>>(z, ln_iw, ln_ib, wt5_h,
                                                     b_ap, b_ag, b_bp, b_bg, dflag,
                                                     Ahi, Alo, Bhi, walo);
    stage2_kernel<<<dim3(16, 128), 256, 0, stream>>>(Ahi, Alo, Bhi, dflag, Tbuf, walo, tfp32);
    if (tfp32)
        stage3ab_kernel<<<4096, 256, 0, stream>>>(z, ln_iw, ln_ib, wt5_h, wt5_l, b_g,
                                                  (const float*)Tbuf, wzt_h, wzt_l,
                                                  uvec, vvec, dflag, d_out);
    else
        stage3c_kernel<<<4096, 256, 0, stream>>>(z, ln_iw, ln_ib, wt5_h, b_g,
                                                 (const ushort*)Tbuf, wzt_h,
                                                 uvec, vvec, dflag, d_out);
}

// Round 10
// 820.806 us; speedup vs baseline: 1.0603x; 1.0603x over previous
//
#include <hip/hip_runtime.h>
#include <hip/hip_bf16.h>

// TriangleMultiplication (outgoing), N=512, C=C_Z=128. Inputs/out fp32
// (runtime-detected; bf16 fallback kept). Internal: bf16 MFMA with hi/lo
// splitting for precision. Tiers by ws_size:
//  B (>=192.5Mi): A single + B hi/lo + T fp32 + split stage3   <- forced (R10)
//  C (>=128.25Mi): bf16 T, proven-safe layout
//  else: zero-fill diagnostic.
//
// R1: weights read direct from global (L2-hot) in stage1/stage3ab.
// R2 FAILED (absmax 0.24): LN restructure was the culprit (isolated by R5).
// R5: occupancy-only changes PASS 867.7us (stage1 306us, occ 42%).
// R6 FAILED (1003us): stage1 group-fusion spilled av[64] VGPRs to scratch.
// R7: stage2 XCD swizzle = NULL (kept). R8: stage2 K-tile 32: 857.2.
// R9: T layout [i][c][j] = NULL (kept; L3 absorbs inter-stage traffic).
// R10: force tier A -> B (walo=0): stage2 drops AlBh term (-1/3 MFMA),
//      stage1 drops A-lo epilogue (one LDS pass + 64MB writes). T stays
//      fp32 and B keeps hi/lo, so t-LN precision path unchanged; expected
//      absmax 0.031 -> <=0.06 vs 0.095 threshold.

#define NSEQ 512
#define NPOS 262144

typedef short bf16x8 __attribute__((ext_vector_type(8)));
typedef float f32x4 __attribute__((ext_vector_type(4)));

__device__ __forceinline__ float bf2f(ushort h) {
    union { uint u; float f; } x; x.u = ((uint)h) << 16; return x.f;
}
__device__ __forceinline__ ushort f2bf(float f) {
    union { float f; uint u; } x; x.f = f;
    uint r = x.u + 0x7fffu + ((x.u >> 16) & 1u);
    return (ushort)(r >> 16);
}
__device__ __forceinline__ float sigm(float x) { return 1.f / (1.f + __expf(-x)); }

__device__ __forceinline__ float loadIn(const void* p, size_t idx, int isbf) {
    return isbf ? bf2f(((const ushort*)p)[idx]) : ((const float*)p)[idx];
}
__device__ __forceinline__ float2 loadIn2(const void* p, size_t base, int col2, int isbf) {
    if (isbf) {
        uint zz = *(const uint*)((const ushort*)p + base + col2);
        float2 r; r.x = bf2f((ushort)(zz & 0xffff)); r.y = bf2f((ushort)(zz >> 16)); return r;
    }
    return *(const float2*)((const float*)p + base + col2);
}

// ---------------------------------------------------------------------------
__global__ void detect_kernel(const uint* __restrict__ z32, int* __restrict__ flag)
{
    int t = threadIdx.x;
    int votes = 0;
    #pragma unroll
    for (int i = 0; i < 4; ++i) {
        uint wv = z32[t * 4 + i];
        uint ex = (wv >> 7) & 0xff;
        votes += (ex >= 118 && ex <= 132) ? 1 : 0;
    }
    #pragma unroll
    for (int m = 32; m >= 1; m >>= 1) votes += __shfl_xor(votes, m);
    if (t == 0) flag[0] = (votes >= 128) ? 1 : 0;
}

__global__ void fill_zero_kernel(ushort* __restrict__ out)
{
    size_t i = ((size_t)blockIdx.x * 256 + threadIdx.x) * 16;
    uint4 z4 = {0u, 0u, 0u, 0u};
    *(uint4*)(out + i) = z4;
    *(uint4*)(out + i + 8) = z4;
}

// ---------------------------------------------------------------------------
// prep: wt5_h/_l[g][co][ci] (transposed, hi/lo bf16); wzt_h/_l[co][c] of
// W' = ln_ow*w_z; u,v fp32 affine-fold vectors.
// ---------------------------------------------------------------------------
__global__ void prep_kernel(const void* __restrict__ w_ap, const void* __restrict__ w_ag,
                            const void* __restrict__ w_bp, const void* __restrict__ w_bg,
                            const void* __restrict__ w_g,  const void* __restrict__ w_z,
                            const void* __restrict__ ln_ow, const void* __restrict__ ln_ob,
                            const void* __restrict__ b_z,  const int* __restrict__ dflag,
                            ushort* __restrict__ wt5_h, ushort* __restrict__ wt5_l,
                            ushort* __restrict__ wzt_h, ushort* __restrict__ wzt_l,
                            float* __restrict__ u, float* __restrict__ v, int store_lo)
{
    const int b = blockIdx.x, t = threadIdx.x;
    const int isbf = dflag[0];
    if (b < 5) {
        const void* src = (b == 0) ? w_ap : (b == 1) ? w_ag : (b == 2) ? w_bp : (b == 3) ? w_bg : w_g;
        for (int k = 0; k < 64; ++k) {
            int o = t + k * 256;
            int co = o >> 7, ci = o & 127;
            float wv = loadIn(src, ci * 128 + co, isbf);
            ushort hi = f2bf(wv);
            wt5_h[b * 16384 + o] = hi;
            if (store_lo) wt5_l[b * 16384 + o] = f2bf(wv - bf2f(hi));
        }
    } else if (b == 5) {
        for (int k = 0; k < 64; ++k) {
            int o = t + k * 256;
            int co = o >> 7, c = o & 127;
            float wv = loadIn(ln_ow, c, isbf) * loadIn(w_z, c * 128 + co, isbf);
            ushort hi = f2bf(wv);
            wzt_h[o] = hi;
            if (store_lo) wzt_l[o] = f2bf(wv - bf2f(hi));
        }
    } else {
        if (t < 128) {
            float su = 0.f, sv = 0.f;
            for (int c = 0; c < 128; ++c) {
                float wzv = loadIn(w_z, c * 128 + t, isbf);
                su += loadIn(ln_ow, c, isbf) * wzv;
                sv += loadIn(ln_ob, c, isbf) * wzv;
            }
            u[t] = su;
            v[t] = sv + loadIn(b_z, t, isbf);
        }
    }
}

// ---------------------------------------------------------------------------
// stage1: grid (4096, 2). grp0 -> a (A_hi[/A_lo]), grp1 -> b (B_hi,B_lo in d_out).
// zn kept as hi+lo bf16 in LDS; gate+proj GEMMs fused (shared A-fragment reads),
// weight fragments read directly from global (L2-hot, layout matches).
// tb (output transpose buf) aliases zn LDS after the K-loop (barrier-guarded).
// Outputs channel-major [c][p].
// ---------------------------------------------------------------------------
__global__ __launch_bounds__(256, 4)
void stage1_kernel(const void* __restrict__ z,
                   const void* __restrict__ ln_iw, const void* __restrict__ ln_ib,
                   const ushort* __restrict__ wt5_h,
                   const void* __restrict__ b_ap, const void* __restrict__ b_ag,
                   const void* __restrict__ b_bp, const void* __restrict__ b_bg,
                   const int* __restrict__ dflag,
                   ushort* __restrict__ Ahi, ushort* __restrict__ Alo,
                   ushort* __restrict__ Bhi, int walo)
{
    __shared__ ushort sm[2 * 64 * 136];
    ushort* lAh = sm;                    // [64][136] zn hi
    ushort* lAl = sm + 64 * 136;         // [64][136] zn lo
    const int tid = threadIdx.x, lane = tid & 63, w = tid >> 6;
    const int l15 = lane & 15, quad = lane >> 4;
    const int grp = blockIdx.y;
    const int p0 = blockIdx.x * 64;
    const int isbf = dflag[0];

    float lw0 = loadIn(ln_iw, 2 * lane, isbf), lw1 = loadIn(ln_iw, 2 * lane + 1, isbf);
    float lb0 = loadIn(ln_ib, 2 * lane, isbf), lb1 = loadIn(ln_ib, 2 * lane + 1, isbf);
    for (int it = 0; it < 16; ++it) {
        int pl = w * 16 + it;
        float2 xv = loadIn2(z, (size_t)(p0 + pl) * 128, 2 * lane, isbf);
        float x0 = xv.x, x1 = xv.y;
        float s = x0 + x1, s2 = x0 * x0 + x1 * x1;
        #pragma unroll
        for (int m = 32; m >= 1; m >>= 1) { s += __shfl_xor(s, m); s2 += __shfl_xor(s2, m); }
        float mean = s * 0.0078125f;
        float var = s2 * 0.0078125f - mean * mean;
        float rs = rsqrtf(var + 1e-5f);
        float zn0 = (x0 - mean) * rs * lw0 + lb0;
        float zn1 = (x1 - mean) * rs * lw1 + lb1;
        ushort h0 = f2bf(zn0), h1 = f2bf(zn1);
        ushort o0 = f2bf(zn0 - bf2f(h0)), o1 = f2bf(zn1 - bf2f(h1));
        *(uint*)(lAh + pl * 136 + 2 * lane) = (uint)h0 | ((uint)h1 << 16);
        *(uint*)(lAl + pl * 136 + 2 * lane) = (uint)o0 | ((uint)o1 << 16);
    }
    __syncthreads();

    const ushort* wG = wt5_h + ((grp == 0) ? 1 : 3) * 16384;
    const ushort* wP = wt5_h + ((grp == 0) ? 0 : 2) * 16384;

    const int wm = w >> 1, wn = w & 1;
    const f32x4 zero4 = {0.f, 0.f, 0.f, 0.f};
    f32x4 accG[2][4], accP[2][4];
    #pragma unroll
    for (int i = 0; i < 2; ++i)
        #pragma unroll
        for (int j = 0; j < 4; ++j) { accG[i][j] = zero4; accP[i][j] = zero4; }

    #pragma unroll
    for (int ks = 0; ks < 4; ++ks) {
        bf16x8 afh[2], afl[2];
        #pragma unroll
        for (int i = 0; i < 2; ++i) {
            afh[i] = *(const bf16x8*)(lAh + (wm * 32 + i * 16 + l15) * 136 + ks * 32 + quad * 8);
            afl[i] = *(const bf16x8*)(lAl + (wm * 32 + i * 16 + l15) * 136 + ks * 32 + quad * 8);
        }
        {
            bf16x8 bG[4];
            #pragma unroll
            for (int j = 0; j < 4; ++j)
                bG[j] = *(const bf16x8*)(wG + (wn * 64 + j * 16 + l15) * 128 + ks * 32 + quad * 8);
            #pragma unroll
            for (int i = 0; i < 2; ++i)
                #pragma unroll
                for (int j = 0; j < 4; ++j) {
                    accG[i][j] = __builtin_amdgcn_mfma_f32_16x16x32_bf16(afh[i], bG[j], accG[i][j], 0, 0, 0);
                    accG[i][j] = __builtin_amdgcn_mfma_f32_16x16x32_bf16(afl[i], bG[j], accG[i][j], 0, 0, 0);
                }
        }
        {
            bf16x8 bP[4];
            #pragma unroll
            for (int j = 0; j < 4; ++j)
                bP[j] = *(const bf16x8*)(wP + (wn * 64 + j * 16 + l15) * 128 + ks * 32 + quad * 8);
            #pragma unroll
            for (int i = 0; i < 2; ++i)
                #pragma unroll
                for (int j = 0; j < 4; ++j) {
                    accP[i][j] = __builtin_amdgcn_mfma_f32_16x16x32_bf16(afh[i], bP[j], accP[i][j], 0, 0, 0);
                    accP[i][j] = __builtin_amdgcn_mfma_f32_16x16x32_bf16(afl[i], bP[j], accP[i][j], 0, 0, 0);
                }
        }
    }

    const void* bgp = (grp == 0) ? b_ag : b_bg;
    const void* bpp = (grp == 0) ? b_ap : b_bp;
    float av[2][4][4];
    #pragma unroll
    for (int i = 0; i < 2; ++i)
        #pragma unroll
        for (int j = 0; j < 4; ++j) {
            int co = wn * 64 + j * 16 + l15;
            float gv = loadIn(bgp, co, isbf);
            float pv = loadIn(bpp, co, isbf);
            #pragma unroll
            for (int r = 0; r < 4; ++r)
                av[i][j][r] = sigm(accG[i][j][r] + gv) * (accP[i][j][r] + pv);
        }

    ushort* dst_hi = (grp == 0) ? Ahi : Bhi;
    ushort* dst_lo = (grp == 0) ? Alo : (Bhi + 33554432);
    int do_lo = (grp == 0) ? walo : (!isbf);

    // tb aliases sm: all MFMA ds_reads are drained by this barrier
    __syncthreads();
    ushort* tb = sm;   // [128][72]
    #pragma unroll
    for (int i = 0; i < 2; ++i)
        #pragma unroll
        for (int j = 0; j < 4; ++j) {
            int co = wn * 64 + j * 16 + l15;
            int pb = wm * 32 + i * 16 + quad * 4;
            uint2 pk;
            pk.x = (uint)f2bf(av[i][j][0]) | ((uint)f2bf(av[i][j][1]) << 16);
            pk.y = (uint)f2bf(av[i][j][2]) | ((uint)f2bf(av[i][j][3]) << 16);
            *(uint2*)(tb + co * 72 + pb) = pk;
        }
    __syncthreads();
    #pragma unroll
    for (int q = 0; q < 4; ++q) {
        int vv = q * 256 + tid;
        int co = vv >> 3, off = vv & 7;
        *(uint4*)(dst_hi + (size_t)co * NPOS + p0 + off * 8) = *(const uint4*)(tb + co * 72 + off * 8);
    }
    if (do_lo) {
        __syncthreads();
        #pragma unroll
        for (int i = 0; i < 2; ++i)
            #pragma unroll
            for (int j = 0; j < 4; ++j) {
                int co = wn * 64 + j * 16 + l15;
                int pb = wm * 32 + i * 16 + quad * 4;
                ushort lo0 = f2bf(av[i][j][0] - bf2f(f2bf(av[i][j][0])));
                ushort lo1 = f2bf(av[i][j][1] - bf2f(f2bf(av[i][j][1])));
                ushort lo2 = f2bf(av[i][j][2] - bf2f(f2bf(av[i][j][2])));
                ushort lo3 = f2bf(av[i][j][3] - bf2f(f2bf(av[i][j][3])));
                uint2 pk;
                pk.x = (uint)lo0 | ((uint)lo1 << 16);
                pk.y = (uint)lo2 | ((uint)lo3 << 16);
                *(uint2*)(tb + co * 72 + pb) = pk;
            }
        __syncthreads();
        #pragma unroll
        for (int q = 0; q < 4; ++q) {
            int vv = q * 256 + tid;
            int co = vv >> 3, off = vv & 7;
            *(uint4*)(dst_lo + (size_t)co * NPOS + p0 + off * 8) = *(const uint4*)(tb + co * 72 + off * 8);
        }
    }
}

// ---------------------------------------------------------------------------
// stage2: grid (16, 128). T_c = A_c * B_c^T. Terms: Ah*Bh [+ Ah*Bl] [+ Al*Bh].
// T written fp32 (tfp32) or bf16 in [i][c][j] layout: idx = (i*128+c)*512+j.
// R7: XCD swizzle (null, kept). R8: K-tile 32, 3 blk/CU.
// ---------------------------------------------------------------------------
__global__ __launch_bounds__(256, 3)
void stage2_kernel(const ushort* __restrict__ Ahi, const ushort* __restrict__ Alo,
                   const ushort* __restrict__ Bhi, const int* __restrict__ dflag,
                   void* __restrict__ Tbuf, int alo, int tfp32)
{
    __shared__ ushort sm[4 * 128 * 40];   // 40960 B
    ushort* lAh = sm;
    ushort* lAl = sm + 128 * 40;
    ushort* lBh = sm + 2 * 128 * 40;
    ushort* lBl = sm + 3 * 128 * 40;
    const int tid = threadIdx.x, lane = tid & 63, w = tid >> 6;
    const int l15 = lane & 15, quad = lane >> 4;
    const int wm = w >> 1, wn = w & 1;
    const int bid = blockIdx.y * 16 + blockIdx.x;          // 0..2047
    const int swz = (bid & 7) * 256 + (bid >> 3);          // bijective
    const int c = swz >> 4;
    const int ti = (swz & 15) >> 2, tj = swz & 3;
    const int blo = !dflag[0];
    const ushort* Blo = Bhi + 33554432;
    const ushort* Aph = Ahi + (size_t)c * NPOS + (size_t)ti * 128 * NSEQ;
    const ushort* Apl = Alo + (size_t)c * NPOS + (size_t)ti * 128 * NSEQ;
    const ushort* Bph = Bhi + (size_t)c * NPOS + (size_t)tj * 128 * NSEQ;
    const ushort* Bpl = Blo + (size_t)c * NPOS + (size_t)tj * 128 * NSEQ;

    const f32x4 zero4 = {0.f, 0.f, 0.f, 0.f};
    f32x4 acc[4][4];
    #pragma unroll
    for (int i = 0; i < 4; ++i)
        #pragma unroll
        for (int j = 0; j < 4; ++j) acc[i][j] = zero4;

    for (int kt = 0; kt < 16; ++kt) {
        // stage [128][32] ushorts per tile = 512 uint4; 2 per thread
        #pragma unroll
        for (int q = 0; q < 2; ++q) {
            int vv = q * 256 + tid;
            int row = vv >> 2, off = vv & 3;
            *(uint4*)(lAh + row * 40 + off * 8) = *(const uint4*)(Aph + (size_t)row * NSEQ + kt * 32 + off * 8);
            *(uint4*)(lBh + row * 40 + off * 8) = *(const uint4*)(Bph + (size_t)row * NSEQ + kt * 32 + off * 8);
        }
        if (alo) {
            #pragma unroll
            for (int q = 0; q < 2; ++q) {
                int vv = q * 256 + tid;
                int row = vv >> 2, off = vv & 3;
                *(uint4*)(lAl + row * 40 + off * 8) = *(const uint4*)(Apl + (size_t)row * NSEQ + kt * 32 + off * 8);
            }
        }
        if (blo) {
            #pragma unroll
            for (int q = 0; q < 2; ++q) {
                int vv = q * 256 + tid;
                int row = vv >> 2, off = vv & 3;
                *(uint4*)(lBl + row * 40 + off * 8) = *(const uint4*)(Bpl + (size_t)row * NSEQ + kt * 32 + off * 8);
            }
        }
        __syncthreads();
        {
            bf16x8 afh[4], bfh[4];
            #pragma unroll
            for (int i = 0; i < 4; ++i)
                afh[i] = *(const bf16x8*)(lAh + (wm * 64 + i * 16 + l15) * 40 + quad * 8);
            #pragma unroll
            for (int j = 0; j < 4; ++j)
                bfh[j] = *(const bf16x8*)(lBh + (wn * 64 + j * 16 + l15) * 40 + quad * 8);
            #pragma unroll
            for (int i = 0; i < 4; ++i)
                #pragma unroll
                for (int j = 0; j < 4; ++j)
                    acc[i][j] = __builtin_amdgcn_mfma_f32_16x16x32_bf16(afh[i], bfh[j], acc[i][j], 0, 0, 0);
            if (blo) {
                bf16x8 bfl[4];
                #pragma unroll
                for (int j = 0; j < 4; ++j)
                    bfl[j] = *(const bf16x8*)(lBl + (wn * 64 + j * 16 + l15) * 40 + quad * 8);
                #pragma unroll
                for (int i = 0; i < 4; ++i)
                    #pragma unroll
                    for (int j = 0; j < 4; ++j)
                        acc[i][j] = __builtin_amdgcn_mfma_f32_16x16x32_bf16(afh[i], bfl[j], acc[i][j], 0, 0, 0);
            }
            if (alo) {
                bf16x8 afl[4];
                #pragma unroll
                for (int i = 0; i < 4; ++i)
                    afl[i] = *(const bf16x8*)(lAl + (wm * 64 + i * 16 + l15) * 40 + quad * 8);
                #pragma unroll
                for (int i = 0; i < 4; ++i)
                    #pragma unroll
                    for (int j = 0; j < 4; ++j)
                        acc[i][j] = __builtin_amdgcn_mfma_f32_16x16x32_bf16(afl[i], bfh[j], acc[i][j], 0, 0, 0);
            }
        }
        __syncthreads();
    }

    // [i][c][j] layout: idx = ((i)*128 + c)*512 + j, i = ti*128+ib+r, j = tj*128+jl
    if (tfp32) {
        float* Tp = (float*)Tbuf + ((size_t)(ti * 128) * 128 + c) * 512 + tj * 128;
        #pragma unroll
        for (int i = 0; i < 4; ++i)
            #pragma unroll
            for (int j = 0; j < 4; ++j) {
                int jl = wn * 64 + j * 16 + l15;
                int ib = wm * 64 + i * 16 + quad * 4;
                #pragma unroll
                for (int r = 0; r < 4; ++r)
                    Tp[(size_t)(ib + r) * 65536 + jl] = acc[i][j][r];
            }
    } else {
        ushort* Tp = (ushort*)Tbuf + ((size_t)(ti * 128) * 128 + c) * 512 + tj * 128;
        #pragma unroll
        for (int i = 0; i < 4; ++i)
            #pragma unroll
            for (int j = 0; j < 4; ++j) {
                int jl = wn * 64 + j * 16 + l15;
                int ib = wm * 64 + i * 16 + quad * 4;
                #pragma unroll
                for (int r = 0; r < 4; ++r)
                    Tp[(size_t)(ib + r) * 65536 + jl] = f2bf(acc[i][j][r]);
            }
    }
}

// ---------------------------------------------------------------------------
// stage3AB: fp32 T ([i][c][j] layout). Gate 3-term; LN stats from hi+lo t;
// output GEMM 3-term. Weights from global; LDS only for zn/T hi+lo.
// ---------------------------------------------------------------------------
__global__ __launch_bounds__(256, 4)
void stage3ab_kernel(const void* __restrict__ z,
                     const void* __restrict__ ln_iw, const void* __restrict__ ln_ib,
                     const ushort* __restrict__ wt5_h, const ushort* __restrict__ wt5_l,
                     const void* __restrict__ b_g,
                     const float* __restrict__ Tf, const ushort* __restrict__ wzt_h,
                     const ushort* __restrict__ wzt_l,
                     const float* __restrict__ uvec, const float* __restrict__ vvec,
                     const int* __restrict__ dflag, void* __restrict__ out)
{
    __shared__ ushort sm[2 * 64 * 136];
    __shared__ float sMean[64], sRs[64];
    ushort* lAh = sm;
    ushort* lAl = sm + 64 * 136;
    const int tid = threadIdx.x, lane = tid & 63, w = tid >> 6;
    const int l15 = lane & 15, quad = lane >> 4;
    const int wm = w >> 1, wn = w & 1;
    const int p0 = blockIdx.x * 64;
    const int isbf = dflag[0];
    const f32x4 zero4 = {0.f, 0.f, 0.f, 0.f};

    // phase A: zn hi/lo
    float lw0 = loadIn(ln_iw, 2 * lane, isbf), lw1 = loadIn(ln_iw, 2 * lane + 1, isbf);
    float lb0 = loadIn(ln_ib, 2 * lane, isbf), lb1 = loadIn(ln_ib, 2 * lane + 1, isbf);
    for (int it = 0; it < 16; ++it) {
        int pl = w * 16 + it;
        float2 xv = loadIn2(z, (size_t)(p0 + pl) * 128, 2 * lane, isbf);
        float x0 = xv.x, x1 = xv.y;
        float s = x0 + x1, s2 = x0 * x0 + x1 * x1;
        #pragma unroll
        for (int m = 32; m >= 1; m >>= 1) { s += __shfl_xor(s, m); s2 += __shfl_xor(s2, m); }
        float mean = s * 0.0078125f;
        float var = s2 * 0.0078125f - mean * mean;
        float rs = rsqrtf(var + 1e-5f);
        float zn0 = (x0 - mean) * rs * lw0 + lb0;
        float zn1 = (x1 - mean) * rs * lw1 + lb1;
        ushort h0 = f2bf(zn0), h1 = f2bf(zn1);
        ushort o0 = f2bf(zn0 - bf2f(h0)), o1 = f2bf(zn1 - bf2f(h1));
        *(uint*)(lAh + pl * 136 + 2 * lane) = (uint)h0 | ((uint)h1 << 16);
        *(uint*)(lAl + pl * 136 + 2 * lane) = (uint)o0 | ((uint)o1 << 16);
    }
    __syncthreads();

    // gate GEMM, weights from global
    const ushort* wgh = wt5_h + 4 * 16384;
    const ushort* wgl = wt5_l + 4 * 16384;
    f32x4 accG[2][4];
    #pragma unroll
    for (int i = 0; i < 2; ++i)
        #pragma unroll
        for (int j = 0; j < 4; ++j) accG[i][j] = zero4;
    #pragma unroll
    for (int ks = 0; ks < 4; ++ks) {
        bf16x8 afh[2], afl[2], bh[4], bl[4];
        #pragma unroll
        for (int i = 0; i < 2; ++i) {
            afh[i] = *(const bf16x8*)(lAh + (wm * 32 + i * 16 + l15) * 136 + ks * 32 + quad * 8);
            afl[i] = *(const bf16x8*)(lAl + (wm * 32 + i * 16 + l15) * 136 + ks * 32 + quad * 8);
        }
        #pragma unroll
        for (int j = 0; j < 4; ++j) {
            bh[j] = *(const bf16x8*)(wgh + (wn * 64 + j * 16 + l15) * 128 + ks * 32 + quad * 8);
            bl[j] = *(const bf16x8*)(wgl + (wn * 64 + j * 16 + l15) * 128 + ks * 32 + quad * 8);
        }
        #pragma unroll
        for (int i = 0; i < 2; ++i)
            #pragma unroll
            for (int j = 0; j < 4; ++j) {
                accG[i][j] = __builtin_amdgcn_mfma_f32_16x16x32_bf16(afh[i], bh[j], accG[i][j], 0, 0, 0);
                accG[i][j] = __builtin_amdgcn_mfma_f32_16x16x32_bf16(afl[i], bh[j], accG[i][j], 0, 0, 0);
                accG[i][j] = __builtin_amdgcn_mfma_f32_16x16x32_bf16(afh[i], bl[j], accG[i][j], 0, 0, 0);
            }
    }
    #pragma unroll
    for (int i = 0; i < 2; ++i)
        #pragma unroll
        for (int j = 0; j < 4; ++j) {
            int co = wn * 64 + j * 16 + l15;
            float bgv = loadIn(b_g, co, isbf);
            #pragma unroll
            for (int r = 0; r < 4; ++r)
                accG[i][j][r] = sigm(accG[i][j][r] + bgv);
        }
    __syncthreads();

    // phase B: fp32 T ([i][c][j]) -> hi/lo LDS
    {
        int c = tid >> 1, h = tid & 1;
        const float* src = Tf + ((size_t)(p0 >> 9) * 128 + c) * 512 + (p0 & 511) + h * 32;
        float tv[32];
        #pragma unroll
        for (int q8 = 0; q8 < 8; ++q8) {
            float4 f4 = ((const float4*)src)[q8];
            tv[q8 * 4 + 0] = f4.x; tv[q8 * 4 + 1] = f4.y;
            tv[q8 * 4 + 2] = f4.z; tv[q8 * 4 + 3] = f4.w;
        }
        #pragma unroll
        for (int jj = 0; jj < 32; ++jj) {
            ushort hi = f2bf(tv[jj]);
            lAh[(h * 32 + jj) * 136 + c] = hi;
            lAl[(h * 32 + jj) * 136 + c] = f2bf(tv[jj] - bf2f(hi));
        }
    }
    __syncthreads();

    for (int it = 0; it < 16; ++it) {
        int pl = w * 16 + it;
        uint zh = *(const uint*)(lAh + pl * 136 + 2 * lane);
        uint zl = *(const uint*)(lAl + pl * 136 + 2 * lane);
        float x0 = bf2f((ushort)(zh & 0xffff)) + bf2f((ushort)(zl & 0xffff));
        float x1 = bf2f((ushort)(zh >> 16)) + bf2f((ushort)(zl >> 16));
        float s = x0 + x1, s2 = x0 * x0 + x1 * x1;
        #pragma unroll
        for (int m = 32; m >= 1; m >>= 1) { s += __shfl_xor(s, m); s2 += __shfl_xor(s2, m); }
        if (lane == 0) {
            float mean = s * 0.0078125f;
            float var = s2 * 0.0078125f - mean * mean;
            sMean[pl] = mean;
            sRs[pl] = rsqrtf(var + 1e-5f);
        }
    }
    __syncthreads();

    // output GEMM, W' from global
    f32x4 acc[2][4];
    #pragma unroll
    for (int i = 0; i < 2; ++i)
        #pragma unroll
        for (int j = 0; j < 4; ++j) acc[i][j] = zero4;
    #pragma unroll
    for (int ks = 0; ks < 4; ++ks) {
        bf16x8 afh[2], afl[2], bh[4], bl[4];
        #pragma unroll
        for (int i = 0; i < 2; ++i) {
            afh[i] = *(const bf16x8*)(lAh + (wm * 32 + i * 16 + l15) * 136 + ks * 32 + quad * 8);
            afl[i] = *(const bf16x8*)(lAl + (wm * 32 + i * 16 + l15) * 136 + ks * 32 + quad * 8);
        }
        #pragma unroll
        for (int j = 0; j < 4; ++j) {
            bh[j] = *(const bf16x8*)(wzt_h + (wn * 64 + j * 16 + l15) * 128 + ks * 32 + quad * 8);
            bl[j] = *(const bf16x8*)(wzt_l + (wn * 64 + j * 16 + l15) * 128 + ks * 32 + quad * 8);
        }
        #pragma unroll
        for (int i = 0; i < 2; ++i)
            #pragma unroll
            for (int j = 0; j < 4; ++j) {
                acc[i][j] = __builtin_amdgcn_mfma_f32_16x16x32_bf16(afh[i], bh[j], acc[i][j], 0, 0, 0);
                acc[i][j] = __builtin_amdgcn_mfma_f32_16x16x32_bf16(afl[i], bh[j], acc[i][j], 0, 0, 0);
                acc[i][j] = __builtin_amdgcn_mfma_f32_16x16x32_bf16(afh[i], bl[j], acc[i][j], 0, 0, 0);
            }
    }

    ushort* outb = (ushort*)out;
    float*  outf = (float*)out;
    #pragma unroll
    for (int i = 0; i < 2; ++i)
        #pragma unroll
        for (int j = 0; j < 4; ++j) {
            int co = wn * 64 + j * 16 + l15;
            float uj = uvec[co], vj = vvec[co];
            int pb = wm * 32 + i * 16 + quad * 4;
            #pragma unroll
            for (int r = 0; r < 4; ++r) {
                int p = pb + r;
                float pre = sRs[p] * (acc[i][j][r] - sMean[p] * uj) + vj;
                float val = accG[i][j][r] * pre;
                size_t oidx = (size_t)(p0 + p) * 128 + co;
                if (isbf) outb[oidx] = f2bf(val);
                else      outf[oidx] = val;
            }
        }
}

// ---------------------------------------------------------------------------
// stage3C: bf16 T fallback ([i][c][j] layout). Gate 2-term zn split.
// ---------------------------------------------------------------------------
__global__ __launch_bounds__(256, 2)
void stage3c_kernel(const void* __restrict__ z,
                    const void* __restrict__ ln_iw, const void* __restrict__ ln_ib,
                    const ushort* __restrict__ wt5_h, const void* __restrict__ b_g,
                    const ushort* __restrict__ Tb, const ushort* __restrict__ wzt_h,
                    const float* __restrict__ uvec, const float* __restrict__ vvec,
                    const int* __restrict__ dflag, void* __restrict__ out)
{
    __shared__ ushort sm[2 * 64 * 136 + 128 * 136];
    __shared__ float sMean[64], sRs[64];
    ushort* lAh = sm;
    ushort* lAl = sm + 64 * 136;
    ushort* lB  = sm + 2 * 64 * 136;
    const int tid = threadIdx.x, lane = tid & 63, w = tid >> 6;
    const int l15 = lane & 15, quad = lane >> 4;
    const int wm = w >> 1, wn = w & 1;
    const int p0 = blockIdx.x * 64;
    const int isbf = dflag[0];
    const f32x4 zero4 = {0.f, 0.f, 0.f, 0.f};

    float lw0 = loadIn(ln_iw, 2 * lane, isbf), lw1 = loadIn(ln_iw, 2 * lane + 1, isbf);
    float lb0 = loadIn(ln_ib, 2 * lane, isbf), lb1 = loadIn(ln_ib, 2 * lane + 1, isbf);
    for (int it = 0; it < 16; ++it) {
        int pl = w * 16 + it;
        float2 xv = loadIn2(z, (size_t)(p0 + pl) * 128, 2 * lane, isbf);
        float x0 = xv.x, x1 = xv.y;
        float s = x0 + x1, s2 = x0 * x0 + x1 * x1;
        #pragma unroll
        for (int m = 32; m >= 1; m >>= 1) { s += __shfl_xor(s, m); s2 += __shfl_xor(s2, m); }
        float mean = s * 0.0078125f;
        float var = s2 * 0.0078125f - mean * mean;
        float rs = rsqrtf(var + 1e-5f);
        float zn0 = (x0 - mean) * rs * lw0 + lb0;
        float zn1 = (x1 - mean) * rs * lw1 + lb1;
        ushort h0 = f2bf(zn0), h1 = f2bf(zn1);
        ushort o0 = f2bf(zn0 - bf2f(h0)), o1 = f2bf(zn1 - bf2f(h1));
        *(uint*)(lAh + pl * 136 + 2 * lane) = (uint)h0 | ((uint)h1 << 16);
        *(uint*)(lAl + pl * 136 + 2 * lane) = (uint)o0 | ((uint)o1 << 16);
    }
    {
        const ushort* src = wt5_h + 4 * 16384;
        #pragma unroll
        for (int q = 0; q < 8; ++q) {
            int vv = q * 256 + tid;
            int co = vv >> 4, off = vv & 15;
            *(uint4*)(lB + co * 136 + off * 8) = *(const uint4*)(src + co * 128 + off * 8);
        }
    }
    __syncthreads();

    f32x4 accG[2][4];
    #pragma unroll
    for (int i = 0; i < 2; ++i)
        #pragma unroll
        for (int j = 0; j < 4; ++j) accG[i][j] = zero4;
    #pragma unroll
    for (int ks = 0; ks < 4; ++ks) {
        bf16x8 afh[2], afl[2], bfr[4];
        #pragma unroll
        for (int i = 0; i < 2; ++i) {
            afh[i] = *(const bf16x8*)(lAh + (wm * 32 + i * 16 + l15) * 136 + ks * 32 + quad * 8);
            afl[i] = *(const bf16x8*)(lAl + (wm * 32 + i * 16 + l15) * 136 + ks * 32 + quad * 8);
        }
        #pragma unroll
        for (int j = 0; j < 4; ++j)
            bfr[j] = *(const bf16x8*)(lB + (wn * 64 + j * 16 + l15) * 136 + ks * 32 + quad * 8);
        #pragma unroll
        for (int i = 0; i < 2; ++i)
            #pragma unroll
            for (int j = 0; j < 4; ++j) {
                accG[i][j] = __builtin_amdgcn_mfma_f32_16x16x32_bf16(afh[i], bfr[j], accG[i][j], 0, 0, 0);
                accG[i][j] = __builtin_amdgcn_mfma_f32_16x16x32_bf16(afl[i], bfr[j], accG[i][j], 0, 0, 0);
            }
    }
    #pragma unroll
    for (int i = 0; i < 2; ++i)
        #pragma unroll
        for (int j = 0; j < 4; ++j) {
            int co = wn * 64 + j * 16 + l15;
            float bgv = loadIn(b_g, co, isbf);
            #pragma unroll
            for (int r = 0; r < 4; ++r)
                accG[i][j][r] = sigm(accG[i][j][r] + bgv);
        }
    __syncthreads();

    {
        int c = tid >> 1, h = tid & 1;
        const ushort* src = Tb + ((size_t)(p0 >> 9) * 128 + c) * 512 + (p0 & 511) + h * 32;
        union { uint4 q[4]; ushort u[32]; } tmp;
        tmp.q[0] = ((const uint4*)src)[0];
        tmp.q[1] = ((const uint4*)src)[1];
        tmp.q[2] = ((const uint4*)src)[2];
        tmp.q[3] = ((const uint4*)src)[3];
        #pragma unroll
        for (int jj = 0; jj < 32; ++jj)
            lAh[(h * 32 + jj) * 136 + c] = tmp.u[jj];
    }
    #pragma unroll
    for (int q = 0; q < 8; ++q) {
        int vv = q * 256 + tid;
        int co = vv >> 4, off = vv & 15;
        *(uint4*)(lB + co * 136 + off * 8) = *(const uint4*)(wzt_h + co * 128 + off * 8);
    }
    __syncthreads();

    for (int it = 0; it < 16; ++it) {
        int pl = w * 16 + it;
        uint zz = *(const uint*)(lAh + pl * 136 + 2 * lane);
        float x0 = bf2f((ushort)(zz & 0xffff)), x1 = bf2f((ushort)(zz >> 16));
        float s = x0 + x1, s2 = x0 * x0 + x1 * x1;
        #pragma unroll
        for (int m = 32; m >= 1; m >>= 1) { s += __shfl_xor(s, m); s2 += __shfl_xor(s2, m); }
        if (lane == 0) {
            float mean = s * 0.0078125f;
            float var = s2 * 0.0078125f - mean * mean;
            sMean[pl] = mean;
            sRs[pl] = rsqrtf(var + 1e-5f);
        }
    }
    __syncthreads();

    f32x4 acc[2][4];
    #pragma unroll
    for (int i = 0; i < 2; ++i)
        #pragma unroll
        for (int j = 0; j < 4; ++j) acc[i][j] = zero4;
    #pragma unroll
    for (int ks = 0; ks < 4; ++ks) {
        bf16x8 af[2], bfr[4];
        #pragma unroll
        for (int i = 0; i < 2; ++i)
            af[i] = *(const bf16x8*)(lAh + (wm * 32 + i * 16 + l15) * 136 + ks * 32 + quad * 8);
        #pragma unroll
        for (int j = 0; j < 4; ++j)
            bfr[j] = *(const bf16x8*)(lB + (wn * 64 + j * 16 + l15) * 136 + ks * 32 + quad * 8);
        #pragma unroll
        for (int i = 0; i < 2; ++i)
            #pragma unroll
            for (int j = 0; j < 4; ++j)
                acc[i][j] = __builtin_amdgcn_mfma_f32_16x16x32_bf16(af[i], bfr[j], acc[i][j], 0, 0, 0);
    }

    ushort* outb = (ushort*)out;
    float*  outf = (float*)out;
    #pragma unroll
    for (int i = 0; i < 2; ++i)
        #pragma unroll
        for (int j = 0; j < 4; ++j) {
            int co = wn * 64 + j * 16 + l15;
            float uj = uvec[co], vj = vvec[co];
            int pb = wm * 32 + i * 16 + quad * 4;
            #pragma unroll
            for (int r = 0; r < 4; ++r) {
                int p = pb + r;
                float pre = sRs[p] * (acc[i][j][r] - sMean[p] * uj) + vj;
                float val = accG[i][j][r] * pre;
                size_t oidx = (size_t)(p0 + p) * 128 + co;
                if (isbf) outb[oidx] = f2bf(val);
                else      outf[oidx] = val;
            }
        }
}

// ---------------------------------------------------------------------------
extern "C" void kernel_launch(void* const* d_in, const int* in_sizes, int n_in,
                              void* d_out, int out_size, void* d_ws, size_t ws_size,
                              hipStream_t stream)
{
    const void* z     = d_in[0];
    const void* ln_iw = d_in[1];
    const void* ln_ib = d_in[2];
    const void* ln_ow = d_in[3];
    const void* ln_ob = d_in[4];
    const void* w_ap  = d_in[5];
    const void* b_ap  = d_in[6];
    const void* w_ag  = d_in[7];
    const void* b_ag  = d_in[8];
    const void* w_bp  = d_in[9];
    const void* b_bp  = d_in[10];
    const void* w_bg  = d_in[11];
    const void* b_bg  = d_in[12];
    const void* w_g   = d_in[13];
    const void* b_g   = d_in[14];
    const void* w_z   = d_in[15];
    const void* b_z   = d_in[16];

    const size_t MB64 = 67108864;
    const size_t REQ_C = 262144 + 2 * MB64;                    // 134,479,872 (proven-safe)
    const size_t REQ_B = 524288 + MB64 + 2 * MB64;             // 201,850,880
    const size_t REQ_A = REQ_B + MB64;                         // 268,959,744

    char* ws = (char*)d_ws;
    if (ws_size < REQ_C) {
        fill_zero_kernel<<<8192, 256, 0, stream>>>((ushort*)d_out);
        return;
    }

    int tier = (ws_size >= REQ_A) ? 0 : (ws_size >= REQ_B) ? 1 : 2;  // 0=A,1=B,2=C
    if (tier == 0) tier = 1;   // R10: force tier B (drop AlBh term; A single-bf16)

    // hi prep area (common offsets)
    ushort* wt5_h = (ushort*)(ws);
    ushort* wzt_h = (ushort*)(ws + 163840);
    float*  uvec  = (float*)(ws + 196608);
    float*  vvec  = (float*)(ws + 197120);
    int*    dflag = (int*)(ws + 198144);
    // lo prep area (tiers A/B)
    ushort* wt5_l = (ushort*)(ws + 262144);
    ushort* wzt_l = (ushort*)(ws + 262144 + 163840);
    int store_lo = (tier <= 1) ? 1 : 0;
    if (tier == 2) { wt5_l = wt5_h; wzt_l = wzt_h; }

    ushort* Ahi; ushort* Alo; void* Tbuf;
    int walo = 0, tfp32 = 0;
    if (tier == 0) {
        Ahi = (ushort*)(ws + 524288);
        Alo = (ushort*)(ws + 524288 + MB64);
        Tbuf = (void*)(ws + 524288 + 2 * MB64);
        walo = 1; tfp32 = 1;
    } else if (tier == 1) {
        Ahi = (ushort*)(ws + 524288);
        Alo = Ahi;
        Tbuf = (void*)(ws + 524288 + MB64);
        walo = 0; tfp32 = 1;
    } else {
        Ahi = (ushort*)(ws + 262144);
        Alo = Ahi;
        Tbuf = (void*)(ws + 262144 + MB64);
        walo = 0; tfp32 = 0;
    }
    ushort* Bhi = (ushort*)d_out;

    detect_kernel<<<1, 64, 0, stream>>>((const uint*)z, dflag);
    prep_kernel<<<7, 256, 0, stream>>>(w_ap, w_ag, w_bp, w_bg, w_g, w_z, ln_ow, ln_ob, b_z,
                                       dflag, wt5_h, wt5_l, wzt_h, wzt_l, uvec, vvec, store_lo);
    stage1_kernel<<<dim3(4096, 2), 256, 0, stream>>>(z, ln_iw, ln_ib, wt5_h,
                                                     b_ap, b_ag, b_bp, b_bg, dflag,
                                                     Ahi, Alo, Bhi, walo);
    stage2_kernel<<<dim3(16, 128), 256, 0, stream>>>(Ahi, Alo, Bhi, dflag, Tbuf, walo, tfp32);
    if (tfp32)
        stage3ab_kernel<<<4096, 256, 0, stream>>>(z, ln_iw, ln_ib, wt5_h, wt5_l, b_g,
                                                  (const float*)Tbuf, wzt_h, wzt_l,
                                                  uvec, vvec, dflag, d_out);
    else
        stage3c_kernel<<<4096, 256, 0, stream>>>(z, ln_iw, ln_ib, wt5_h, b_g,
                                                 (const ushort*)Tbuf, wzt_h,
                                                 uvec, vvec, dflag, d_out);
}

// Round 12
// 780.584 us; speedup vs baseline: 1.1149x; 1.0515x over previous
//
#include <hip/hip_runtime.h>
#include <hip/hip_bf16.h>

// TriangleMultiplication (outgoing), N=512, C=C_Z=128. Inputs/out fp32
// (runtime-detected; bf16 fallback kept). Internal: bf16 MFMA; hi/lo
// splitting retained only where it matters (zn in small GEMMs, T fp32).
//
// R1: weights read direct from global (L2-hot) in stage1/stage3ab.
// R2 FAILED (absmax 0.24): LN restructure was the culprit (isolated by R5).
// R5: occupancy-only changes PASS 867.7us (stage1 306us, occ 42%).
// R6 FAILED (1003us): stage1 group-fusion spilled av[64] VGPRs to scratch.
// R7: stage2 XCD swizzle = NULL (kept). R8: stage2 K-tile 32: 857.2.
// R9: T layout [i][c][j] = NULL (kept; L3 absorbs inter-stage traffic).
// R10: tier A->B (drop A-lo): 820.8us, absmax UNCHANGED 0.03125 -> lo-planes
//      contribute ~5.6e-4 relative on T (random-sign cancellation).
// R11: drop B-lo too (stage2 blo=0 -> 1 MFMA term-set, -50% stage2 MFMA;
//      LDS 40960->30720; stage1 grp1 lo-epilogue removed, WRITE 196->131MB).
//      Expected absmax <=0.0625 vs 0.095 threshold.
// R12: identical resubmit (container infra failure, no signal).

#define NSEQ 512
#define NPOS 262144

typedef short bf16x8 __attribute__((ext_vector_type(8)));
typedef float f32x4 __attribute__((ext_vector_type(4)));

__device__ __forceinline__ float bf2f(ushort h) {
    union { uint u; float f; } x; x.u = ((uint)h) << 16; return x.f;
}
__device__ __forceinline__ ushort f2bf(float f) {
    union { float f; uint u; } x; x.f = f;
    uint r = x.u + 0x7fffu + ((x.u >> 16) & 1u);
    return (ushort)(r >> 16);
}
__device__ __forceinline__ float sigm(float x) { return 1.f / (1.f + __expf(-x)); }

__device__ __forceinline__ float loadIn(const void* p, size_t idx, int isbf) {
    return isbf ? bf2f(((const ushort*)p)[idx]) : ((const float*)p)[idx];
}
__device__ __forceinline__ float2 loadIn2(const void* p, size_t base, int col2, int isbf) {
    if (isbf) {
        uint zz = *(const uint*)((const ushort*)p + base + col2);
        float2 r; r.x = bf2f((ushort)(zz & 0xffff)); r.y = bf2f((ushort)(zz >> 16)); return r;
    }
    return *(const float2*)((const float*)p + base + col2);
}

// ---------------------------------------------------------------------------
__global__ void detect_kernel(const uint* __restrict__ z32, int* __restrict__ flag)
{
    int t = threadIdx.x;
    int votes = 0;
    #pragma unroll
    for (int i = 0; i < 4; ++i) {
        uint wv = z32[t * 4 + i];
        uint ex = (wv >> 7) & 0xff;
        votes += (ex >= 118 && ex <= 132) ? 1 : 0;
    }
    #pragma unroll
    for (int m = 32; m >= 1; m >>= 1) votes += __shfl_xor(votes, m);
    if (t == 0) flag[0] = (votes >= 128) ? 1 : 0;
}

__global__ void fill_zero_kernel(ushort* __restrict__ out)
{
    size_t i = ((size_t)blockIdx.x * 256 + threadIdx.x) * 16;
    uint4 z4 = {0u, 0u, 0u, 0u};
    *(uint4*)(out + i) = z4;
    *(uint4*)(out + i + 8) = z4;
}

// ---------------------------------------------------------------------------
// prep: wt5_h/_l[g][co][ci] (transposed, hi/lo bf16); wzt_h/_l[co][c] of
// W' = ln_ow*w_z; u,v fp32 affine-fold vectors.
// ---------------------------------------------------------------------------
__global__ void prep_kernel(const void* __restrict__ w_ap, const void* __restrict__ w_ag,
                            const void* __restrict__ w_bp, const void* __restrict__ w_bg,
                            const void* __restrict__ w_g,  const void* __restrict__ w_z,
                            const void* __restrict__ ln_ow, const void* __restrict__ ln_ob,
                            const void* __restrict__ b_z,  const int* __restrict__ dflag,
                            ushort* __restrict__ wt5_h, ushort* __restrict__ wt5_l,
                            ushort* __restrict__ wzt_h, ushort* __restrict__ wzt_l,
                            float* __restrict__ u, float* __restrict__ v, int store_lo)
{
    const int b = blockIdx.x, t = threadIdx.x;
    const int isbf = dflag[0];
    if (b < 5) {
        const void* src = (b == 0) ? w_ap : (b == 1) ? w_ag : (b == 2) ? w_bp : (b == 3) ? w_bg : w_g;
        for (int k = 0; k < 64; ++k) {
            int o = t + k * 256;
            int co = o >> 7, ci = o & 127;
            float wv = loadIn(src, ci * 128 + co, isbf);
            ushort hi = f2bf(wv);
            wt5_h[b * 16384 + o] = hi;
            if (store_lo) wt5_l[b * 16384 + o] = f2bf(wv - bf2f(hi));
        }
    } else if (b == 5) {
        for (int k = 0; k < 64; ++k) {
            int o = t + k * 256;
            int co = o >> 7, c = o & 127;
            float wv = loadIn(ln_ow, c, isbf) * loadIn(w_z, c * 128 + co, isbf);
            ushort hi = f2bf(wv);
            wzt_h[o] = hi;
            if (store_lo) wzt_l[o] = f2bf(wv - bf2f(hi));
        }
    } else {
        if (t < 128) {
            float su = 0.f, sv = 0.f;
            for (int c = 0; c < 128; ++c) {
                float wzv = loadIn(w_z, c * 128 + t, isbf);
                su += loadIn(ln_ow, c, isbf) * wzv;
                sv += loadIn(ln_ob, c, isbf) * wzv;
            }
            u[t] = su;
            v[t] = sv + loadIn(b_z, t, isbf);
        }
    }
}

// ---------------------------------------------------------------------------
// stage1: grid (4096, 2). grp0 -> a (A_hi), grp1 -> b (B_hi in d_out).
// zn kept as hi+lo bf16 in LDS; gate+proj GEMMs fused (shared A-fragment reads),
// weight fragments read directly from global (L2-hot, layout matches).
// tb (output transpose buf) aliases zn LDS after the K-loop (barrier-guarded).
// Outputs channel-major [c][p]. R11: lo-epilogue gated by walo for BOTH groups.
// ---------------------------------------------------------------------------
__global__ __launch_bounds__(256, 4)
void stage1_kernel(const void* __restrict__ z,
                   const void* __restrict__ ln_iw, const void* __restrict__ ln_ib,
                   const ushort* __restrict__ wt5_h,
                   const void* __restrict__ b_ap, const void* __restrict__ b_ag,
                   const void* __restrict__ b_bp, const void* __restrict__ b_bg,
                   const int* __restrict__ dflag,
                   ushort* __restrict__ Ahi, ushort* __restrict__ Alo,
                   ushort* __restrict__ Bhi, int walo)
{
    __shared__ ushort sm[2 * 64 * 136];
    ushort* lAh = sm;                    // [64][136] zn hi
    ushort* lAl = sm + 64 * 136;         // [64][136] zn lo
    const int tid = threadIdx.x, lane = tid & 63, w = tid >> 6;
    const int l15 = lane & 15, quad = lane >> 4;
    const int grp = blockIdx.y;
    const int p0 = blockIdx.x * 64;
    const int isbf = dflag[0];

    float lw0 = loadIn(ln_iw, 2 * lane, isbf), lw1 = loadIn(ln_iw, 2 * lane + 1, isbf);
    float lb0 = loadIn(ln_ib, 2 * lane, isbf), lb1 = loadIn(ln_ib, 2 * lane + 1, isbf);
    for (int it = 0; it < 16; ++it) {
        int pl = w * 16 + it;
        float2 xv = loadIn2(z, (size_t)(p0 + pl) * 128, 2 * lane, isbf);
        float x0 = xv.x, x1 = xv.y;
        float s = x0 + x1, s2 = x0 * x0 + x1 * x1;
        #pragma unroll
        for (int m = 32; m >= 1; m >>= 1) { s += __shfl_xor(s, m); s2 += __shfl_xor(s2, m); }
        float mean = s * 0.0078125f;
        float var = s2 * 0.0078125f - mean * mean;
        float rs = rsqrtf(var + 1e-5f);
        float zn0 = (x0 - mean) * rs * lw0 + lb0;
        float zn1 = (x1 - mean) * rs * lw1 + lb1;
        ushort h0 = f2bf(zn0), h1 = f2bf(zn1);
        ushort o0 = f2bf(zn0 - bf2f(h0)), o1 = f2bf(zn1 - bf2f(h1));
        *(uint*)(lAh + pl * 136 + 2 * lane) = (uint)h0 | ((uint)h1 << 16);
        *(uint*)(lAl + pl * 136 + 2 * lane) = (uint)o0 | ((uint)o1 << 16);
    }
    __syncthreads();

    const ushort* wG = wt5_h + ((grp == 0) ? 1 : 3) * 16384;
    const ushort* wP = wt5_h + ((grp == 0) ? 0 : 2) * 16384;

    const int wm = w >> 1, wn = w & 1;
    const f32x4 zero4 = {0.f, 0.f, 0.f, 0.f};
    f32x4 accG[2][4], accP[2][4];
    #pragma unroll
    for (int i = 0; i < 2; ++i)
        #pragma unroll
        for (int j = 0; j < 4; ++j) { accG[i][j] = zero4; accP[i][j] = zero4; }

    #pragma unroll
    for (int ks = 0; ks < 4; ++ks) {
        bf16x8 afh[2], afl[2];
        #pragma unroll
        for (int i = 0; i < 2; ++i) {
            afh[i] = *(const bf16x8*)(lAh + (wm * 32 + i * 16 + l15) * 136 + ks * 32 + quad * 8);
            afl[i] = *(const bf16x8*)(lAl + (wm * 32 + i * 16 + l15) * 136 + ks * 32 + quad * 8);
        }
        {
            bf16x8 bG[4];
            #pragma unroll
            for (int j = 0; j < 4; ++j)
                bG[j] = *(const bf16x8*)(wG + (wn * 64 + j * 16 + l15) * 128 + ks * 32 + quad * 8);
            #pragma unroll
            for (int i = 0; i < 2; ++i)
                #pragma unroll
                for (int j = 0; j < 4; ++j) {
                    accG[i][j] = __builtin_amdgcn_mfma_f32_16x16x32_bf16(afh[i], bG[j], accG[i][j], 0, 0, 0);
                    accG[i][j] = __builtin_amdgcn_mfma_f32_16x16x32_bf16(afl[i], bG[j], accG[i][j], 0, 0, 0);
                }
        }
        {
            bf16x8 bP[4];
            #pragma unroll
            for (int j = 0; j < 4; ++j)
                bP[j] = *(const bf16x8*)(wP + (wn * 64 + j * 16 + l15) * 128 + ks * 32 + quad * 8);
            #pragma unroll
            for (int i = 0; i < 2; ++i)
                #pragma unroll
                for (int j = 0; j < 4; ++j) {
                    accP[i][j] = __builtin_amdgcn_mfma_f32_16x16x32_bf16(afh[i], bP[j], accP[i][j], 0, 0, 0);
                    accP[i][j] = __builtin_amdgcn_mfma_f32_16x16x32_bf16(afl[i], bP[j], accP[i][j], 0, 0, 0);
                }
        }
    }

    const void* bgp = (grp == 0) ? b_ag : b_bg;
    const void* bpp = (grp == 0) ? b_ap : b_bp;
    float av[2][4][4];
    #pragma unroll
    for (int i = 0; i < 2; ++i)
        #pragma unroll
        for (int j = 0; j < 4; ++j) {
            int co = wn * 64 + j * 16 + l15;
            float gv = loadIn(bgp, co, isbf);
            float pv = loadIn(bpp, co, isbf);
            #pragma unroll
            for (int r = 0; r < 4; ++r)
                av[i][j][r] = sigm(accG[i][j][r] + gv) * (accP[i][j][r] + pv);
        }

    ushort* dst_hi = (grp == 0) ? Ahi : Bhi;
    ushort* dst_lo = (grp == 0) ? Alo : (Bhi + 33554432);
    const int do_lo = walo;   // R11: lo-plane disabled for both groups

    // tb aliases sm: all MFMA ds_reads are drained by this barrier
    __syncthreads();
    ushort* tb = sm;   // [128][72]
    #pragma unroll
    for (int i = 0; i < 2; ++i)
        #pragma unroll
        for (int j = 0; j < 4; ++j) {
            int co = wn * 64 + j * 16 + l15;
            int pb = wm * 32 + i * 16 + quad * 4;
            uint2 pk;
            pk.x = (uint)f2bf(av[i][j][0]) | ((uint)f2bf(av[i][j][1]) << 16);
            pk.y = (uint)f2bf(av[i][j][2]) | ((uint)f2bf(av[i][j][3]) << 16);
            *(uint2*)(tb + co * 72 + pb) = pk;
        }
    __syncthreads();
    #pragma unroll
    for (int q = 0; q < 4; ++q) {
        int vv = q * 256 + tid;
        int co = vv >> 3, off = vv & 7;
        *(uint4*)(dst_hi + (size_t)co * NPOS + p0 + off * 8) = *(const uint4*)(tb + co * 72 + off * 8);
    }
    if (do_lo) {
        __syncthreads();
        #pragma unroll
        for (int i = 0; i < 2; ++i)
            #pragma unroll
            for (int j = 0; j < 4; ++j) {
                int co = wn * 64 + j * 16 + l15;
                int pb = wm * 32 + i * 16 + quad * 4;
                ushort lo0 = f2bf(av[i][j][0] - bf2f(f2bf(av[i][j][0])));
                ushort lo1 = f2bf(av[i][j][1] - bf2f(f2bf(av[i][j][1])));
                ushort lo2 = f2bf(av[i][j][2] - bf2f(f2bf(av[i][j][2])));
                ushort lo3 = f2bf(av[i][j][3] - bf2f(f2bf(av[i][j][3])));
                uint2 pk;
                pk.x = (uint)lo0 | ((uint)lo1 << 16);
                pk.y = (uint)lo2 | ((uint)lo3 << 16);
                *(uint2*)(tb + co * 72 + pb) = pk;
            }
        __syncthreads();
        #pragma unroll
        for (int q = 0; q < 4; ++q) {
            int vv = q * 256 + tid;
            int co = vv >> 3, off = vv & 7;
            *(uint4*)(dst_lo + (size_t)co * NPOS + p0 + off * 8) = *(const uint4*)(tb + co * 72 + off * 8);
        }
    }
}

// ---------------------------------------------------------------------------
// stage2: grid (16, 128). T_c = A_c * B_c^T, single hi*hi MFMA term (R11).
// T written fp32 (tfp32) or bf16 in [i][c][j] layout: idx = (i*128+c)*512+j.
// R7: XCD swizzle (null, kept). R8: K-tile 32. R11: LDS 30720 B (3 planes).
// ---------------------------------------------------------------------------
__global__ __launch_bounds__(256, 3)
void stage2_kernel(const ushort* __restrict__ Ahi, const ushort* __restrict__ Alo,
                   const ushort* __restrict__ Bhi, const int* __restrict__ dflag,
                   void* __restrict__ Tbuf, int alo, int tfp32)
{
    __shared__ ushort sm[3 * 128 * 40];   // 30720 B
    ushort* lAh = sm;
    ushort* lAl = sm + 128 * 40;
    ushort* lBh = sm + 2 * 128 * 40;
    const int tid = threadIdx.x, lane = tid & 63, w = tid >> 6;
    const int l15 = lane & 15, quad = lane >> 4;
    const int wm = w >> 1, wn = w & 1;
    const int bid = blockIdx.y * 16 + blockIdx.x;          // 0..2047
    const int swz = (bid & 7) * 256 + (bid >> 3);          // bijective
    const int c = swz >> 4;
    const int ti = (swz & 15) >> 2, tj = swz & 3;
    const ushort* Aph = Ahi + (size_t)c * NPOS + (size_t)ti * 128 * NSEQ;
    const ushort* Apl = Alo + (size_t)c * NPOS + (size_t)ti * 128 * NSEQ;
    const ushort* Bph = Bhi + (size_t)c * NPOS + (size_t)tj * 128 * NSEQ;

    const f32x4 zero4 = {0.f, 0.f, 0.f, 0.f};
    f32x4 acc[4][4];
    #pragma unroll
    for (int i = 0; i < 4; ++i)
        #pragma unroll
        for (int j = 0; j < 4; ++j) acc[i][j] = zero4;

    for (int kt = 0; kt < 16; ++kt) {
        // stage [128][32] ushorts per tile = 512 uint4; 2 per thread
        #pragma unroll
        for (int q = 0; q < 2; ++q) {
            int vv = q * 256 + tid;
            int row = vv >> 2, off = vv & 3;
            *(uint4*)(lAh + row * 40 + off * 8) = *(const uint4*)(Aph + (size_t)row * NSEQ + kt * 32 + off * 8);
            *(uint4*)(lBh + row * 40 + off * 8) = *(const uint4*)(Bph + (size_t)row * NSEQ + kt * 32 + off * 8);
        }
        if (alo) {
            #pragma unroll
            for (int q = 0; q < 2; ++q) {
                int vv = q * 256 + tid;
                int row = vv >> 2, off = vv & 3;
                *(uint4*)(lAl + row * 40 + off * 8) = *(const uint4*)(Apl + (size_t)row * NSEQ + kt * 32 + off * 8);
            }
        }
        __syncthreads();
        {
            bf16x8 afh[4], bfh[4];
            #pragma unroll
            for (int i = 0; i < 4; ++i)
                afh[i] = *(const bf16x8*)(lAh + (wm * 64 + i * 16 + l15) * 40 + quad * 8);
            #pragma unroll
            for (int j = 0; j < 4; ++j)
                bfh[j] = *(const bf16x8*)(lBh + (wn * 64 + j * 16 + l15) * 40 + quad * 8);
            #pragma unroll
            for (int i = 0; i < 4; ++i)
                #pragma unroll
                for (int j = 0; j < 4; ++j)
                    acc[i][j] = __builtin_amdgcn_mfma_f32_16x16x32_bf16(afh[i], bfh[j], acc[i][j], 0, 0, 0);
            if (alo) {
                bf16x8 afl[4];
                #pragma unroll
                for (int i = 0; i < 4; ++i)
                    afl[i] = *(const bf16x8*)(lAl + (wm * 64 + i * 16 + l15) * 40 + quad * 8);
                #pragma unroll
                for (int i = 0; i < 4; ++i)
                    #pragma unroll
                    for (int j = 0; j < 4; ++j)
                        acc[i][j] = __builtin_amdgcn_mfma_f32_16x16x32_bf16(afl[i], bfh[j], acc[i][j], 0, 0, 0);
            }
        }
        __syncthreads();
    }

    // [i][c][j] layout: idx = ((i)*128 + c)*512 + j, i = ti*128+ib+r, j = tj*128+jl
    if (tfp32) {
        float* Tp = (float*)Tbuf + ((size_t)(ti * 128) * 128 + c) * 512 + tj * 128;
        #pragma unroll
        for (int i = 0; i < 4; ++i)
            #pragma unroll
            for (int j = 0; j < 4; ++j) {
                int jl = wn * 64 + j * 16 + l15;
                int ib = wm * 64 + i * 16 + quad * 4;
                #pragma unroll
                for (int r = 0; r < 4; ++r)
                    Tp[(size_t)(ib + r) * 65536 + jl] = acc[i][j][r];
            }
    } else {
        ushort* Tp = (ushort*)Tbuf + ((size_t)(ti * 128) * 128 + c) * 512 + tj * 128;
        #pragma unroll
        for (int i = 0; i < 4; ++i)
            #pragma unroll
            for (int j = 0; j < 4; ++j) {
                int jl = wn * 64 + j * 16 + l15;
                int ib = wm * 64 + i * 16 + quad * 4;
                #pragma unroll
                for (int r = 0; r < 4; ++r)
                    Tp[(size_t)(ib + r) * 65536 + jl] = f2bf(acc[i][j][r]);
            }
    }
}

// ---------------------------------------------------------------------------
// stage3AB: fp32 T ([i][c][j] layout). Gate 3-term; LN stats from hi+lo t;
// output GEMM 3-term. Weights from global; LDS only for zn/T hi+lo.
// ---------------------------------------------------------------------------
__global__ __launch_bounds__(256, 4)
void stage3ab_kernel(const void* __restrict__ z,
                     const void* __restrict__ ln_iw, const void* __restrict__ ln_ib,
                     const ushort* __restrict__ wt5_h, const ushort* __restrict__ wt5_l,
                     const void* __restrict__ b_g,
                     const float* __restrict__ Tf, const ushort* __restrict__ wzt_h,
                     const ushort* __restrict__ wzt_l,
                     const float* __restrict__ uvec, const float* __restrict__ vvec,
                     const int* __restrict__ dflag, void* __restrict__ out)
{
    __shared__ ushort sm[2 * 64 * 136];
    __shared__ float sMean[64], sRs[64];
    ushort* lAh = sm;
    ushort* lAl = sm + 64 * 136;
    const int tid = threadIdx.x, lane = tid & 63, w = tid >> 6;
    const int l15 = lane & 15, quad = lane >> 4;
    const int wm = w >> 1, wn = w & 1;
    const int p0 = blockIdx.x * 64;
    const int isbf = dflag[0];
    const f32x4 zero4 = {0.f, 0.f, 0.f, 0.f};

    // phase A: zn hi/lo
    float lw0 = loadIn(ln_iw, 2 * lane, isbf), lw1 = loadIn(ln_iw, 2 * lane + 1, isbf);
    float lb0 = loadIn(ln_ib, 2 * lane, isbf), lb1 = loadIn(ln_ib, 2 * lane + 1, isbf);
    for (int it = 0; it < 16; ++it) {
        int pl = w * 16 + it;
        float2 xv = loadIn2(z, (size_t)(p0 + pl) * 128, 2 * lane, isbf);
        float x0 = xv.x, x1 = xv.y;
        float s = x0 + x1, s2 = x0 * x0 + x1 * x1;
        #pragma unroll
        for (int m = 32; m >= 1; m >>= 1) { s += __shfl_xor(s, m); s2 += __shfl_xor(s2, m); }
        float mean = s * 0.0078125f;
        float var = s2 * 0.0078125f - mean * mean;
        float rs = rsqrtf(var + 1e-5f);
        float zn0 = (x0 - mean) * rs * lw0 + lb0;
        float zn1 = (x1 - mean) * rs * lw1 + lb1;
        ushort h0 = f2bf(zn0), h1 = f2bf(zn1);
        ushort o0 = f2bf(zn0 - bf2f(h0)), o1 = f2bf(zn1 - bf2f(h1));
        *(uint*)(lAh + pl * 136 + 2 * lane) = (uint)h0 | ((uint)h1 << 16);
        *(uint*)(lAl + pl * 136 + 2 * lane) = (uint)o0 | ((uint)o1 << 16);
    }
    __syncthreads();

    // gate GEMM, weights from global
    const ushort* wgh = wt5_h + 4 * 16384;
    const ushort* wgl = wt5_l + 4 * 16384;
    f32x4 accG[2][4];
    #pragma unroll
    for (int i = 0; i < 2; ++i)
        #pragma unroll
        for (int j = 0; j < 4; ++j) accG[i][j] = zero4;
    #pragma unroll
    for (int ks = 0; ks < 4; ++ks) {
        bf16x8 afh[2], afl[2], bh[4], bl[4];
        #pragma unroll
        for (int i = 0; i < 2; ++i) {
            afh[i] = *(const bf16x8*)(lAh + (wm * 32 + i * 16 + l15) * 136 + ks * 32 + quad * 8);
            afl[i] = *(const bf16x8*)(lAl + (wm * 32 + i * 16 + l15) * 136 + ks * 32 + quad * 8);
        }
        #pragma unroll
        for (int j = 0; j < 4; ++j) {
            bh[j] = *(const bf16x8*)(wgh + (wn * 64 + j * 16 + l15) * 128 + ks * 32 + quad * 8);
            bl[j] = *(const bf16x8*)(wgl + (wn * 64 + j * 16 + l15) * 128 + ks * 32 + quad * 8);
        }
        #pragma unroll
        for (int i = 0; i < 2; ++i)
            #pragma unroll
            for (int j = 0; j < 4; ++j) {
                accG[i][j] = __builtin_amdgcn_mfma_f32_16x16x32_bf16(afh[i], bh[j], accG[i][j], 0, 0, 0);
                accG[i][j] = __builtin_amdgcn_mfma_f32_16x16x32_bf16(afl[i], bh[j], accG[i][j], 0, 0, 0);
                accG[i][j] = __builtin_amdgcn_mfma_f32_16x16x32_bf16(afh[i], bl[j], accG[i][j], 0, 0, 0);
            }
    }
    #pragma unroll
    for (int i = 0; i < 2; ++i)
        #pragma unroll
        for (int j = 0; j < 4; ++j) {
            int co = wn * 64 + j * 16 + l15;
            float bgv = loadIn(b_g, co, isbf);
            #pragma unroll
            for (int r = 0; r < 4; ++r)
                accG[i][j][r] = sigm(accG[i][j][r] + bgv);
        }
    __syncthreads();

    // phase B: fp32 T ([i][c][j]) -> hi/lo LDS
    {
        int c = tid >> 1, h = tid & 1;
        const float* src = Tf + ((size_t)(p0 >> 9) * 128 + c) * 512 + (p0 & 511) + h * 32;
        float tv[32];
        #pragma unroll
        for (int q8 = 0; q8 < 8; ++q8) {
            float4 f4 = ((const float4*)src)[q8];
            tv[q8 * 4 + 0] = f4.x; tv[q8 * 4 + 1] = f4.y;
            tv[q8 * 4 + 2] = f4.z; tv[q8 * 4 + 3] = f4.w;
        }
        #pragma unroll
        for (int jj = 0; jj < 32; ++jj) {
            ushort hi = f2bf(tv[jj]);
            lAh[(h * 32 + jj) * 136 + c] = hi;
            lAl[(h * 32 + jj) * 136 + c] = f2bf(tv[jj] - bf2f(hi));
        }
    }
    __syncthreads();

    for (int it = 0; it < 16; ++it) {
        int pl = w * 16 + it;
        uint zh = *(const uint*)(lAh + pl * 136 + 2 * lane);
        uint zl = *(const uint*)(lAl + pl * 136 + 2 * lane);
        float x0 = bf2f((ushort)(zh & 0xffff)) + bf2f((ushort)(zl & 0xffff));
        float x1 = bf2f((ushort)(zh >> 16)) + bf2f((ushort)(zl >> 16));
        float s = x0 + x1, s2 = x0 * x0 + x1 * x1;
        #pragma unroll
        for (int m = 32; m >= 1; m >>= 1) { s += __shfl_xor(s, m); s2 += __shfl_xor(s2, m); }
        if (lane == 0) {
            float mean = s * 0.0078125f;
            float var = s2 * 0.0078125f - mean * mean;
            sMean[pl] = mean;
            sRs[pl] = rsqrtf(var + 1e-5f);
        }
    }
    __syncthreads();

    // output GEMM, W' from global
    f32x4 acc[2][4];
    #pragma unroll
    for (int i = 0; i < 2; ++i)
        #pragma unroll
        for (int j = 0; j < 4; ++j) acc[i][j] = zero4;
    #pragma unroll
    for (int ks = 0; ks < 4; ++ks) {
        bf16x8 afh[2], afl[2], bh[4], bl[4];
        #pragma unroll
        for (int i = 0; i < 2; ++i) {
            afh[i] = *(const bf16x8*)(lAh + (wm * 32 + i * 16 + l15) * 136 + ks * 32 + quad * 8);
            afl[i] = *(const bf16x8*)(lAl + (wm * 32 + i * 16 + l15) * 136 + ks * 32 + quad * 8);
        }
        #pragma unroll
        for (int j = 0; j < 4; ++j) {
            bh[j] = *(const bf16x8*)(wzt_h + (wn * 64 + j * 16 + l15) * 128 + ks * 32 + quad * 8);
            bl[j] = *(const bf16x8*)(wzt_l + (wn * 64 + j * 16 + l15) * 128 + ks * 32 + quad * 8);
        }
        #pragma unroll
        for (int i = 0; i < 2; ++i)
            #pragma unroll
            for (int j = 0; j < 4; ++j) {
                acc[i][j] = __builtin_amdgcn_mfma_f32_16x16x32_bf16(afh[i], bh[j], acc[i][j], 0, 0, 0);
                acc[i][j] = __builtin_amdgcn_mfma_f32_16x16x32_bf16(afl[i], bh[j], acc[i][j], 0, 0, 0);
                acc[i][j] = __builtin_amdgcn_mfma_f32_16x16x32_bf16(afh[i], bl[j], acc[i][j], 0, 0, 0);
            }
    }

    ushort* outb = (ushort*)out;
    float*  outf = (float*)out;
    #pragma unroll
    for (int i = 0; i < 2; ++i)
        #pragma unroll
        for (int j = 0; j < 4; ++j) {
            int co = wn * 64 + j * 16 + l15;
            float uj = uvec[co], vj = vvec[co];
            int pb = wm * 32 + i * 16 + quad * 4;
            #pragma unroll
            for (int r = 0; r < 4; ++r) {
                int p = pb + r;
                float pre = sRs[p] * (acc[i][j][r] - sMean[p] * uj) + vj;
                float val = accG[i][j][r] * pre;
                size_t oidx = (size_t)(p0 + p) * 128 + co;
                if (isbf) outb[oidx] = f2bf(val);
                else      outf[oidx] = val;
            }
        }
}

// ---------------------------------------------------------------------------
// stage3C: bf16 T fallback ([i][c][j] layout). Gate 2-term zn split.
// ---------------------------------------------------------------------------
__global__ __launch_bounds__(256, 2)
void stage3c_kernel(const void* __restrict__ z,
                    const void* __restrict__ ln_iw, const void* __restrict__ ln_ib,
                    const ushort* __restrict__ wt5_h, const void* __restrict__ b_g,
                    const ushort* __restrict__ Tb, const ushort* __restrict__ wzt_h,
                    const float* __restrict__ uvec, const float* __restrict__ vvec,
                    const int* __restrict__ dflag, void* __restrict__ out)
{
    __shared__ ushort sm[2 * 64 * 136 + 128 * 136];
    __shared__ float sMean[64], sRs[64];
    ushort* lAh = sm;
    ushort* lAl = sm + 64 * 136;
    ushort* lB  = sm + 2 * 64 * 136;
    const int tid = threadIdx.x, lane = tid & 63, w = tid >> 6;
    const int l15 = lane & 15, quad = lane >> 4;
    const int wm = w >> 1, wn = w & 1;
    const int p0 = blockIdx.x * 64;
    const int isbf = dflag[0];
    const f32x4 zero4 = {0.f, 0.f, 0.f, 0.f};

    float lw0 = loadIn(ln_iw, 2 * lane, isbf), lw1 = loadIn(ln_iw, 2 * lane + 1, isbf);
    float lb0 = loadIn(ln_ib, 2 * lane, isbf), lb1 = loadIn(ln_ib, 2 * lane + 1, isbf);
    for (int it = 0; it < 16; ++it) {
        int pl = w * 16 + it;
        float2 xv = loadIn2(z, (size_t)(p0 + pl) * 128, 2 * lane, isbf);
        float x0 = xv.x, x1 = xv.y;
        float s = x0 + x1, s2 = x0 * x0 + x1 * x1;
        #pragma unroll
        for (int m = 32; m >= 1; m >>= 1) { s += __shfl_xor(s, m); s2 += __shfl_xor(s2, m); }
        float mean = s * 0.0078125f;
        float var = s2 * 0.0078125f - mean * mean;
        float rs = rsqrtf(var + 1e-5f);
        float zn0 = (x0 - mean) * rs * lw0 + lb0;
        float zn1 = (x1 - mean) * rs * lw1 + lb1;
        ushort h0 = f2bf(zn0), h1 = f2bf(zn1);
        ushort o0 = f2bf(zn0 - bf2f(h0)), o1 = f2bf(zn1 - bf2f(h1));
        *(uint*)(lAh + pl * 136 + 2 * lane) = (uint)h0 | ((uint)h1 << 16);
        *(uint*)(lAl + pl * 136 + 2 * lane) = (uint)o0 | ((uint)o1 << 16);
    }
    {
        const ushort* src = wt5_h + 4 * 16384;
        #pragma unroll
        for (int q = 0; q < 8; ++q) {
            int vv = q * 256 + tid;
            int co = vv >> 4, off = vv & 15;
            *(uint4*)(lB + co * 136 + off * 8) = *(const uint4*)(src + co * 128 + off * 8);
        }
    }
    __syncthreads();

    f32x4 accG[2][4];
    #pragma unroll
    for (int i = 0; i < 2; ++i)
        #pragma unroll
        for (int j = 0; j < 4; ++j) accG[i][j] = zero4;
    #pragma unroll
    for (int ks = 0; ks < 4; ++ks) {
        bf16x8 afh[2], afl[2], bfr[4];
        #pragma unroll
        for (int i = 0; i < 2; ++i) {
            afh[i] = *(const bf16x8*)(lAh + (wm * 32 + i * 16 + l15) * 136 + ks * 32 + quad * 8);
            afl[i] = *(const bf16x8*)(lAl + (wm * 32 + i * 16 + l15) * 136 + ks * 32 + quad * 8);
        }
        #pragma unroll
        for (int j = 0; j < 4; ++j)
            bfr[j] = *(const bf16x8*)(lB + (wn * 64 + j * 16 + l15) * 136 + ks * 32 + quad * 8);
        #pragma unroll
        for (int i = 0; i < 2; ++i)
            #pragma unroll
            for (int j = 0; j < 4; ++j) {
                accG[i][j] = __builtin_amdgcn_mfma_f32_16x16x32_bf16(afh[i], bfr[j], accG[i][j], 0, 0, 0);
                accG[i][j] = __builtin_amdgcn_mfma_f32_16x16x32_bf16(afl[i], bfr[j], accG[i][j], 0, 0, 0);
            }
    }
    #pragma unroll
    for (int i = 0; i < 2; ++i)
        #pragma unroll
        for (int j = 0; j < 4; ++j) {
            int co = wn * 64 + j * 16 + l15;
            float bgv = loadIn(b_g, co, isbf);
            #pragma unroll
            for (int r = 0; r < 4; ++r)
                accG[i][j][r] = sigm(accG[i][j][r] + bgv);
        }
    __syncthreads();

    {
        int c = tid >> 1, h = tid & 1;
        const ushort* src = Tb + ((size_t)(p0 >> 9) * 128 + c) * 512 + (p0 & 511) + h * 32;
        union { uint4 q[4]; ushort u[32]; } tmp;
        tmp.q[0] = ((const uint4*)src)[0];
        tmp.q[1] = ((const uint4*)src)[1];
        tmp.q[2] = ((const uint4*)src)[2];
        tmp.q[3] = ((const uint4*)src)[3];
        #pragma unroll
        for (int jj = 0; jj < 32; ++jj)
            lAh[(h * 32 + jj) * 136 + c] = tmp.u[jj];
    }
    #pragma unroll
    for (int q = 0; q < 8; ++q) {
        int vv = q * 256 + tid;
        int co = vv >> 4, off = vv & 15;
        *(uint4*)(lB + co * 136 + off * 8) = *(const uint4*)(wzt_h + co * 128 + off * 8);
    }
    __syncthreads();

    for (int it = 0; it < 16; ++it) {
        int pl = w * 16 + it;
        uint zz = *(const uint*)(lAh + pl * 136 + 2 * lane);
        float x0 = bf2f((ushort)(zz & 0xffff)), x1 = bf2f((ushort)(zz >> 16));
        float s = x0 + x1, s2 = x0 * x0 + x1 * x1;
        #pragma unroll
        for (int m = 32; m >= 1; m >>= 1) { s += __shfl_xor(s, m); s2 += __shfl_xor(s2, m); }
        if (lane == 0) {
            float mean = s * 0.0078125f;
            float var = s2 * 0.0078125f - mean * mean;
            sMean[pl] = mean;
            sRs[pl] = rsqrtf(var + 1e-5f);
        }
    }
    __syncthreads();

    f32x4 acc[2][4];
    #pragma unroll
    for (int i = 0; i < 2; ++i)
        #pragma unroll
        for (int j = 0; j < 4; ++j) acc[i][j] = zero4;
    #pragma unroll
    for (int ks = 0; ks < 4; ++ks) {
        bf16x8 af[2], bfr[4];
        #pragma unroll
        for (int i = 0; i < 2; ++i)
            af[i] = *(const bf16x8*)(lAh + (wm * 32 + i * 16 + l15) * 136 + ks * 32 + quad * 8);
        #pragma unroll
        for (int j = 0; j < 4; ++j)
            bfr[j] = *(const bf16x8*)(lB + (wn * 64 + j * 16 + l15) * 136 + ks * 32 + quad * 8);
        #pragma unroll
        for (int i = 0; i < 2; ++i)
            #pragma unroll
            for (int j = 0; j < 4; ++j)
                acc[i][j] = __builtin_amdgcn_mfma_f32_16x16x32_bf16(af[i], bfr[j], acc[i][j], 0, 0, 0);
    }

    ushort* outb = (ushort*)out;
    float*  outf = (float*)out;
    #pragma unroll
    for (int i = 0; i < 2; ++i)
        #pragma unroll
        for (int j = 0; j < 4; ++j) {
            int co = wn * 64 + j * 16 + l15;
            float uj = uvec[co], vj = vvec[co];
            int pb = wm * 32 + i * 16 + quad * 4;
            #pragma unroll
            for (int r = 0; r < 4; ++r) {
                int p = pb + r;
                float pre = sRs[p] * (acc[i][j][r] - sMean[p] * uj) + vj;
                float val = accG[i][j][r] * pre;
                size_t oidx = (size_t)(p0 + p) * 128 + co;
                if (isbf) outb[oidx] = f2bf(val);
                else      outf[oidx] = val;
            }
        }
}

// ---------------------------------------------------------------------------
extern "C" void kernel_launch(void* const* d_in, const int* in_sizes, int n_in,
                              void* d_out, int out_size, void* d_ws, size_t ws_size,
                              hipStream_t stream)
{
    const void* z     = d_in[0];
    const void* ln_iw = d_in[1];
    const void* ln_ib = d_in[2];
    const void* ln_ow = d_in[3];
    const void* ln_ob = d_in[4];
    const void* w_ap  = d_in[5];
    const void* b_ap  = d_in[6];
    const void* w_ag  = d_in[7];
    const void* b_ag  = d_in[8];
    const void* w_bp  = d_in[9];
    const void* b_bp  = d_in[10];
    const void* w_bg  = d_in[11];
    const void* b_bg  = d_in[12];
    const void* w_g   = d_in[13];
    const void* b_g   = d_in[14];
    const void* w_z   = d_in[15];
    const void* b_z   = d_in[16];

    const size_t MB64 = 67108864;
    const size_t REQ_C = 262144 + 2 * MB64;                    // 134,479,872 (proven-safe)
    const size_t REQ_B = 524288 + MB64 + 2 * MB64;             // 201,850,880
    const size_t REQ_A = REQ_B + MB64;                         // 268,959,744

    char* ws = (char*)d_ws;
    if (ws_size < REQ_C) {
        fill_zero_kernel<<<8192, 256, 0, stream>>>((ushort*)d_out);
        return;
    }

    int tier = (ws_size >= REQ_A) ? 0 : (ws_size >= REQ_B) ? 1 : 2;  // 0=A,1=B,2=C
    if (tier == 0) tier = 1;   // R10: force tier B (single-bf16 A; R11: single-bf16 B too)

    // hi prep area (common offsets)
    ushort* wt5_h = (ushort*)(ws);
    ushort* wzt_h = (ushort*)(ws + 163840);
    float*  uvec  = (float*)(ws + 196608);
    float*  vvec  = (float*)(ws + 197120);
    int*    dflag = (int*)(ws + 198144);
    // lo prep area (tiers A/B)
    ushort* wt5_l = (ushort*)(ws + 262144);
    ushort* wzt_l = (ushort*)(ws + 262144 + 163840);
    int store_lo = (tier <= 1) ? 1 : 0;
    if (tier == 2) { wt5_l = wt5_h; wzt_l = wzt_h; }

    ushort* Ahi; ushort* Alo; void* Tbuf;
    int walo = 0, tfp32 = 0;
    if (tier == 0) {
        Ahi = (ushort*)(ws + 524288);
        Alo = (ushort*)(ws + 524288 + MB64);
        Tbuf = (void*)(ws + 524288 + 2 * MB64);
        walo = 1; tfp32 = 1;
    } else if (tier == 1) {
        Ahi = (ushort*)(ws + 524288);
        Alo = Ahi;
        Tbuf = (void*)(ws + 524288 + MB64);
        walo = 0; tfp32 = 1;
    } else {
        Ahi = (ushort*)(ws + 262144);
        Alo = Ahi;
        Tbuf = (void*)(ws + 262144 + MB64);
        walo = 0; tfp32 = 0;
    }
    ushort* Bhi = (ushort*)d_out;

    detect_kernel<<<1, 64, 0, stream>>>((const uint*)z, dflag);
    prep_kernel<<<7, 256, 0, stream>>>(w_ap, w_ag, w_bp, w_bg, w_g, w_z, ln_ow, ln_ob, b_z,
                                       dflag, wt5_h, wt5_l, wzt_h, wzt_l, uvec, vvec, store_lo);
    stage1_kernel<<<dim3(4096, 2), 256, 0, stream>>>(z, ln_iw, ln_ib, wt5_h,
                                                     b_ap, b_ag, b_bp, b_bg, dflag,
                                                     Ahi, Alo, Bhi, walo);
    stage2_kernel<<<dim3(16, 128), 256, 0, stream>>>(Ahi, Alo, Bhi, dflag, Tbuf, walo, tfp32);
    if (tfp32)
        stage3ab_kernel<<<4096, 256, 0, stream>>>(z, ln_iw, ln_ib, wt5_h, wt5_l, b_g,
                                                  (const float*)Tbuf, wzt_h, wzt_l,
                                                  uvec, vvec, dflag, d_out);
    else
        stage3c_kernel<<<4096, 256, 0, stream>>>(z, ln_iw, ln_ib, wt5_h, b_g,
                                                 (const ushort*)Tbuf, wzt_h,
                                                 uvec, vvec, dflag, d_out);
}

// Round 13
// 768.981 us; speedup vs baseline: 1.1317x; 1.0151x over previous
//
#include <hip/hip_runtime.h>
#include <hip/hip_bf16.h>

// TriangleMultiplication (outgoing), N=512, C=C_Z=128. Inputs/out fp32
// (runtime-detected; bf16 fallback kept). Internal: bf16 MFMA; hi/lo
// splitting retained only for zn (data) in the small GEMMs; T fp32.
//
// R1: weights direct from global. R2 FAILED (LN restructure). R5: occupancy
// changes PASS 867.7. R6 FAILED (fusion spill). R7: XCD swizzle null (kept).
// R8: stage2 K-tile 32: 857.2. R9: T [i][c][j] null (kept).
// R10: drop A-lo: 820.8, absmax unchanged 0.03125.
// R11/R12: drop B-lo: 780.6, absmax unchanged 0.03125.
// R13: (a) stage2 K-tile 64 w/ 2 planes (36864B, (256,3), barriers 16->8,
//      bit-identical T); (b) stage3ab drops weight-lo terms in gate+output
//      GEMMs (2-term each, -1/3 MFMA); store_lo=0.

#define NSEQ 512
#define NPOS 262144

typedef short bf16x8 __attribute__((ext_vector_type(8)));
typedef float f32x4 __attribute__((ext_vector_type(4)));

__device__ __forceinline__ float bf2f(ushort h) {
    union { uint u; float f; } x; x.u = ((uint)h) << 16; return x.f;
}
__device__ __forceinline__ ushort f2bf(float f) {
    union { float f; uint u; } x; x.f = f;
    uint r = x.u + 0x7fffu + ((x.u >> 16) & 1u);
    return (ushort)(r >> 16);
}
__device__ __forceinline__ float sigm(float x) { return 1.f / (1.f + __expf(-x)); }

__device__ __forceinline__ float loadIn(const void* p, size_t idx, int isbf) {
    return isbf ? bf2f(((const ushort*)p)[idx]) : ((const float*)p)[idx];
}
__device__ __forceinline__ float2 loadIn2(const void* p, size_t base, int col2, int isbf) {
    if (isbf) {
        uint zz = *(const uint*)((const ushort*)p + base + col2);
        float2 r; r.x = bf2f((ushort)(zz & 0xffff)); r.y = bf2f((ushort)(zz >> 16)); return r;
    }
    return *(const float2*)((const float*)p + base + col2);
}

// ---------------------------------------------------------------------------
__global__ void detect_kernel(const uint* __restrict__ z32, int* __restrict__ flag)
{
    int t = threadIdx.x;
    int votes = 0;
    #pragma unroll
    for (int i = 0; i < 4; ++i) {
        uint wv = z32[t * 4 + i];
        uint ex = (wv >> 7) & 0xff;
        votes += (ex >= 118 && ex <= 132) ? 1 : 0;
    }
    #pragma unroll
    for (int m = 32; m >= 1; m >>= 1) votes += __shfl_xor(votes, m);
    if (t == 0) flag[0] = (votes >= 128) ? 1 : 0;
}

__global__ void fill_zero_kernel(ushort* __restrict__ out)
{
    size_t i = ((size_t)blockIdx.x * 256 + threadIdx.x) * 16;
    uint4 z4 = {0u, 0u, 0u, 0u};
    *(uint4*)(out + i) = z4;
    *(uint4*)(out + i + 8) = z4;
}

// ---------------------------------------------------------------------------
// prep: wt5_h/_l[g][co][ci] (transposed, hi/lo bf16); wzt_h/_l[co][c] of
// W' = ln_ow*w_z; u,v fp32 affine-fold vectors.
// ---------------------------------------------------------------------------
__global__ void prep_kernel(const void* __restrict__ w_ap, const void* __restrict__ w_ag,
                            const void* __restrict__ w_bp, const void* __restrict__ w_bg,
                            const void* __restrict__ w_g,  const void* __restrict__ w_z,
                            const void* __restrict__ ln_ow, const void* __restrict__ ln_ob,
                            const void* __restrict__ b_z,  const int* __restrict__ dflag,
                            ushort* __restrict__ wt5_h, ushort* __restrict__ wt5_l,
                            ushort* __restrict__ wzt_h, ushort* __restrict__ wzt_l,
                            float* __restrict__ u, float* __restrict__ v, int store_lo)
{
    const int b = blockIdx.x, t = threadIdx.x;
    const int isbf = dflag[0];
    if (b < 5) {
        const void* src = (b == 0) ? w_ap : (b == 1) ? w_ag : (b == 2) ? w_bp : (b == 3) ? w_bg : w_g;
        for (int k = 0; k < 64; ++k) {
            int o = t + k * 256;
            int co = o >> 7, ci = o & 127;
            float wv = loadIn(src, ci * 128 + co, isbf);
            ushort hi = f2bf(wv);
            wt5_h[b * 16384 + o] = hi;
            if (store_lo) wt5_l[b * 16384 + o] = f2bf(wv - bf2f(hi));
        }
    } else if (b == 5) {
        for (int k = 0; k < 64; ++k) {
            int o = t + k * 256;
            int co = o >> 7, c = o & 127;
            float wv = loadIn(ln_ow, c, isbf) * loadIn(w_z, c * 128 + co, isbf);
            ushort hi = f2bf(wv);
            wzt_h[o] = hi;
            if (store_lo) wzt_l[o] = f2bf(wv - bf2f(hi));
        }
    } else {
        if (t < 128) {
            float su = 0.f, sv = 0.f;
            for (int c = 0; c < 128; ++c) {
                float wzv = loadIn(w_z, c * 128 + t, isbf);
                su += loadIn(ln_ow, c, isbf) * wzv;
                sv += loadIn(ln_ob, c, isbf) * wzv;
            }
            u[t] = su;
            v[t] = sv + loadIn(b_z, t, isbf);
        }
    }
}

// ---------------------------------------------------------------------------
// stage1: grid (4096, 2). grp0 -> a (A_hi), grp1 -> b (B_hi in d_out).
// zn kept as hi+lo bf16 in LDS; gate+proj GEMMs fused (shared A-fragment reads),
// weight fragments read directly from global (L2-hot, layout matches).
// tb (output transpose buf) aliases zn LDS after the K-loop (barrier-guarded).
// Outputs channel-major [c][p]. Lo-epilogue gated by walo (always 0 now).
// ---------------------------------------------------------------------------
__global__ __launch_bounds__(256, 4)
void stage1_kernel(const void* __restrict__ z,
                   const void* __restrict__ ln_iw, const void* __restrict__ ln_ib,
                   const ushort* __restrict__ wt5_h,
                   const void* __restrict__ b_ap, const void* __restrict__ b_ag,
                   const void* __restrict__ b_bp, const void* __restrict__ b_bg,
                   const int* __restrict__ dflag,
                   ushort* __restrict__ Ahi, ushort* __restrict__ Alo,
                   ushort* __restrict__ Bhi, int walo)
{
    __shared__ ushort sm[2 * 64 * 136];
    ushort* lAh = sm;                    // [64][136] zn hi
    ushort* lAl = sm + 64 * 136;         // [64][136] zn lo
    const int tid = threadIdx.x, lane = tid & 63, w = tid >> 6;
    const int l15 = lane & 15, quad = lane >> 4;
    const int grp = blockIdx.y;
    const int p0 = blockIdx.x * 64;
    const int isbf = dflag[0];

    float lw0 = loadIn(ln_iw, 2 * lane, isbf), lw1 = loadIn(ln_iw, 2 * lane + 1, isbf);
    float lb0 = loadIn(ln_ib, 2 * lane, isbf), lb1 = loadIn(ln_ib, 2 * lane + 1, isbf);
    for (int it = 0; it < 16; ++it) {
        int pl = w * 16 + it;
        float2 xv = loadIn2(z, (size_t)(p0 + pl) * 128, 2 * lane, isbf);
        float x0 = xv.x, x1 = xv.y;
        float s = x0 + x1, s2 = x0 * x0 + x1 * x1;
        #pragma unroll
        for (int m = 32; m >= 1; m >>= 1) { s += __shfl_xor(s, m); s2 += __shfl_xor(s2, m); }
        float mean = s * 0.0078125f;
        float var = s2 * 0.0078125f - mean * mean;
        float rs = rsqrtf(var + 1e-5f);
        float zn0 = (x0 - mean) * rs * lw0 + lb0;
        float zn1 = (x1 - mean) * rs * lw1 + lb1;
        ushort h0 = f2bf(zn0), h1 = f2bf(zn1);
        ushort o0 = f2bf(zn0 - bf2f(h0)), o1 = f2bf(zn1 - bf2f(h1));
        *(uint*)(lAh + pl * 136 + 2 * lane) = (uint)h0 | ((uint)h1 << 16);
        *(uint*)(lAl + pl * 136 + 2 * lane) = (uint)o0 | ((uint)o1 << 16);
    }
    __syncthreads();

    const ushort* wG = wt5_h + ((grp == 0) ? 1 : 3) * 16384;
    const ushort* wP = wt5_h + ((grp == 0) ? 0 : 2) * 16384;

    const int wm = w >> 1, wn = w & 1;
    const f32x4 zero4 = {0.f, 0.f, 0.f, 0.f};
    f32x4 accG[2][4], accP[2][4];
    #pragma unroll
    for (int i = 0; i < 2; ++i)
        #pragma unroll
        for (int j = 0; j < 4; ++j) { accG[i][j] = zero4; accP[i][j] = zero4; }

    #pragma unroll
    for (int ks = 0; ks < 4; ++ks) {
        bf16x8 afh[2], afl[2];
        #pragma unroll
        for (int i = 0; i < 2; ++i) {
            afh[i] = *(const bf16x8*)(lAh + (wm * 32 + i * 16 + l15) * 136 + ks * 32 + quad * 8);
            afl[i] = *(const bf16x8*)(lAl + (wm * 32 + i * 16 + l15) * 136 + ks * 32 + quad * 8);
        }
        {
            bf16x8 bG[4];
            #pragma unroll
            for (int j = 0; j < 4; ++j)
                bG[j] = *(const bf16x8*)(wG + (wn * 64 + j * 16 + l15) * 128 + ks * 32 + quad * 8);
            #pragma unroll
            for (int i = 0; i < 2; ++i)
                #pragma unroll
                for (int j = 0; j < 4; ++j) {
                    accG[i][j] = __builtin_amdgcn_mfma_f32_16x16x32_bf16(afh[i], bG[j], accG[i][j], 0, 0, 0);
                    accG[i][j] = __builtin_amdgcn_mfma_f32_16x16x32_bf16(afl[i], bG[j], accG[i][j], 0, 0, 0);
                }
        }
        {
            bf16x8 bP[4];
            #pragma unroll
            for (int j = 0; j < 4; ++j)
                bP[j] = *(const bf16x8*)(wP + (wn * 64 + j * 16 + l15) * 128 + ks * 32 + quad * 8);
            #pragma unroll
            for (int i = 0; i < 2; ++i)
                #pragma unroll
                for (int j = 0; j < 4; ++j) {
                    accP[i][j] = __builtin_amdgcn_mfma_f32_16x16x32_bf16(afh[i], bP[j], accP[i][j], 0, 0, 0);
                    accP[i][j] = __builtin_amdgcn_mfma_f32_16x16x32_bf16(afl[i], bP[j], accP[i][j], 0, 0, 0);
                }
        }
    }

    const void* bgp = (grp == 0) ? b_ag : b_bg;
    const void* bpp = (grp == 0) ? b_ap : b_bp;
    float av[2][4][4];
    #pragma unroll
    for (int i = 0; i < 2; ++i)
        #pragma unroll
        for (int j = 0; j < 4; ++j) {
            int co = wn * 64 + j * 16 + l15;
            float gv = loadIn(bgp, co, isbf);
            float pv = loadIn(bpp, co, isbf);
            #pragma unroll
            for (int r = 0; r < 4; ++r)
                av[i][j][r] = sigm(accG[i][j][r] + gv) * (accP[i][j][r] + pv);
        }

    ushort* dst_hi = (grp == 0) ? Ahi : Bhi;
    ushort* dst_lo = (grp == 0) ? Alo : (Bhi + 33554432);
    const int do_lo = walo;

    // tb aliases sm: all MFMA ds_reads are drained by this barrier
    __syncthreads();
    ushort* tb = sm;   // [128][72]
    #pragma unroll
    for (int i = 0; i < 2; ++i)
        #pragma unroll
        for (int j = 0; j < 4; ++j) {
            int co = wn * 64 + j * 16 + l15;
            int pb = wm * 32 + i * 16 + quad * 4;
            uint2 pk;
            pk.x = (uint)f2bf(av[i][j][0]) | ((uint)f2bf(av[i][j][1]) << 16);
            pk.y = (uint)f2bf(av[i][j][2]) | ((uint)f2bf(av[i][j][3]) << 16);
            *(uint2*)(tb + co * 72 + pb) = pk;
        }
    __syncthreads();
    #pragma unroll
    for (int q = 0; q < 4; ++q) {
        int vv = q * 256 + tid;
        int co = vv >> 3, off = vv & 7;
        *(uint4*)(dst_hi + (size_t)co * NPOS + p0 + off * 8) = *(const uint4*)(tb + co * 72 + off * 8);
    }
    if (do_lo) {
        __syncthreads();
        #pragma unroll
        for (int i = 0; i < 2; ++i)
            #pragma unroll
            for (int j = 0; j < 4; ++j) {
                int co = wn * 64 + j * 16 + l15;
                int pb = wm * 32 + i * 16 + quad * 4;
                ushort lo0 = f2bf(av[i][j][0] - bf2f(f2bf(av[i][j][0])));
                ushort lo1 = f2bf(av[i][j][1] - bf2f(f2bf(av[i][j][1])));
                ushort lo2 = f2bf(av[i][j][2] - bf2f(f2bf(av[i][j][2])));
                ushort lo3 = f2bf(av[i][j][3] - bf2f(f2bf(av[i][j][3])));
                uint2 pk;
                pk.x = (uint)lo0 | ((uint)lo1 << 16);
                pk.y = (uint)lo2 | ((uint)lo3 << 16);
                *(uint2*)(tb + co * 72 + pb) = pk;
            }
        __syncthreads();
        #pragma unroll
        for (int q = 0; q < 4; ++q) {
            int vv = q * 256 + tid;
            int co = vv >> 3, off = vv & 7;
            *(uint4*)(dst_lo + (size_t)co * NPOS + p0 + off * 8) = *(const uint4*)(tb + co * 72 + off * 8);
        }
    }
}

// ---------------------------------------------------------------------------
// stage2: grid (16, 128). T_c = A_c * B_c^T, single hi*hi MFMA term.
// R13: K-tile 64 with only 2 LDS planes (36864 B, (256,3)); barriers 16->8.
// Accumulation order over K-slices unchanged -> bit-identical T.
// T written fp32 (tfp32) or bf16 in [i][c][j] layout: idx = (i*128+c)*512+j.
// ---------------------------------------------------------------------------
__global__ __launch_bounds__(256, 3)
void stage2_kernel(const ushort* __restrict__ Ahi, const ushort* __restrict__ Alo,
                   const ushort* __restrict__ Bhi, const int* __restrict__ dflag,
                   void* __restrict__ Tbuf, int alo, int tfp32)
{
    __shared__ ushort sm[2 * 128 * 72];   // 36864 B
    ushort* lAh = sm;
    ushort* lBh = sm + 128 * 72;
    const int tid = threadIdx.x, lane = tid & 63, w = tid >> 6;
    const int l15 = lane & 15, quad = lane >> 4;
    const int wm = w >> 1, wn = w & 1;
    const int bid = blockIdx.y * 16 + blockIdx.x;          // 0..2047
    const int swz = (bid & 7) * 256 + (bid >> 3);          // bijective
    const int c = swz >> 4;
    const int ti = (swz & 15) >> 2, tj = swz & 3;
    const ushort* Aph = Ahi + (size_t)c * NPOS + (size_t)ti * 128 * NSEQ;
    const ushort* Bph = Bhi + (size_t)c * NPOS + (size_t)tj * 128 * NSEQ;
    (void)Alo; (void)alo;

    const f32x4 zero4 = {0.f, 0.f, 0.f, 0.f};
    f32x4 acc[4][4];
    #pragma unroll
    for (int i = 0; i < 4; ++i)
        #pragma unroll
        for (int j = 0; j < 4; ++j) acc[i][j] = zero4;

    for (int kt = 0; kt < 8; ++kt) {
        #pragma unroll
        for (int q = 0; q < 4; ++q) {
            int vv = q * 256 + tid;
            int row = vv >> 3, off = vv & 7;
            *(uint4*)(lAh + row * 72 + off * 8) = *(const uint4*)(Aph + (size_t)row * NSEQ + kt * 64 + off * 8);
            *(uint4*)(lBh + row * 72 + off * 8) = *(const uint4*)(Bph + (size_t)row * NSEQ + kt * 64 + off * 8);
        }
        __syncthreads();
        #pragma unroll
        for (int ks = 0; ks < 2; ++ks) {
            bf16x8 afh[4], bfh[4];
            #pragma unroll
            for (int i = 0; i < 4; ++i)
                afh[i] = *(const bf16x8*)(lAh + (wm * 64 + i * 16 + l15) * 72 + ks * 32 + quad * 8);
            #pragma unroll
            for (int j = 0; j < 4; ++j)
                bfh[j] = *(const bf16x8*)(lBh + (wn * 64 + j * 16 + l15) * 72 + ks * 32 + quad * 8);
            #pragma unroll
            for (int i = 0; i < 4; ++i)
                #pragma unroll
                for (int j = 0; j < 4; ++j)
                    acc[i][j] = __builtin_amdgcn_mfma_f32_16x16x32_bf16(afh[i], bfh[j], acc[i][j], 0, 0, 0);
        }
        __syncthreads();
    }

    // [i][c][j] layout: idx = ((i)*128 + c)*512 + j, i = ti*128+ib+r, j = tj*128+jl
    if (tfp32) {
        float* Tp = (float*)Tbuf + ((size_t)(ti * 128) * 128 + c) * 512 + tj * 128;
        #pragma unroll
        for (int i = 0; i < 4; ++i)
            #pragma unroll
            for (int j = 0; j < 4; ++j) {
                int jl = wn * 64 + j * 16 + l15;
                int ib = wm * 64 + i * 16 + quad * 4;
                #pragma unroll
                for (int r = 0; r < 4; ++r)
                    Tp[(size_t)(ib + r) * 65536 + jl] = acc[i][j][r];
            }
    } else {
        ushort* Tp = (ushort*)Tbuf + ((size_t)(ti * 128) * 128 + c) * 512 + tj * 128;
        #pragma unroll
        for (int i = 0; i < 4; ++i)
            #pragma unroll
            for (int j = 0; j < 4; ++j) {
                int jl = wn * 64 + j * 16 + l15;
                int ib = wm * 64 + i * 16 + quad * 4;
                #pragma unroll
                for (int r = 0; r < 4; ++r)
                    Tp[(size_t)(ib + r) * 65536 + jl] = f2bf(acc[i][j][r]);
            }
    }
}

// ---------------------------------------------------------------------------
// stage3AB: fp32 T ([i][c][j] layout). R13: gate and output GEMMs drop the
// weight-lo term (2-term each: znh*Wh + znl*Wh). LN stats from hi+lo t.
// Weights from global; LDS only for zn/T hi+lo.
// ---------------------------------------------------------------------------
__global__ __launch_bounds__(256, 4)
void stage3ab_kernel(const void* __restrict__ z,
                     const void* __restrict__ ln_iw, const void* __restrict__ ln_ib,
                     const ushort* __restrict__ wt5_h, const ushort* __restrict__ wt5_l,
                     const void* __restrict__ b_g,
                     const float* __restrict__ Tf, const ushort* __restrict__ wzt_h,
                     const ushort* __restrict__ wzt_l,
                     const float* __restrict__ uvec, const float* __restrict__ vvec,
                     const int* __restrict__ dflag, void* __restrict__ out)
{
    __shared__ ushort sm[2 * 64 * 136];
    __shared__ float sMean[64], sRs[64];
    ushort* lAh = sm;
    ushort* lAl = sm + 64 * 136;
    const int tid = threadIdx.x, lane = tid & 63, w = tid >> 6;
    const int l15 = lane & 15, quad = lane >> 4;
    const int wm = w >> 1, wn = w & 1;
    const int p0 = blockIdx.x * 64;
    const int isbf = dflag[0];
    const f32x4 zero4 = {0.f, 0.f, 0.f, 0.f};
    (void)wt5_l; (void)wzt_l;

    // phase A: zn hi/lo
    float lw0 = loadIn(ln_iw, 2 * lane, isbf), lw1 = loadIn(ln_iw, 2 * lane + 1, isbf);
    float lb0 = loadIn(ln_ib, 2 * lane, isbf), lb1 = loadIn(ln_ib, 2 * lane + 1, isbf);
    for (int it = 0; it < 16; ++it) {
        int pl = w * 16 + it;
        float2 xv = loadIn2(z, (size_t)(p0 + pl) * 128, 2 * lane, isbf);
        float x0 = xv.x, x1 = xv.y;
        float s = x0 + x1, s2 = x0 * x0 + x1 * x1;
        #pragma unroll
        for (int m = 32; m >= 1; m >>= 1) { s += __shfl_xor(s, m); s2 += __shfl_xor(s2, m); }
        float mean = s * 0.0078125f;
        float var = s2 * 0.0078125f - mean * mean;
        float rs = rsqrtf(var + 1e-5f);
        float zn0 = (x0 - mean) * rs * lw0 + lb0;
        float zn1 = (x1 - mean) * rs * lw1 + lb1;
        ushort h0 = f2bf(zn0), h1 = f2bf(zn1);
        ushort o0 = f2bf(zn0 - bf2f(h0)), o1 = f2bf(zn1 - bf2f(h1));
        *(uint*)(lAh + pl * 136 + 2 * lane) = (uint)h0 | ((uint)h1 << 16);
        *(uint*)(lAl + pl * 136 + 2 * lane) = (uint)o0 | ((uint)o1 << 16);
    }
    __syncthreads();

    // gate GEMM (2-term), weights from global
    const ushort* wgh = wt5_h + 4 * 16384;
    f32x4 accG[2][4];
    #pragma unroll
    for (int i = 0; i < 2; ++i)
        #pragma unroll
        for (int j = 0; j < 4; ++j) accG[i][j] = zero4;
    #pragma unroll
    for (int ks = 0; ks < 4; ++ks) {
        bf16x8 afh[2], afl[2], bh[4];
        #pragma unroll
        for (int i = 0; i < 2; ++i) {
            afh[i] = *(const bf16x8*)(lAh + (wm * 32 + i * 16 + l15) * 136 + ks * 32 + quad * 8);
            afl[i] = *(const bf16x8*)(lAl + (wm * 32 + i * 16 + l15) * 136 + ks * 32 + quad * 8);
        }
        #pragma unroll
        for (int j = 0; j < 4; ++j)
            bh[j] = *(const bf16x8*)(wgh + (wn * 64 + j * 16 + l15) * 128 + ks * 32 + quad * 8);
        #pragma unroll
        for (int i = 0; i < 2; ++i)
            #pragma unroll
            for (int j = 0; j < 4; ++j) {
                accG[i][j] = __builtin_amdgcn_mfma_f32_16x16x32_bf16(afh[i], bh[j], accG[i][j], 0, 0, 0);
                accG[i][j] = __builtin_amdgcn_mfma_f32_16x16x32_bf16(afl[i], bh[j], accG[i][j], 0, 0, 0);
            }
    }
    #pragma unroll
    for (int i = 0; i < 2; ++i)
        #pragma unroll
        for (int j = 0; j < 4; ++j) {
            int co = wn * 64 + j * 16 + l15;
            float bgv = loadIn(b_g, co, isbf);
            #pragma unroll
            for (int r = 0; r < 4; ++r)
                accG[i][j][r] = sigm(accG[i][j][r] + bgv);
        }
    __syncthreads();

    // phase B: fp32 T ([i][c][j]) -> hi/lo LDS
    {
        int c = tid >> 1, h = tid & 1;
        const float* src = Tf + ((size_t)(p0 >> 9) * 128 + c) * 512 + (p0 & 511) + h * 32;
        float tv[32];
        #pragma unroll
        for (int q8 = 0; q8 < 8; ++q8) {
            float4 f4 = ((const float4*)src)[q8];
            tv[q8 * 4 + 0] = f4.x; tv[q8 * 4 + 1] = f4.y;
            tv[q8 * 4 + 2] = f4.z; tv[q8 * 4 + 3] = f4.w;
        }
        #pragma unroll
        for (int jj = 0; jj < 32; ++jj) {
            ushort hi = f2bf(tv[jj]);
            lAh[(h * 32 + jj) * 136 + c] = hi;
            lAl[(h * 32 + jj) * 136 + c] = f2bf(tv[jj] - bf2f(hi));
        }
    }
    __syncthreads();

    for (int it = 0; it < 16; ++it) {
        int pl = w * 16 + it;
        uint zh = *(const uint*)(lAh + pl * 136 + 2 * lane);
        uint zl = *(const uint*)(lAl + pl * 136 + 2 * lane);
        float x0 = bf2f((ushort)(zh & 0xffff)) + bf2f((ushort)(zl & 0xffff));
        float x1 = bf2f((ushort)(zh >> 16)) + bf2f((ushort)(zl >> 16));
        float s = x0 + x1, s2 = x0 * x0 + x1 * x1;
        #pragma unroll
        for (int m = 32; m >= 1; m >>= 1) { s += __shfl_xor(s, m); s2 += __shfl_xor(s2, m); }
        if (lane == 0) {
            float mean = s * 0.0078125f;
            float var = s2 * 0.0078125f - mean * mean;
            sMean[pl] = mean;
            sRs[pl] = rsqrtf(var + 1e-5f);
        }
    }
    __syncthreads();

    // output GEMM (2-term), W'hi from global
    f32x4 acc[2][4];
    #pragma unroll
    for (int i = 0; i < 2; ++i)
        #pragma unroll
        for (int j = 0; j < 4; ++j) acc[i][j] = zero4;
    #pragma unroll
    for (int ks = 0; ks < 4; ++ks) {
        bf16x8 afh[2], afl[2], bh[4];
        #pragma unroll
        for (int i = 0; i < 2; ++i) {
            afh[i] = *(const bf16x8*)(lAh + (wm * 32 + i * 16 + l15) * 136 + ks * 32 + quad * 8);
            afl[i] = *(const bf16x8*)(lAl + (wm * 32 + i * 16 + l15) * 136 + ks * 32 + quad * 8);
        }
        #pragma unroll
        for (int j = 0; j < 4; ++j)
            bh[j] = *(const bf16x8*)(wzt_h + (wn * 64 + j * 16 + l15) * 128 + ks * 32 + quad * 8);
        #pragma unroll
        for (int i = 0; i < 2; ++i)
            #pragma unroll
            for (int j = 0; j < 4; ++j) {
                acc[i][j] = __builtin_amdgcn_mfma_f32_16x16x32_bf16(afh[i], bh[j], acc[i][j], 0, 0, 0);
                acc[i][j] = __builtin_amdgcn_mfma_f32_16x16x32_bf16(afl[i], bh[j], acc[i][j], 0, 0, 0);
            }
    }

    ushort* outb = (ushort*)out;
    float*  outf = (float*)out;
    #pragma unroll
    for (int i = 0; i < 2; ++i)
        #pragma unroll
        for (int j = 0; j < 4; ++j) {
            int co = wn * 64 + j * 16 + l15;
            float uj = uvec[co], vj = vvec[co];
            int pb = wm * 32 + i * 16 + quad * 4;
            #pragma unroll
            for (int r = 0; r < 4; ++r) {
                int p = pb + r;
                float pre = sRs[p] * (acc[i][j][r] - sMean[p] * uj) + vj;
                float val = accG[i][j][r] * pre;
                size_t oidx = (size_t)(p0 + p) * 128 + co;
                if (isbf) outb[oidx] = f2bf(val);
                else      outf[oidx] = val;
            }
        }
}

// ---------------------------------------------------------------------------
// stage3C: bf16 T fallback ([i][c][j] layout). Gate 2-term zn split.
// ---------------------------------------------------------------------------
__global__ __launch_bounds__(256, 2)
void stage3c_kernel(const void* __restrict__ z,
                    const void* __restrict__ ln_iw, const void* __restrict__ ln_ib,
                    const ushort* __restrict__ wt5_h, const void* __restrict__ b_g,
                    const ushort* __restrict__ Tb, const ushort* __restrict__ wzt_h,
                    const float* __restrict__ uvec, const float* __restrict__ vvec,
                    const int* __restrict__ dflag, void* __restrict__ out)
{
    __shared__ ushort sm[2 * 64 * 136 + 128 * 136];
    __shared__ float sMean[64], sRs[64];
    ushort* lAh = sm;
    ushort* lAl = sm + 64 * 136;
    ushort* lB  = sm + 2 * 64 * 136;
    const int tid = threadIdx.x, lane = tid & 63, w = tid >> 6;
    const int l15 = lane & 15, quad = lane >> 4;
    const int wm = w >> 1, wn = w & 1;
    const int p0 = blockIdx.x * 64;
    const int isbf = dflag[0];
    const f32x4 zero4 = {0.f, 0.f, 0.f, 0.f};

    float lw0 = loadIn(ln_iw, 2 * lane, isbf), lw1 = loadIn(ln_iw, 2 * lane + 1, isbf);
    float lb0 = loadIn(ln_ib, 2 * lane, isbf), lb1 = loadIn(ln_ib, 2 * lane + 1, isbf);
    for (int it = 0; it < 16; ++it) {
        int pl = w * 16 + it;
        float2 xv = loadIn2(z, (size_t)(p0 + pl) * 128, 2 * lane, isbf);
        float x0 = xv.x, x1 = xv.y;
        float s = x0 + x1, s2 = x0 * x0 + x1 * x1;
        #pragma unroll
        for (int m = 32; m >= 1; m >>= 1) { s += __shfl_xor(s, m); s2 += __shfl_xor(s2, m); }
        float mean = s * 0.0078125f;
        float var = s2 * 0.0078125f - mean * mean;
        float rs = rsqrtf(var + 1e-5f);
        float zn0 = (x0 - mean) * rs * lw0 + lb0;
        float zn1 = (x1 - mean) * rs * lw1 + lb1;
        ushort h0 = f2bf(zn0), h1 = f2bf(zn1);
        ushort o0 = f2bf(zn0 - bf2f(h0)), o1 = f2bf(zn1 - bf2f(h1));
        *(uint*)(lAh + pl * 136 + 2 * lane) = (uint)h0 | ((uint)h1 << 16);
        *(uint*)(lAl + pl * 136 + 2 * lane) = (uint)o0 | ((uint)o1 << 16);
    }
    {
        const ushort* src = wt5_h + 4 * 16384;
        #pragma unroll
        for (int q = 0; q < 8; ++q) {
            int vv = q * 256 + tid;
            int co = vv >> 4, off = vv & 15;
            *(uint4*)(lB + co * 136 + off * 8) = *(const uint4*)(src + co * 128 + off * 8);
        }
    }
    __syncthreads();

    f32x4 accG[2][4];
    #pragma unroll
    for (int i = 0; i < 2; ++i)
        #pragma unroll
        for (int j = 0; j < 4; ++j) accG[i][j] = zero4;
    #pragma unroll
    for (int ks = 0; ks < 4; ++ks) {
        bf16x8 afh[2], afl[2], bfr[4];
        #pragma unroll
        for (int i = 0; i < 2; ++i) {
            afh[i] = *(const bf16x8*)(lAh + (wm * 32 + i * 16 + l15) * 136 + ks * 32 + quad * 8);
            afl[i] = *(const bf16x8*)(lAl + (wm * 32 + i * 16 + l15) * 136 + ks * 32 + quad * 8);
        }
        #pragma unroll
        for (int j = 0; j < 4; ++j)
            bfr[j] = *(const bf16x8*)(lB + (wn * 64 + j * 16 + l15) * 136 + ks * 32 + quad * 8);
        #pragma unroll
        for (int i = 0; i < 2; ++i)
            #pragma unroll
            for (int j = 0; j < 4; ++j) {
                accG[i][j] = __builtin_amdgcn_mfma_f32_16x16x32_bf16(afh[i], bfr[j], accG[i][j], 0, 0, 0);
                accG[i][j] = __builtin_amdgcn_mfma_f32_16x16x32_bf16(afl[i], bfr[j], accG[i][j], 0, 0, 0);
            }
    }
    #pragma unroll
    for (int i = 0; i < 2; ++i)
        #pragma unroll
        for (int j = 0; j < 4; ++j) {
            int co = wn * 64 + j * 16 + l15;
            float bgv = loadIn(b_g, co, isbf);
            #pragma unroll
            for (int r = 0; r < 4; ++r)
                accG[i][j][r] = sigm(accG[i][j][r] + bgv);
        }
    __syncthreads();

    {
        int c = tid >> 1, h = tid & 1;
        const ushort* src = Tb + ((size_t)(p0 >> 9) * 128 + c) * 512 + (p0 & 511) + h * 32;
        union { uint4 q[4]; ushort u[32]; } tmp;
        tmp.q[0] = ((const uint4*)src)[0];
        tmp.q[1] = ((const uint4*)src)[1];
        tmp.q[2] = ((const uint4*)src)[2];
        tmp.q[3] = ((const uint4*)src)[3];
        #pragma unroll
        for (int jj = 0; jj < 32; ++jj)
            lAh[(h * 32 + jj) * 136 + c] = tmp.u[jj];
    }
    #pragma unroll
    for (int q = 0; q < 8; ++q) {
        int vv = q * 256 + tid;
        int co = vv >> 4, off = vv & 15;
        *(uint4*)(lB + co * 136 + off * 8) = *(const uint4*)(wzt_h + co * 128 + off * 8);
    }
    __syncthreads();

    for (int it = 0; it < 16; ++it) {
        int pl = w * 16 + it;
        uint zz = *(const uint*)(lAh + pl * 136 + 2 * lane);
        float x0 = bf2f((ushort)(zz & 0xffff)), x1 = bf2f((ushort)(zz >> 16));
        float s = x0 + x1, s2 = x0 * x0 + x1 * x1;
        #pragma unroll
        for (int m = 32; m >= 1; m >>= 1) { s += __shfl_xor(s, m); s2 += __shfl_xor(s2, m); }
        if (lane == 0) {
            float mean = s * 0.0078125f;
            float var = s2 * 0.0078125f - mean * mean;
            sMean[pl] = mean;
            sRs[pl] = rsqrtf(var + 1e-5f);
        }
    }
    __syncthreads();

    f32x4 acc[2][4];
    #pragma unroll
    for (int i = 0; i < 2; ++i)
        #pragma unroll
        for (int j = 0; j < 4; ++j) acc[i][j] = zero4;
    #pragma unroll
    for (int ks = 0; ks < 4; ++ks) {
        bf16x8 af[2], bfr[4];
        #pragma unroll
        for (int i = 0; i < 2; ++i)
            af[i] = *(const bf16x8*)(lAh + (wm * 32 + i * 16 + l15) * 136 + ks * 32 + quad * 8);
        #pragma unroll
        for (int j = 0; j < 4; ++j)
            bfr[j] = *(const bf16x8*)(lB + (wn * 64 + j * 16 + l15) * 136 + ks * 32 + quad * 8);
        #pragma unroll
        for (int i = 0; i < 2; ++i)
            #pragma unroll
            for (int j = 0; j < 4; ++j)
                acc[i][j] = __builtin_amdgcn_mfma_f32_16x16x32_bf16(af[i], bfr[j], acc[i][j], 0, 0, 0);
    }

    ushort* outb = (ushort*)out;
    float*  outf = (float*)out;
    #pragma unroll
    for (int i = 0; i < 2; ++i)
        #pragma unroll
        for (int j = 0; j < 4; ++j) {
            int co = wn * 64 + j * 16 + l15;
            float uj = uvec[co], vj = vvec[co];
            int pb = wm * 32 + i * 16 + quad * 4;
            #pragma unroll
            for (int r = 0; r < 4; ++r) {
                int p = pb + r;
                float pre = sRs[p] * (acc[i][j][r] - sMean[p] * uj) + vj;
                float val = accG[i][j][r] * pre;
                size_t oidx = (size_t)(p0 + p) * 128 + co;
                if (isbf) outb[oidx] = f2bf(val);
                else      outf[oidx] = val;
            }
        }
}

// ---------------------------------------------------------------------------
extern "C" void kernel_launch(void* const* d_in, const int* in_sizes, int n_in,
                              void* d_out, int out_size, void* d_ws, size_t ws_size,
                              hipStream_t stream)
{
    const void* z     = d_in[0];
    const void* ln_iw = d_in[1];
    const void* ln_ib = d_in[2];
    const void* ln_ow = d_in[3];
    const void* ln_ob = d_in[4];
    const void* w_ap  = d_in[5];
    const void* b_ap  = d_in[6];
    const void* w_ag  = d_in[7];
    const void* b_ag  = d_in[8];
    const void* w_bp  = d_in[9];
    const void* b_bp  = d_in[10];
    const void* w_bg  = d_in[11];
    const void* b_bg  = d_in[12];
    const void* w_g   = d_in[13];
    const void* b_g   = d_in[14];
    const void* w_z   = d_in[15];
    const void* b_z   = d_in[16];

    const size_t MB64 = 67108864;
    const size_t REQ_C = 262144 + 2 * MB64;                    // 134,479,872 (proven-safe)
    const size_t REQ_B = 524288 + MB64 + 2 * MB64;             // 201,850,880
    const size_t REQ_A = REQ_B + MB64;                         // 268,959,744

    char* ws = (char*)d_ws;
    if (ws_size < REQ_C) {
        fill_zero_kernel<<<8192, 256, 0, stream>>>((ushort*)d_out);
        return;
    }

    int tier = (ws_size >= REQ_A) ? 0 : (ws_size >= REQ_B) ? 1 : 2;  // 0=A,1=B,2=C
    if (tier == 0) tier = 1;   // forced tier B (single-bf16 A and B planes)

    // hi prep area (common offsets)
    ushort* wt5_h = (ushort*)(ws);
    ushort* wzt_h = (ushort*)(ws + 163840);
    float*  uvec  = (float*)(ws + 196608);
    float*  vvec  = (float*)(ws + 197120);
    int*    dflag = (int*)(ws + 198144);
    // lo prep area (unused since R13: weight-lo terms dropped everywhere)
    ushort* wt5_l = (ushort*)(ws + 262144);
    ushort* wzt_l = (ushort*)(ws + 262144 + 163840);
    int store_lo = 0;   // R13: no consumer of weight-lo planes remains
    if (tier == 2) { wt5_l = wt5_h; wzt_l = wzt_h; }

    ushort* Ahi; ushort* Alo; void* Tbuf;
    int walo = 0, tfp32 = 0;
    if (tier == 1) {
        Ahi = (ushort*)(ws + 524288);
        Alo = Ahi;
        Tbuf = (void*)(ws + 524288 + MB64);
        walo = 0; tfp32 = 1;
    } else {
        Ahi = (ushort*)(ws + 262144);
        Alo = Ahi;
        Tbuf = (void*)(ws + 262144 + MB64);
        walo = 0; tfp32 = 0;
    }
    ushort* Bhi = (ushort*)d_out;

    detect_kernel<<<1, 64, 0, stream>>>((const uint*)z, dflag);
    prep_kernel<<<7, 256, 0, stream>>>(w_ap, w_ag, w_bp, w_bg, w_g, w_z, ln_ow, ln_ob, b_z,
                                       dflag, wt5_h, wt5_l, wzt_h, wzt_l, uvec, vvec, store_lo);
    stage1_kernel<<<dim3(4096, 2), 256, 0, stream>>>(z, ln_iw, ln_ib, wt5_h,
                                                     b_ap, b_ag, b_bp, b_bg, dflag,
                                                     Ahi, Alo, Bhi, walo);
    stage2_kernel<<<dim3(16, 128), 256, 0, stream>>>(Ahi, Alo, Bhi, dflag, Tbuf, walo, tfp32);
    if (tfp32)
        stage3ab_kernel<<<4096, 256, 0, stream>>>(z, ln_iw, ln_ib, wt5_h, wt5_l, b_g,
                                                  (const float*)Tbuf, wzt_h, wzt_l,
                                                  uvec, vvec, dflag, d_out);
    else
        stage3c_kernel<<<4096, 256, 0, stream>>>(z, ln_iw, ln_ib, wt5_h, b_g,
                                                 (const ushort*)Tbuf, wzt_h,
                                                 uvec, vvec, dflag, d_out);
}

// Round 14
// 759.499 us; speedup vs baseline: 1.1458x; 1.0125x over previous
//
#include <hip/hip_runtime.h>
#include <hip/hip_bf16.h>

// TriangleMultiplication (outgoing), N=512, C=C_Z=128. Inputs/out fp32
// (runtime-detected; bf16 fallback kept). Internal: bf16 MFMA; hi/lo
// splitting retained only for zn (data) in the small GEMMs; T fp32.
//
// R5: occupancy changes 867.7. R6 FAILED: parallel-group fusion spilled
//     av[64] (both groups live). R7 swizzle null (kept). R8 K-tile 32.
// R9: T [i][c][j] null (kept). R10: drop A-lo 820.8 (absmax unchanged).
// R11/R12: drop B-lo 780.6 (absmax unchanged). R13: stage2 K-tile 64 2-plane
//     + stage3ab 2-term GEMMs: 769.0 (absmax unchanged 0.03125).
// R14: stage1 SEQUENTIAL-group fusion (grid 4096x2 -> 4096): LN computed
//     once; g=0 GEMM+epilogue+store fully completes before g=1 (only ONE
//     group's av/acc live at a time -> no R6 spill). tb separate buffer
//     (zn survives into g=1). LDS 53248, (256,3). #pragma unroll 1 on g.

#define NSEQ 512
#define NPOS 262144

typedef short bf16x8 __attribute__((ext_vector_type(8)));
typedef float f32x4 __attribute__((ext_vector_type(4)));

__device__ __forceinline__ float bf2f(ushort h) {
    union { uint u; float f; } x; x.u = ((uint)h) << 16; return x.f;
}
__device__ __forceinline__ ushort f2bf(float f) {
    union { float f; uint u; } x; x.f = f;
    uint r = x.u + 0x7fffu + ((x.u >> 16) & 1u);
    return (ushort)(r >> 16);
}
__device__ __forceinline__ float sigm(float x) { return 1.f / (1.f + __expf(-x)); }

__device__ __forceinline__ float loadIn(const void* p, size_t idx, int isbf) {
    return isbf ? bf2f(((const ushort*)p)[idx]) : ((const float*)p)[idx];
}
__device__ __forceinline__ float2 loadIn2(const void* p, size_t base, int col2, int isbf) {
    if (isbf) {
        uint zz = *(const uint*)((const ushort*)p + base + col2);
        float2 r; r.x = bf2f((ushort)(zz & 0xffff)); r.y = bf2f((ushort)(zz >> 16)); return r;
    }
    return *(const float2*)((const float*)p + base + col2);
}

// ---------------------------------------------------------------------------
__global__ void detect_kernel(const uint* __restrict__ z32, int* __restrict__ flag)
{
    int t = threadIdx.x;
    int votes = 0;
    #pragma unroll
    for (int i = 0; i < 4; ++i) {
        uint wv = z32[t * 4 + i];
        uint ex = (wv >> 7) & 0xff;
        votes += (ex >= 118 && ex <= 132) ? 1 : 0;
    }
    #pragma unroll
    for (int m = 32; m >= 1; m >>= 1) votes += __shfl_xor(votes, m);
    if (t == 0) flag[0] = (votes >= 128) ? 1 : 0;
}

__global__ void fill_zero_kernel(ushort* __restrict__ out)
{
    size_t i = ((size_t)blockIdx.x * 256 + threadIdx.x) * 16;
    uint4 z4 = {0u, 0u, 0u, 0u};
    *(uint4*)(out + i) = z4;
    *(uint4*)(out + i + 8) = z4;
}

// ---------------------------------------------------------------------------
// prep: wt5_h/_l[g][co][ci] (transposed, hi/lo bf16); wzt_h/_l[co][c] of
// W' = ln_ow*w_z; u,v fp32 affine-fold vectors.
// ---------------------------------------------------------------------------
__global__ void prep_kernel(const void* __restrict__ w_ap, const void* __restrict__ w_ag,
                            const void* __restrict__ w_bp, const void* __restrict__ w_bg,
                            const void* __restrict__ w_g,  const void* __restrict__ w_z,
                            const void* __restrict__ ln_ow, const void* __restrict__ ln_ob,
                            const void* __restrict__ b_z,  const int* __restrict__ dflag,
                            ushort* __restrict__ wt5_h, ushort* __restrict__ wt5_l,
                            ushort* __restrict__ wzt_h, ushort* __restrict__ wzt_l,
                            float* __restrict__ u, float* __restrict__ v, int store_lo)
{
    const int b = blockIdx.x, t = threadIdx.x;
    const int isbf = dflag[0];
    if (b < 5) {
        const void* src = (b == 0) ? w_ap : (b == 1) ? w_ag : (b == 2) ? w_bp : (b == 3) ? w_bg : w_g;
        for (int k = 0; k < 64; ++k) {
            int o = t + k * 256;
            int co = o >> 7, ci = o & 127;
            float wv = loadIn(src, ci * 128 + co, isbf);
            ushort hi = f2bf(wv);
            wt5_h[b * 16384 + o] = hi;
            if (store_lo) wt5_l[b * 16384 + o] = f2bf(wv - bf2f(hi));
        }
    } else if (b == 5) {
        for (int k = 0; k < 64; ++k) {
            int o = t + k * 256;
            int co = o >> 7, c = o & 127;
            float wv = loadIn(ln_ow, c, isbf) * loadIn(w_z, c * 128 + co, isbf);
            ushort hi = f2bf(wv);
            wzt_h[o] = hi;
            if (store_lo) wzt_l[o] = f2bf(wv - bf2f(hi));
        }
    } else {
        if (t < 128) {
            float su = 0.f, sv = 0.f;
            for (int c = 0; c < 128; ++c) {
                float wzv = loadIn(w_z, c * 128 + t, isbf);
                su += loadIn(ln_ow, c, isbf) * wzv;
                sv += loadIn(ln_ob, c, isbf) * wzv;
            }
            u[t] = su;
            v[t] = sv + loadIn(b_z, t, isbf);
        }
    }
}

// ---------------------------------------------------------------------------
// stage1: grid (4096). LN ONCE, then sequential loop over both groups:
// g0 -> a (A_hi), g1 -> b (B_hi in d_out). zn hi+lo bf16 in LDS (persists
// across both GEMMs); tb is a SEPARATE transpose buffer. Weight fragments
// read directly from global. Outputs channel-major [c][p].
// ---------------------------------------------------------------------------
__global__ __launch_bounds__(256, 3)
void stage1_kernel(const void* __restrict__ z,
                   const void* __restrict__ ln_iw, const void* __restrict__ ln_ib,
                   const ushort* __restrict__ wt5_h,
                   const void* __restrict__ b_ap, const void* __restrict__ b_ag,
                   const void* __restrict__ b_bp, const void* __restrict__ b_bg,
                   const int* __restrict__ dflag,
                   ushort* __restrict__ Ahi, ushort* __restrict__ Alo,
                   ushort* __restrict__ Bhi, int walo)
{
    __shared__ ushort sm[2 * 64 * 136 + 128 * 72];
    ushort* lAh = sm;                    // [64][136] zn hi
    ushort* lAl = sm + 64 * 136;         // [64][136] zn lo
    ushort* tb  = sm + 2 * 64 * 136;     // [128][72] transpose buf (separate)
    const int tid = threadIdx.x, lane = tid & 63, w = tid >> 6;
    const int l15 = lane & 15, quad = lane >> 4;
    const int p0 = blockIdx.x * 64;
    const int isbf = dflag[0];
    (void)Alo; (void)walo;

    float lw0 = loadIn(ln_iw, 2 * lane, isbf), lw1 = loadIn(ln_iw, 2 * lane + 1, isbf);
    float lb0 = loadIn(ln_ib, 2 * lane, isbf), lb1 = loadIn(ln_ib, 2 * lane + 1, isbf);
    for (int it = 0; it < 16; ++it) {
        int pl = w * 16 + it;
        float2 xv = loadIn2(z, (size_t)(p0 + pl) * 128, 2 * lane, isbf);
        float x0 = xv.x, x1 = xv.y;
        float s = x0 + x1, s2 = x0 * x0 + x1 * x1;
        #pragma unroll
        for (int m = 32; m >= 1; m >>= 1) { s += __shfl_xor(s, m); s2 += __shfl_xor(s2, m); }
        float mean = s * 0.0078125f;
        float var = s2 * 0.0078125f - mean * mean;
        float rs = rsqrtf(var + 1e-5f);
        float zn0 = (x0 - mean) * rs * lw0 + lb0;
        float zn1 = (x1 - mean) * rs * lw1 + lb1;
        ushort h0 = f2bf(zn0), h1 = f2bf(zn1);
        ushort o0 = f2bf(zn0 - bf2f(h0)), o1 = f2bf(zn1 - bf2f(h1));
        *(uint*)(lAh + pl * 136 + 2 * lane) = (uint)h0 | ((uint)h1 << 16);
        *(uint*)(lAl + pl * 136 + 2 * lane) = (uint)o0 | ((uint)o1 << 16);
    }
    __syncthreads();

    const int wm = w >> 1, wn = w & 1;
    const f32x4 zero4 = {0.f, 0.f, 0.f, 0.f};

    #pragma unroll 1
    for (int g = 0; g < 2; ++g) {
        const ushort* wG = wt5_h + ((g == 0) ? 1 : 3) * 16384;
        const ushort* wP = wt5_h + ((g == 0) ? 0 : 2) * 16384;

        f32x4 accG[2][4], accP[2][4];
        #pragma unroll
        for (int i = 0; i < 2; ++i)
            #pragma unroll
            for (int j = 0; j < 4; ++j) { accG[i][j] = zero4; accP[i][j] = zero4; }

        #pragma unroll
        for (int ks = 0; ks < 4; ++ks) {
            bf16x8 afh[2], afl[2];
            #pragma unroll
            for (int i = 0; i < 2; ++i) {
                afh[i] = *(const bf16x8*)(lAh + (wm * 32 + i * 16 + l15) * 136 + ks * 32 + quad * 8);
                afl[i] = *(const bf16x8*)(lAl + (wm * 32 + i * 16 + l15) * 136 + ks * 32 + quad * 8);
            }
            {
                bf16x8 bG[4];
                #pragma unroll
                for (int j = 0; j < 4; ++j)
                    bG[j] = *(const bf16x8*)(wG + (wn * 64 + j * 16 + l15) * 128 + ks * 32 + quad * 8);
                #pragma unroll
                for (int i = 0; i < 2; ++i)
                    #pragma unroll
                    for (int j = 0; j < 4; ++j) {
                        accG[i][j] = __builtin_amdgcn_mfma_f32_16x16x32_bf16(afh[i], bG[j], accG[i][j], 0, 0, 0);
                        accG[i][j] = __builtin_amdgcn_mfma_f32_16x16x32_bf16(afl[i], bG[j], accG[i][j], 0, 0, 0);
                    }
            }
            {
                bf16x8 bP[4];
                #pragma unroll
                for (int j = 0; j < 4; ++j)
                    bP[j] = *(const bf16x8*)(wP + (wn * 64 + j * 16 + l15) * 128 + ks * 32 + quad * 8);
                #pragma unroll
                for (int i = 0; i < 2; ++i)
                    #pragma unroll
                    for (int j = 0; j < 4; ++j) {
                        accP[i][j] = __builtin_amdgcn_mfma_f32_16x16x32_bf16(afh[i], bP[j], accP[i][j], 0, 0, 0);
                        accP[i][j] = __builtin_amdgcn_mfma_f32_16x16x32_bf16(afl[i], bP[j], accP[i][j], 0, 0, 0);
                    }
            }
        }

        const void* bgp = (g == 0) ? b_ag : b_bg;
        const void* bpp = (g == 0) ? b_ap : b_bp;
        float av[2][4][4];
        #pragma unroll
        for (int i = 0; i < 2; ++i)
            #pragma unroll
            for (int j = 0; j < 4; ++j) {
                int co = wn * 64 + j * 16 + l15;
                float gv = loadIn(bgp, co, isbf);
                float pv = loadIn(bpp, co, isbf);
                #pragma unroll
                for (int r = 0; r < 4; ++r)
                    av[i][j][r] = sigm(accG[i][j][r] + gv) * (accP[i][j][r] + pv);
            }

        ushort* dst_hi = (g == 0) ? Ahi : Bhi;

        __syncthreads();   // g=0: no-op guard; g=1: prior store's tb reads done
        #pragma unroll
        for (int i = 0; i < 2; ++i)
            #pragma unroll
            for (int j = 0; j < 4; ++j) {
                int co = wn * 64 + j * 16 + l15;
                int pb = wm * 32 + i * 16 + quad * 4;
                uint2 pk;
                pk.x = (uint)f2bf(av[i][j][0]) | ((uint)f2bf(av[i][j][1]) << 16);
                pk.y = (uint)f2bf(av[i][j][2]) | ((uint)f2bf(av[i][j][3]) << 16);
                *(uint2*)(tb + co * 72 + pb) = pk;
            }
        __syncthreads();
        #pragma unroll
        for (int q = 0; q < 4; ++q) {
            int vv = q * 256 + tid;
            int co = vv >> 3, off = vv & 7;
            *(uint4*)(dst_hi + (size_t)co * NPOS + p0 + off * 8) = *(const uint4*)(tb + co * 72 + off * 8);
        }
    }
}

// ---------------------------------------------------------------------------
// stage2: grid (16, 128). T_c = A_c * B_c^T, single hi*hi MFMA term.
// K-tile 64, 2 LDS planes (36864 B, (256,3)); 8 barrier pairs.
// T written fp32 (tfp32) or bf16 in [i][c][j] layout: idx = (i*128+c)*512+j.
// ---------------------------------------------------------------------------
__global__ __launch_bounds__(256, 3)
void stage2_kernel(const ushort* __restrict__ Ahi, const ushort* __restrict__ Alo,
                   const ushort* __restrict__ Bhi, const int* __restrict__ dflag,
                   void* __restrict__ Tbuf, int alo, int tfp32)
{
    __shared__ ushort sm[2 * 128 * 72];   // 36864 B
    ushort* lAh = sm;
    ushort* lBh = sm + 128 * 72;
    const int tid = threadIdx.x, lane = tid & 63, w = tid >> 6;
    const int l15 = lane & 15, quad = lane >> 4;
    const int wm = w >> 1, wn = w & 1;
    const int bid = blockIdx.y * 16 + blockIdx.x;          // 0..2047
    const int swz = (bid & 7) * 256 + (bid >> 3);          // bijective
    const int c = swz >> 4;
    const int ti = (swz & 15) >> 2, tj = swz & 3;
    const ushort* Aph = Ahi + (size_t)c * NPOS + (size_t)ti * 128 * NSEQ;
    const ushort* Bph = Bhi + (size_t)c * NPOS + (size_t)tj * 128 * NSEQ;
    (void)Alo; (void)alo;

    const f32x4 zero4 = {0.f, 0.f, 0.f, 0.f};
    f32x4 acc[4][4];
    #pragma unroll
    for (int i = 0; i < 4; ++i)
        #pragma unroll
        for (int j = 0; j < 4; ++j) acc[i][j] = zero4;

    for (int kt = 0; kt < 8; ++kt) {
        #pragma unroll
        for (int q = 0; q < 4; ++q) {
            int vv = q * 256 + tid;
            int row = vv >> 3, off = vv & 7;
            *(uint4*)(lAh + row * 72 + off * 8) = *(const uint4*)(Aph + (size_t)row * NSEQ + kt * 64 + off * 8);
            *(uint4*)(lBh + row * 72 + off * 8) = *(const uint4*)(Bph + (size_t)row * NSEQ + kt * 64 + off * 8);
        }
        __syncthreads();
        #pragma unroll
        for (int ks = 0; ks < 2; ++ks) {
            bf16x8 afh[4], bfh[4];
            #pragma unroll
            for (int i = 0; i < 4; ++i)
                afh[i] = *(const bf16x8*)(lAh + (wm * 64 + i * 16 + l15) * 72 + ks * 32 + quad * 8);
            #pragma unroll
            for (int j = 0; j < 4; ++j)
                bfh[j] = *(const bf16x8*)(lBh + (wn * 64 + j * 16 + l15) * 72 + ks * 32 + quad * 8);
            #pragma unroll
            for (int i = 0; i < 4; ++i)
                #pragma unroll
                for (int j = 0; j < 4; ++j)
                    acc[i][j] = __builtin_amdgcn_mfma_f32_16x16x32_bf16(afh[i], bfh[j], acc[i][j], 0, 0, 0);
        }
        __syncthreads();
    }

    // [i][c][j] layout: idx = ((i)*128 + c)*512 + j, i = ti*128+ib+r, j = tj*128+jl
    if (tfp32) {
        float* Tp = (float*)Tbuf + ((size_t)(ti * 128) * 128 + c) * 512 + tj * 128;
        #pragma unroll
        for (int i = 0; i < 4; ++i)
            #pragma unroll
            for (int j = 0; j < 4; ++j) {
                int jl = wn * 64 + j * 16 + l15;
                int ib = wm * 64 + i * 16 + quad * 4;
                #pragma unroll
                for (int r = 0; r < 4; ++r)
                    Tp[(size_t)(ib + r) * 65536 + jl] = acc[i][j][r];
            }
    } else {
        ushort* Tp = (ushort*)Tbuf + ((size_t)(ti * 128) * 128 + c) * 512 + tj * 128;
        #pragma unroll
        for (int i = 0; i < 4; ++i)
            #pragma unroll
            for (int j = 0; j < 4; ++j) {
                int jl = wn * 64 + j * 16 + l15;
                int ib = wm * 64 + i * 16 + quad * 4;
                #pragma unroll
                for (int r = 0; r < 4; ++r)
                    Tp[(size_t)(ib + r) * 65536 + jl] = f2bf(acc[i][j][r]);
            }
    }
}

// ---------------------------------------------------------------------------
// stage3AB: fp32 T ([i][c][j] layout). Gate and output GEMMs 2-term
// (znh*Wh + znl*Wh). LN stats from hi+lo t. Weights from global.
// ---------------------------------------------------------------------------
__global__ __launch_bounds__(256, 4)
void stage3ab_kernel(const void* __restrict__ z,
                     const void* __restrict__ ln_iw, const void* __restrict__ ln_ib,
                     const ushort* __restrict__ wt5_h, const ushort* __restrict__ wt5_l,
                     const void* __restrict__ b_g,
                     const float* __restrict__ Tf, const ushort* __restrict__ wzt_h,
                     const ushort* __restrict__ wzt_l,
                     const float* __restrict__ uvec, const float* __restrict__ vvec,
                     const int* __restrict__ dflag, void* __restrict__ out)
{
    __shared__ ushort sm[2 * 64 * 136];
    __shared__ float sMean[64], sRs[64];
    ushort* lAh = sm;
    ushort* lAl = sm + 64 * 136;
    const int tid = threadIdx.x, lane = tid & 63, w = tid >> 6;
    const int l15 = lane & 15, quad = lane >> 4;
    const int wm = w >> 1, wn = w & 1;
    const int p0 = blockIdx.x * 64;
    const int isbf = dflag[0];
    const f32x4 zero4 = {0.f, 0.f, 0.f, 0.f};
    (void)wt5_l; (void)wzt_l;

    // phase A: zn hi/lo
    float lw0 = loadIn(ln_iw, 2 * lane, isbf), lw1 = loadIn(ln_iw, 2 * lane + 1, isbf);
    float lb0 = loadIn(ln_ib, 2 * lane, isbf), lb1 = loadIn(ln_ib, 2 * lane + 1, isbf);
    for (int it = 0; it < 16; ++it) {
        int pl = w * 16 + it;
        float2 xv = loadIn2(z, (size_t)(p0 + pl) * 128, 2 * lane, isbf);
        float x0 = xv.x, x1 = xv.y;
        float s = x0 + x1, s2 = x0 * x0 + x1 * x1;
        #pragma unroll
        for (int m = 32; m >= 1; m >>= 1) { s += __shfl_xor(s, m); s2 += __shfl_xor(s2, m); }
        float mean = s * 0.0078125f;
        float var = s2 * 0.0078125f - mean * mean;
        float rs = rsqrtf(var + 1e-5f);
        float zn0 = (x0 - mean) * rs * lw0 + lb0;
        float zn1 = (x1 - mean) * rs * lw1 + lb1;
        ushort h0 = f2bf(zn0), h1 = f2bf(zn1);
        ushort o0 = f2bf(zn0 - bf2f(h0)), o1 = f2bf(zn1 - bf2f(h1));
        *(uint*)(lAh + pl * 136 + 2 * lane) = (uint)h0 | ((uint)h1 << 16);
        *(uint*)(lAl + pl * 136 + 2 * lane) = (uint)o0 | ((uint)o1 << 16);
    }
    __syncthreads();

    // gate GEMM (2-term), weights from global
    const ushort* wgh = wt5_h + 4 * 16384;
    f32x4 accG[2][4];
    #pragma unroll
    for (int i = 0; i < 2; ++i)
        #pragma unroll
        for (int j = 0; j < 4; ++j) accG[i][j] = zero4;
    #pragma unroll
    for (int ks = 0; ks < 4; ++ks) {
        bf16x8 afh[2], afl[2], bh[4];
        #pragma unroll
        for (int i = 0; i < 2; ++i) {
            afh[i] = *(const bf16x8*)(lAh + (wm * 32 + i * 16 + l15) * 136 + ks * 32 + quad * 8);
            afl[i] = *(const bf16x8*)(lAl + (wm * 32 + i * 16 + l15) * 136 + ks * 32 + quad * 8);
        }
        #pragma unroll
        for (int j = 0; j < 4; ++j)
            bh[j] = *(const bf16x8*)(wgh + (wn * 64 + j * 16 + l15) * 128 + ks * 32 + quad * 8);
        #pragma unroll
        for (int i = 0; i < 2; ++i)
            #pragma unroll
            for (int j = 0; j < 4; ++j) {
                accG[i][j] = __builtin_amdgcn_mfma_f32_16x16x32_bf16(afh[i], bh[j], accG[i][j], 0, 0, 0);
                accG[i][j] = __builtin_amdgcn_mfma_f32_16x16x32_bf16(afl[i], bh[j], accG[i][j], 0, 0, 0);
            }
    }
    #pragma unroll
    for (int i = 0; i < 2; ++i)
        #pragma unroll
        for (int j = 0; j < 4; ++j) {
            int co = wn * 64 + j * 16 + l15;
            float bgv = loadIn(b_g, co, isbf);
            #pragma unroll
            for (int r = 0; r < 4; ++r)
                accG[i][j][r] = sigm(accG[i][j][r] + bgv);
        }
    __syncthreads();

    // phase B: fp32 T ([i][c][j]) -> hi/lo LDS
    {
        int c = tid >> 1, h = tid & 1;
        const float* src = Tf + ((size_t)(p0 >> 9) * 128 + c) * 512 + (p0 & 511) + h * 32;
        float tv[32];
        #pragma unroll
        for (int q8 = 0; q8 < 8; ++q8) {
            float4 f4 = ((const float4*)src)[q8];
            tv[q8 * 4 + 0] = f4.x; tv[q8 * 4 + 1] = f4.y;
            tv[q8 * 4 + 2] = f4.z; tv[q8 * 4 + 3] = f4.w;
        }
        #pragma unroll
        for (int jj = 0; jj < 32; ++jj) {
            ushort hi = f2bf(tv[jj]);
            lAh[(h * 32 + jj) * 136 + c] = hi;
            lAl[(h * 32 + jj) * 136 + c] = f2bf(tv[jj] - bf2f(hi));
        }
    }
    __syncthreads();

    for (int it = 0; it < 16; ++it) {
        int pl = w * 16 + it;
        uint zh = *(const uint*)(lAh + pl * 136 + 2 * lane);
        uint zl = *(const uint*)(lAl + pl * 136 + 2 * lane);
        float x0 = bf2f((ushort)(zh & 0xffff)) + bf2f((ushort)(zl & 0xffff));
        float x1 = bf2f((ushort)(zh >> 16)) + bf2f((ushort)(zl >> 16));
        float s = x0 + x1, s2 = x0 * x0 + x1 * x1;
        #pragma unroll
        for (int m = 32; m >= 1; m >>= 1) { s += __shfl_xor(s, m); s2 += __shfl_xor(s2, m); }
        if (lane == 0) {
            float mean = s * 0.0078125f;
            float var = s2 * 0.0078125f - mean * mean;
            sMean[pl] = mean;
            sRs[pl] = rsqrtf(var + 1e-5f);
        }
    }
    __syncthreads();

    // output GEMM (2-term), W'hi from global
    f32x4 acc[2][4];
    #pragma unroll
    for (int i = 0; i < 2; ++i)
        #pragma unroll
        for (int j = 0; j < 4; ++j) acc[i][j] = zero4;
    #pragma unroll
    for (int ks = 0; ks < 4; ++ks) {
        bf16x8 afh[2], afl[2], bh[4];
        #pragma unroll
        for (int i = 0; i < 2; ++i) {
            afh[i] = *(const bf16x8*)(lAh + (wm * 32 + i * 16 + l15) * 136 + ks * 32 + quad * 8);
            afl[i] = *(const bf16x8*)(lAl + (wm * 32 + i * 16 + l15) * 136 + ks * 32 + quad * 8);
        }
        #pragma unroll
        for (int j = 0; j < 4; ++j)
            bh[j] = *(const bf16x8*)(wzt_h + (wn * 64 + j * 16 + l15) * 128 + ks * 32 + quad * 8);
        #pragma unroll
        for (int i = 0; i < 2; ++i)
            #pragma unroll
            for (int j = 0; j < 4; ++j) {
                acc[i][j] = __builtin_amdgcn_mfma_f32_16x16x32_bf16(afh[i], bh[j], acc[i][j], 0, 0, 0);
                acc[i][j] = __builtin_amdgcn_mfma_f32_16x16x32_bf16(afl[i], bh[j], acc[i][j], 0, 0, 0);
            }
    }

    ushort* outb = (ushort*)out;
    float*  outf = (float*)out;
    #pragma unroll
    for (int i = 0; i < 2; ++i)
        #pragma unroll
        for (int j = 0; j < 4; ++j) {
            int co = wn * 64 + j * 16 + l15;
            float uj = uvec[co], vj = vvec[co];
            int pb = wm * 32 + i * 16 + quad * 4;
            #pragma unroll
            for (int r = 0; r < 4; ++r) {
                int p = pb + r;
                float pre = sRs[p] * (acc[i][j][r] - sMean[p] * uj) + vj;
                float val = accG[i][j][r] * pre;
                size_t oidx = (size_t)(p0 + p) * 128 + co;
                if (isbf) outb[oidx] = f2bf(val);
                else      outf[oidx] = val;
            }
        }
}

// ---------------------------------------------------------------------------
// stage3C: bf16 T fallback ([i][c][j] layout). Gate 2-term zn split.
// ---------------------------------------------------------------------------
__global__ __launch_bounds__(256, 2)
void stage3c_kernel(const void* __restrict__ z,
                    const void* __restrict__ ln_iw, const void* __restrict__ ln_ib,
                    const ushort* __restrict__ wt5_h, const void* __restrict__ b_g,
                    const ushort* __restrict__ Tb, const ushort* __restrict__ wzt_h,
                    const float* __restrict__ uvec, const float* __restrict__ vvec,
                    const int* __restrict__ dflag, void* __restrict__ out)
{
    __shared__ ushort sm[2 * 64 * 136 + 128 * 136];
    __shared__ float sMean[64], sRs[64];
    ushort* lAh = sm;
    ushort* lAl = sm + 64 * 136;
    ushort* lB  = sm + 2 * 64 * 136;
    const int tid = threadIdx.x, lane = tid & 63, w = tid >> 6;
    const int l15 = lane & 15, quad = lane >> 4;
    const int wm = w >> 1, wn = w & 1;
    const int p0 = blockIdx.x * 64;
    const int isbf = dflag[0];
    const f32x4 zero4 = {0.f, 0.f, 0.f, 0.f};

    float lw0 = loadIn(ln_iw, 2 * lane, isbf), lw1 = loadIn(ln_iw, 2 * lane + 1, isbf);
    float lb0 = loadIn(ln_ib, 2 * lane, isbf), lb1 = loadIn(ln_ib, 2 * lane + 1, isbf);
    for (int it = 0; it < 16; ++it) {
        int pl = w * 16 + it;
        float2 xv = loadIn2(z, (size_t)(p0 + pl) * 128, 2 * lane, isbf);
        float x0 = xv.x, x1 = xv.y;
        float s = x0 + x1, s2 = x0 * x0 + x1 * x1;
        #pragma unroll
        for (int m = 32; m >= 1; m >>= 1) { s += __shfl_xor(s, m); s2 += __shfl_xor(s2, m); }
        float mean = s * 0.0078125f;
        float var = s2 * 0.0078125f - mean * mean;
        float rs = rsqrtf(var + 1e-5f);
        float zn0 = (x0 - mean) * rs * lw0 + lb0;
        float zn1 = (x1 - mean) * rs * lw1 + lb1;
        ushort h0 = f2bf(zn0), h1 = f2bf(zn1);
        ushort o0 = f2bf(zn0 - bf2f(h0)), o1 = f2bf(zn1 - bf2f(h1));
        *(uint*)(lAh + pl * 136 + 2 * lane) = (uint)h0 | ((uint)h1 << 16);
        *(uint*)(lAl + pl * 136 + 2 * lane) = (uint)o0 | ((uint)o1 << 16);
    }
    {
        const ushort* src = wt5_h + 4 * 16384;
        #pragma unroll
        for (int q = 0; q < 8; ++q) {
            int vv = q * 256 + tid;
            int co = vv >> 4, off = vv & 15;
            *(uint4*)(lB + co * 136 + off * 8) = *(const uint4*)(src + co * 128 + off * 8);
        }
    }
    __syncthreads();

    f32x4 accG[2][4];
    #pragma unroll
    for (int i = 0; i < 2; ++i)
        #pragma unroll
        for (int j = 0; j < 4; ++j) accG[i][j] = zero4;
    #pragma unroll
    for (int ks = 0; ks < 4; ++ks) {
        bf16x8 afh[2], afl[2], bfr[4];
        #pragma unroll
        for (int i = 0; i < 2; ++i) {
            afh[i] = *(const bf16x8*)(lAh + (wm * 32 + i * 16 + l15) * 136 + ks * 32 + quad * 8);
            afl[i] = *(const bf16x8*)(lAl + (wm * 32 + i * 16 + l15) * 136 + ks * 32 + quad * 8);
        }
        #pragma unroll
        for (int j = 0; j < 4; ++j)
            bfr[j] = *(const bf16x8*)(lB + (wn * 64 + j * 16 + l15) * 136 + ks * 32 + quad * 8);
        #pragma unroll
        for (int i = 0; i < 2; ++i)
            #pragma unroll
            for (int j = 0; j < 4; ++j) {
                accG[i][j] = __builtin_amdgcn_mfma_f32_16x16x32_bf16(afh[i], bfr[j], accG[i][j], 0, 0, 0);
                accG[i][j] = __builtin_amdgcn_mfma_f32_16x16x32_bf16(afl[i], bfr[j], accG[i][j], 0, 0, 0);
            }
    }
    #pragma unroll
    for (int i = 0; i < 2; ++i)
        #pragma unroll
        for (int j = 0; j < 4; ++j) {
            int co = wn * 64 + j * 16 + l15;
            float bgv = loadIn(b_g, co, isbf);
            #pragma unroll
            for (int r = 0; r < 4; ++r)
                accG[i][j][r] = sigm(accG[i][j][r] + bgv);
        }
    __syncthreads();

    {
        int c = tid >> 1, h = tid & 1;
        const ushort* src = Tb + ((size_t)(p0 >> 9) * 128 + c) * 512 + (p0 & 511) + h * 32;
        union { uint4 q[4]; ushort u[32]; } tmp;
        tmp.q[0] = ((const uint4*)src)[0];
        tmp.q[1] = ((const uint4*)src)[1];
        tmp.q[2] = ((const uint4*)src)[2];
        tmp.q[3] = ((const uint4*)src)[3];
        #pragma unroll
        for (int jj = 0; jj < 32; ++jj)
            lAh[(h * 32 + jj) * 136 + c] = tmp.u[jj];
    }
    #pragma unroll
    for (int q = 0; q < 8; ++q) {
        int vv = q * 256 + tid;
        int co = vv >> 4, off = vv & 15;
        *(uint4*)(lB + co * 136 + off * 8) = *(const uint4*)(wzt_h + co * 128 + off * 8);
    }
    __syncthreads();

    for (int it = 0; it < 16; ++it) {
        int pl = w * 16 + it;
        uint zz = *(const uint*)(lAh + pl * 136 + 2 * lane);
        float x0 = bf2f((ushort)(zz & 0xffff)), x1 = bf2f((ushort)(zz >> 16));
        float s = x0 + x1, s2 = x0 * x0 + x1 * x1;
        #pragma unroll
        for (int m = 32; m >= 1; m >>= 1) { s += __shfl_xor(s, m); s2 += __shfl_xor(s2, m); }
        if (lane == 0) {
            float mean = s * 0.0078125f;
            float var = s2 * 0.0078125f - mean * mean;
            sMean[pl] = mean;
            sRs[pl] = rsqrtf(var + 1e-5f);
        }
    }
    __syncthreads();

    f32x4 acc[2][4];
    #pragma unroll
    for (int i = 0; i < 2; ++i)
        #pragma unroll
        for (int j = 0; j < 4; ++j) acc[i][j] = zero4;
    #pragma unroll
    for (int ks = 0; ks < 4; ++ks) {
        bf16x8 af[2], bfr[4];
        #pragma unroll
        for (int i = 0; i < 2; ++i)
            af[i] = *(const bf16x8*)(lAh + (wm * 32 + i * 16 + l15) * 136 + ks * 32 + quad * 8);
        #pragma unroll
        for (int j = 0; j < 4; ++j)
            bfr[j] = *(const bf16x8*)(lB + (wn * 64 + j * 16 + l15) * 136 + ks * 32 + quad * 8);
        #pragma unroll
        for (int i = 0; i < 2; ++i)
            #pragma unroll
            for (int j = 0; j < 4; ++j)
                acc[i][j] = __builtin_amdgcn_mfma_f32_16x16x32_bf16(af[i], bfr[j], acc[i][j], 0, 0, 0);
    }

    ushort* outb = (ushort*)out;
    float*  outf = (float*)out;
    #pragma unroll
    for (int i = 0; i < 2; ++i)
        #pragma unroll
        for (int j = 0; j < 4; ++j) {
            int co = wn * 64 + j * 16 + l15;
            float uj = uvec[co], vj = vvec[co];
            int pb = wm * 32 + i * 16 + quad * 4;
            #pragma unroll
            for (int r = 0; r < 4; ++r) {
                int p = pb + r;
                float pre = sRs[p] * (acc[i][j][r] - sMean[p] * uj) + vj;
                float val = accG[i][j][r] * pre;
                size_t oidx = (size_t)(p0 + p) * 128 + co;
                if (isbf) outb[oidx] = f2bf(val);
                else      outf[oidx] = val;
            }
        }
}

// ---------------------------------------------------------------------------
extern "C" void kernel_launch(void* const* d_in, const int* in_sizes, int n_in,
                              void* d_out, int out_size, void* d_ws, size_t ws_size,
                              hipStream_t stream)
{
    const void* z     = d_in[0];
    const void* ln_iw = d_in[1];
    const void* ln_ib = d_in[2];
    const void* ln_ow = d_in[3];
    const void* ln_ob = d_in[4];
    const void* w_ap  = d_in[5];
    const void* b_ap  = d_in[6];
    const void* w_ag  = d_in[7];
    const void* b_ag  = d_in[8];
    const void* w_bp  = d_in[9];
    const void* b_bp  = d_in[10];
    const void* w_bg  = d_in[11];
    const void* b_bg  = d_in[12];
    const void* w_g   = d_in[13];
    const void* b_g   = d_in[14];
    const void* w_z   = d_in[15];
    const void* b_z   = d_in[16];

    const size_t MB64 = 67108864;
    const size_t REQ_C = 262144 + 2 * MB64;                    // 134,479,872 (proven-safe)
    const size_t REQ_B = 524288 + MB64 + 2 * MB64;             // 201,850,880
    const size_t REQ_A = REQ_B + MB64;                         // 268,959,744

    char* ws = (char*)d_ws;
    if (ws_size < REQ_C) {
        fill_zero_kernel<<<8192, 256, 0, stream>>>((ushort*)d_out);
        return;
    }

    int tier = (ws_size >= REQ_A) ? 0 : (ws_size >= REQ_B) ? 1 : 2;  // 0=A,1=B,2=C
    if (tier == 0) tier = 1;   // forced tier B (single-bf16 A and B planes)

    // hi prep area (common offsets)
    ushort* wt5_h = (ushort*)(ws);
    ushort* wzt_h = (ushort*)(ws + 163840);
    float*  uvec  = (float*)(ws + 196608);
    float*  vvec  = (float*)(ws + 197120);
    int*    dflag = (int*)(ws + 198144);
    // lo prep area (unused since R13: weight-lo terms dropped everywhere)
    ushort* wt5_l = (ushort*)(ws + 262144);
    ushort* wzt_l = (ushort*)(ws + 262144 + 163840);
    int store_lo = 0;   // no consumer of weight-lo planes remains
    if (tier == 2) { wt5_l = wt5_h; wzt_l = wzt_h; }

    ushort* Ahi; ushort* Alo; void* Tbuf;
    int walo = 0, tfp32 = 0;
    if (tier == 1) {
        Ahi = (ushort*)(ws + 524288);
        Alo = Ahi;
        Tbuf = (void*)(ws + 524288 + MB64);
        walo = 0; tfp32 = 1;
    } else {
        Ahi = (ushort*)(ws + 262144);
        Alo = Ahi;
        Tbuf = (void*)(ws + 262144 + MB64);
        walo = 0; tfp32 = 0;
    }
    ushort* Bhi = (ushort*)d_out;

    detect_kernel<<<1, 64, 0, stream>>>((const uint*)z, dflag);
    prep_kernel<<<7, 256, 0, stream>>>(w_ap, w_ag, w_bp, w_bg, w_g, w_z, ln_ow, ln_ob, b_z,
                                       dflag, wt5_h, wt5_l, wzt_h, wzt_l, uvec, vvec, store_lo);
    stage1_kernel<<<4096, 256, 0, stream>>>(z, ln_iw, ln_ib, wt5_h,
                                            b_ap, b_ag, b_bp, b_bg, dflag,
                                            Ahi, Alo, Bhi, walo);
    stage2_kernel<<<dim3(16, 128), 256, 0, stream>>>(Ahi, Alo, Bhi, dflag, Tbuf, walo, tfp32);
    if (tfp32)
        stage3ab_kernel<<<4096, 256, 0, stream>>>(z, ln_iw, ln_ib, wt5_h, wt5_l, b_g,
                                                  (const float*)Tbuf, wzt_h, wzt_l,
                                                  uvec, vvec, dflag, d_out);
    else
        stage3c_kernel<<<4096, 256, 0, stream>>>(z, ln_iw, ln_ib, wt5_h, b_g,
                                                 (const ushort*)Tbuf, wzt_h,
                                                 uvec, vvec, dflag, d_out);
}

// Round 16
// 747.287 us; speedup vs baseline: 1.1646x; 1.0163x over previous
//
#include <hip/hip_runtime.h>
#include <hip/hip_bf16.h>

// TriangleMultiplication (outgoing), N=512, C=C_Z=128. Inputs/out fp32
// (runtime-detected; bf16 fallback kept). Internal: bf16 MFMA; zn hi/lo
// split in small GEMMs; T fp32.
//
// R5 occupancy 867.7 | R7 swizzle null | R8/R13 stage2 tiling | R9 T layout
// R10-R12 drop A-lo/B-lo (absmax unchanged) 780.6 | R13 2-term stage3: 769.0
// R14 stage1 sequential-group fusion (LN once): 759.5, FETCH halved.
// R15: gate GEMM moved from stage3ab into stage1 (3rd sequential pass over
//      the resident zn LDS; bit-identical pre-sigmoid arithmetic; g stored
//      bf16 channel-major in ws). stage3ab loses phase A entirely (z load,
//      LN, gate GEMM). Requires ws>=REQ_A for the 64MB g buffer; falls back
//      to the R14 path otherwise.
// R16: identical resubmit (container infra failure, no signal).

#define NSEQ 512
#define NPOS 262144

typedef short bf16x8 __attribute__((ext_vector_type(8)));
typedef float f32x4 __attribute__((ext_vector_type(4)));

__device__ __forceinline__ float bf2f(ushort h) {
    union { uint u; float f; } x; x.u = ((uint)h) << 16; return x.f;
}
__device__ __forceinline__ ushort f2bf(float f) {
    union { float f; uint u; } x; x.f = f;
    uint r = x.u + 0x7fffu + ((x.u >> 16) & 1u);
    return (ushort)(r >> 16);
}
__device__ __forceinline__ float sigm(float x) { return 1.f / (1.f + __expf(-x)); }

__device__ __forceinline__ float loadIn(const void* p, size_t idx, int isbf) {
    return isbf ? bf2f(((const ushort*)p)[idx]) : ((const float*)p)[idx];
}
__device__ __forceinline__ float2 loadIn2(const void* p, size_t base, int col2, int isbf) {
    if (isbf) {
        uint zz = *(const uint*)((const ushort*)p + base + col2);
        float2 r; r.x = bf2f((ushort)(zz & 0xffff)); r.y = bf2f((ushort)(zz >> 16)); return r;
    }
    return *(const float2*)((const float*)p + base + col2);
}

// ---------------------------------------------------------------------------
__global__ void detect_kernel(const uint* __restrict__ z32, int* __restrict__ flag)
{
    int t = threadIdx.x;
    int votes = 0;
    #pragma unroll
    for (int i = 0; i < 4; ++i) {
        uint wv = z32[t * 4 + i];
        uint ex = (wv >> 7) & 0xff;
        votes += (ex >= 118 && ex <= 132) ? 1 : 0;
    }
    #pragma unroll
    for (int m = 32; m >= 1; m >>= 1) votes += __shfl_xor(votes, m);
    if (t == 0) flag[0] = (votes >= 128) ? 1 : 0;
}

__global__ void fill_zero_kernel(ushort* __restrict__ out)
{
    size_t i = ((size_t)blockIdx.x * 256 + threadIdx.x) * 16;
    uint4 z4 = {0u, 0u, 0u, 0u};
    *(uint4*)(out + i) = z4;
    *(uint4*)(out + i + 8) = z4;
}

// ---------------------------------------------------------------------------
// prep: wt5_h[g][co][ci] (transposed bf16); wzt_h[co][c] of W' = ln_ow*w_z;
// u,v fp32 affine-fold vectors. (lo planes unused since R13)
// ---------------------------------------------------------------------------
__global__ void prep_kernel(const void* __restrict__ w_ap, const void* __restrict__ w_ag,
                            const void* __restrict__ w_bp, const void* __restrict__ w_bg,
                            const void* __restrict__ w_g,  const void* __restrict__ w_z,
                            const void* __restrict__ ln_ow, const void* __restrict__ ln_ob,
                            const void* __restrict__ b_z,  const int* __restrict__ dflag,
                            ushort* __restrict__ wt5_h, ushort* __restrict__ wt5_l,
                            ushort* __restrict__ wzt_h, ushort* __restrict__ wzt_l,
                            float* __restrict__ u, float* __restrict__ v, int store_lo)
{
    const int b = blockIdx.x, t = threadIdx.x;
    const int isbf = dflag[0];
    if (b < 5) {
        const void* src = (b == 0) ? w_ap : (b == 1) ? w_ag : (b == 2) ? w_bp : (b == 3) ? w_bg : w_g;
        for (int k = 0; k < 64; ++k) {
            int o = t + k * 256;
            int co = o >> 7, ci = o & 127;
            float wv = loadIn(src, ci * 128 + co, isbf);
            ushort hi = f2bf(wv);
            wt5_h[b * 16384 + o] = hi;
            if (store_lo) wt5_l[b * 16384 + o] = f2bf(wv - bf2f(hi));
        }
    } else if (b == 5) {
        for (int k = 0; k < 64; ++k) {
            int o = t + k * 256;
            int co = o >> 7, c = o & 127;
            float wv = loadIn(ln_ow, c, isbf) * loadIn(w_z, c * 128 + co, isbf);
            ushort hi = f2bf(wv);
            wzt_h[o] = hi;
            if (store_lo) wzt_l[o] = f2bf(wv - bf2f(hi));
        }
    } else {
        if (t < 128) {
            float su = 0.f, sv = 0.f;
            for (int c = 0; c < 128; ++c) {
                float wzv = loadIn(w_z, c * 128 + t, isbf);
                su += loadIn(ln_ow, c, isbf) * wzv;
                sv += loadIn(ln_ob, c, isbf) * wzv;
            }
            u[t] = su;
            v[t] = sv + loadIn(b_z, t, isbf);
        }
    }
}

// ---------------------------------------------------------------------------
// stage1: grid (4096). LN ONCE, then sequential passes: g0 -> a (A_hi),
// g1 -> b (B_hi in d_out), and (do_gate) gate -> Gbuf (sigmoid(zn.w_g+b_g),
// bf16 channel-major). zn hi+lo persists in LDS; tb separate transpose buf.
// ---------------------------------------------------------------------------
__global__ __launch_bounds__(256, 3)
void stage1_kernel(const void* __restrict__ z,
                   const void* __restrict__ ln_iw, const void* __restrict__ ln_ib,
                   const ushort* __restrict__ wt5_h,
                   const void* __restrict__ b_ap, const void* __restrict__ b_ag,
                   const void* __restrict__ b_bp, const void* __restrict__ b_bg,
                   const void* __restrict__ b_g,
                   const int* __restrict__ dflag,
                   ushort* __restrict__ Ahi, ushort* __restrict__ Bhi,
                   ushort* __restrict__ Gbuf, int do_gate)
{
    __shared__ ushort sm[2 * 64 * 136 + 128 * 72];
    ushort* lAh = sm;                    // [64][136] zn hi
    ushort* lAl = sm + 64 * 136;         // [64][136] zn lo
    ushort* tb  = sm + 2 * 64 * 136;     // [128][72] transpose buf (separate)
    const int tid = threadIdx.x, lane = tid & 63, w = tid >> 6;
    const int l15 = lane & 15, quad = lane >> 4;
    const int p0 = blockIdx.x * 64;
    const int isbf = dflag[0];

    float lw0 = loadIn(ln_iw, 2 * lane, isbf), lw1 = loadIn(ln_iw, 2 * lane + 1, isbf);
    float lb0 = loadIn(ln_ib, 2 * lane, isbf), lb1 = loadIn(ln_ib, 2 * lane + 1, isbf);
    for (int it = 0; it < 16; ++it) {
        int pl = w * 16 + it;
        float2 xv = loadIn2(z, (size_t)(p0 + pl) * 128, 2 * lane, isbf);
        float x0 = xv.x, x1 = xv.y;
        float s = x0 + x1, s2 = x0 * x0 + x1 * x1;
        #pragma unroll
        for (int m = 32; m >= 1; m >>= 1) { s += __shfl_xor(s, m); s2 += __shfl_xor(s2, m); }
        float mean = s * 0.0078125f;
        float var = s2 * 0.0078125f - mean * mean;
        float rs = rsqrtf(var + 1e-5f);
        float zn0 = (x0 - mean) * rs * lw0 + lb0;
        float zn1 = (x1 - mean) * rs * lw1 + lb1;
        ushort h0 = f2bf(zn0), h1 = f2bf(zn1);
        ushort o0 = f2bf(zn0 - bf2f(h0)), o1 = f2bf(zn1 - bf2f(h1));
        *(uint*)(lAh + pl * 136 + 2 * lane) = (uint)h0 | ((uint)h1 << 16);
        *(uint*)(lAl + pl * 136 + 2 * lane) = (uint)o0 | ((uint)o1 << 16);
    }
    __syncthreads();

    const int wm = w >> 1, wn = w & 1;
    const f32x4 zero4 = {0.f, 0.f, 0.f, 0.f};

    #pragma unroll 1
    for (int g = 0; g < 2; ++g) {
        const ushort* wG = wt5_h + ((g == 0) ? 1 : 3) * 16384;
        const ushort* wP = wt5_h + ((g == 0) ? 0 : 2) * 16384;

        f32x4 accG[2][4], accP[2][4];
        #pragma unroll
        for (int i = 0; i < 2; ++i)
            #pragma unroll
            for (int j = 0; j < 4; ++j) { accG[i][j] = zero4; accP[i][j] = zero4; }

        #pragma unroll
        for (int ks = 0; ks < 4; ++ks) {
            bf16x8 afh[2], afl[2];
            #pragma unroll
            for (int i = 0; i < 2; ++i) {
                afh[i] = *(const bf16x8*)(lAh + (wm * 32 + i * 16 + l15) * 136 + ks * 32 + quad * 8);
                afl[i] = *(const bf16x8*)(lAl + (wm * 32 + i * 16 + l15) * 136 + ks * 32 + quad * 8);
            }
            {
                bf16x8 bG[4];
                #pragma unroll
                for (int j = 0; j < 4; ++j)
                    bG[j] = *(const bf16x8*)(wG + (wn * 64 + j * 16 + l15) * 128 + ks * 32 + quad * 8);
                #pragma unroll
                for (int i = 0; i < 2; ++i)
                    #pragma unroll
                    for (int j = 0; j < 4; ++j) {
                        accG[i][j] = __builtin_amdgcn_mfma_f32_16x16x32_bf16(afh[i], bG[j], accG[i][j], 0, 0, 0);
                        accG[i][j] = __builtin_amdgcn_mfma_f32_16x16x32_bf16(afl[i], bG[j], accG[i][j], 0, 0, 0);
                    }
            }
            {
                bf16x8 bP[4];
                #pragma unroll
                for (int j = 0; j < 4; ++j)
                    bP[j] = *(const bf16x8*)(wP + (wn * 64 + j * 16 + l15) * 128 + ks * 32 + quad * 8);
                #pragma unroll
                for (int i = 0; i < 2; ++i)
                    #pragma unroll
                    for (int j = 0; j < 4; ++j) {
                        accP[i][j] = __builtin_amdgcn_mfma_f32_16x16x32_bf16(afh[i], bP[j], accP[i][j], 0, 0, 0);
                        accP[i][j] = __builtin_amdgcn_mfma_f32_16x16x32_bf16(afl[i], bP[j], accP[i][j], 0, 0, 0);
                    }
            }
        }

        const void* bgp = (g == 0) ? b_ag : b_bg;
        const void* bpp = (g == 0) ? b_ap : b_bp;
        float av[2][4][4];
        #pragma unroll
        for (int i = 0; i < 2; ++i)
            #pragma unroll
            for (int j = 0; j < 4; ++j) {
                int co = wn * 64 + j * 16 + l15;
                float gv = loadIn(bgp, co, isbf);
                float pv = loadIn(bpp, co, isbf);
                #pragma unroll
                for (int r = 0; r < 4; ++r)
                    av[i][j][r] = sigm(accG[i][j][r] + gv) * (accP[i][j][r] + pv);
            }

        ushort* dst_hi = (g == 0) ? Ahi : Bhi;

        __syncthreads();   // prior tb reads done
        #pragma unroll
        for (int i = 0; i < 2; ++i)
            #pragma unroll
            for (int j = 0; j < 4; ++j) {
                int co = wn * 64 + j * 16 + l15;
                int pb = wm * 32 + i * 16 + quad * 4;
                uint2 pk;
                pk.x = (uint)f2bf(av[i][j][0]) | ((uint)f2bf(av[i][j][1]) << 16);
                pk.y = (uint)f2bf(av[i][j][2]) | ((uint)f2bf(av[i][j][3]) << 16);
                *(uint2*)(tb + co * 72 + pb) = pk;
            }
        __syncthreads();
        #pragma unroll
        for (int q = 0; q < 4; ++q) {
            int vv = q * 256 + tid;
            int co = vv >> 3, off = vv & 7;
            *(uint4*)(dst_hi + (size_t)co * NPOS + p0 + off * 8) = *(const uint4*)(tb + co * 72 + off * 8);
        }
    }

    if (do_gate) {
        // gate pass: acc = zn . w_g (2-term), sigmoid, store channel-major
        const ushort* wGt = wt5_h + 4 * 16384;
        f32x4 acc[2][4];
        #pragma unroll
        for (int i = 0; i < 2; ++i)
            #pragma unroll
            for (int j = 0; j < 4; ++j) acc[i][j] = zero4;
        #pragma unroll
        for (int ks = 0; ks < 4; ++ks) {
            bf16x8 afh[2], afl[2], bh[4];
            #pragma unroll
            for (int i = 0; i < 2; ++i) {
                afh[i] = *(const bf16x8*)(lAh + (wm * 32 + i * 16 + l15) * 136 + ks * 32 + quad * 8);
                afl[i] = *(const bf16x8*)(lAl + (wm * 32 + i * 16 + l15) * 136 + ks * 32 + quad * 8);
            }
            #pragma unroll
            for (int j = 0; j < 4; ++j)
                bh[j] = *(const bf16x8*)(wGt + (wn * 64 + j * 16 + l15) * 128 + ks * 32 + quad * 8);
            #pragma unroll
            for (int i = 0; i < 2; ++i)
                #pragma unroll
                for (int j = 0; j < 4; ++j) {
                    acc[i][j] = __builtin_amdgcn_mfma_f32_16x16x32_bf16(afh[i], bh[j], acc[i][j], 0, 0, 0);
                    acc[i][j] = __builtin_amdgcn_mfma_f32_16x16x32_bf16(afl[i], bh[j], acc[i][j], 0, 0, 0);
                }
        }
        __syncthreads();   // prior store's tb reads done
        #pragma unroll
        for (int i = 0; i < 2; ++i)
            #pragma unroll
            for (int j = 0; j < 4; ++j) {
                int co = wn * 64 + j * 16 + l15;
                float bgv = loadIn(b_g, co, isbf);
                int pb = wm * 32 + i * 16 + quad * 4;
                uint2 pk;
                pk.x = (uint)f2bf(sigm(acc[i][j][0] + bgv)) | ((uint)f2bf(sigm(acc[i][j][1] + bgv)) << 16);
                pk.y = (uint)f2bf(sigm(acc[i][j][2] + bgv)) | ((uint)f2bf(sigm(acc[i][j][3] + bgv)) << 16);
                *(uint2*)(tb + co * 72 + pb) = pk;
            }
        __syncthreads();
        #pragma unroll
        for (int q = 0; q < 4; ++q) {
            int vv = q * 256 + tid;
            int co = vv >> 3, off = vv & 7;
            *(uint4*)(Gbuf + (size_t)co * NPOS + p0 + off * 8) = *(const uint4*)(tb + co * 72 + off * 8);
        }
    }
}

// ---------------------------------------------------------------------------
// stage2: grid (16, 128). T_c = A_c * B_c^T, single hi*hi MFMA term.
// K-tile 64, 2 LDS planes (36864 B, (256,3)); 8 barrier pairs.
// T written fp32 (tfp32) or bf16 in [i][c][j] layout: idx = (i*128+c)*512+j.
// ---------------------------------------------------------------------------
__global__ __launch_bounds__(256, 3)
void stage2_kernel(const ushort* __restrict__ Ahi, const ushort* __restrict__ Bhi,
                   const int* __restrict__ dflag,
                   void* __restrict__ Tbuf, int tfp32)
{
    __shared__ ushort sm[2 * 128 * 72];   // 36864 B
    ushort* lAh = sm;
    ushort* lBh = sm + 128 * 72;
    const int tid = threadIdx.x, lane = tid & 63, w = tid >> 6;
    const int l15 = lane & 15, quad = lane >> 4;
    const int wm = w >> 1, wn = w & 1;
    const int bid = blockIdx.y * 16 + blockIdx.x;          // 0..2047
    const int swz = (bid & 7) * 256 + (bid >> 3);          // bijective
    const int c = swz >> 4;
    const int ti = (swz & 15) >> 2, tj = swz & 3;
    const ushort* Aph = Ahi + (size_t)c * NPOS + (size_t)ti * 128 * NSEQ;
    const ushort* Bph = Bhi + (size_t)c * NPOS + (size_t)tj * 128 * NSEQ;

    const f32x4 zero4 = {0.f, 0.f, 0.f, 0.f};
    f32x4 acc[4][4];
    #pragma unroll
    for (int i = 0; i < 4; ++i)
        #pragma unroll
        for (int j = 0; j < 4; ++j) acc[i][j] = zero4;

    for (int kt = 0; kt < 8; ++kt) {
        #pragma unroll
        for (int q = 0; q < 4; ++q) {
            int vv = q * 256 + tid;
            int row = vv >> 3, off = vv & 7;
            *(uint4*)(lAh + row * 72 + off * 8) = *(const uint4*)(Aph + (size_t)row * NSEQ + kt * 64 + off * 8);
            *(uint4*)(lBh + row * 72 + off * 8) = *(const uint4*)(Bph + (size_t)row * NSEQ + kt * 64 + off * 8);
        }
        __syncthreads();
        #pragma unroll
        for (int ks = 0; ks < 2; ++ks) {
            bf16x8 afh[4], bfh[4];
            #pragma unroll
            for (int i = 0; i < 4; ++i)
                afh[i] = *(const bf16x8*)(lAh + (wm * 64 + i * 16 + l15) * 72 + ks * 32 + quad * 8);
            #pragma unroll
            for (int j = 0; j < 4; ++j)
                bfh[j] = *(const bf16x8*)(lBh + (wn * 64 + j * 16 + l15) * 72 + ks * 32 + quad * 8);
            #pragma unroll
            for (int i = 0; i < 4; ++i)
                #pragma unroll
                for (int j = 0; j < 4; ++j)
                    acc[i][j] = __builtin_amdgcn_mfma_f32_16x16x32_bf16(afh[i], bfh[j], acc[i][j], 0, 0, 0);
        }
        __syncthreads();
    }

    // [i][c][j] layout: idx = ((i)*128 + c)*512 + j
    if (tfp32) {
        float* Tp = (float*)Tbuf + ((size_t)(ti * 128) * 128 + c) * 512 + tj * 128;
        #pragma unroll
        for (int i = 0; i < 4; ++i)
            #pragma unroll
            for (int j = 0; j < 4; ++j) {
                int jl = wn * 64 + j * 16 + l15;
                int ib = wm * 64 + i * 16 + quad * 4;
                #pragma unroll
                for (int r = 0; r < 4; ++r)
                    Tp[(size_t)(ib + r) * 65536 + jl] = acc[i][j][r];
            }
    } else {
        ushort* Tp = (ushort*)Tbuf + ((size_t)(ti * 128) * 128 + c) * 512 + tj * 128;
        #pragma unroll
        for (int i = 0; i < 4; ++i)
            #pragma unroll
            for (int j = 0; j < 4; ++j) {
                int jl = wn * 64 + j * 16 + l15;
                int ib = wm * 64 + i * 16 + quad * 4;
                #pragma unroll
                for (int r = 0; r < 4; ++r)
                    Tp[(size_t)(ib + r) * 65536 + jl] = f2bf(acc[i][j][r]);
            }
    }
}

// ---------------------------------------------------------------------------
// stage3g (R15): fp32 T ([i][c][j]); g from Gbuf (bf16, channel-major).
// {T load -> hi/lo LDS -> t-LN stats -> output GEMM 2-term -> epilogue*g}.
// No z load, no input-LN, no gate GEMM.
// ---------------------------------------------------------------------------
__global__ __launch_bounds__(256, 4)
void stage3g_kernel(const float* __restrict__ Tf, const ushort* __restrict__ Gbuf,
                    const ushort* __restrict__ wzt_h,
                    const float* __restrict__ uvec, const float* __restrict__ vvec,
                    const int* __restrict__ dflag, void* __restrict__ out)
{
    __shared__ ushort sm[2 * 64 * 136];
    __shared__ float sMean[64], sRs[64];
    ushort* lAh = sm;
    ushort* lAl = sm + 64 * 136;
    const int tid = threadIdx.x, lane = tid & 63, w = tid >> 6;
    const int l15 = lane & 15, quad = lane >> 4;
    const int wm = w >> 1, wn = w & 1;
    const int p0 = blockIdx.x * 64;
    const int isbf = dflag[0];
    const f32x4 zero4 = {0.f, 0.f, 0.f, 0.f};

    // fp32 T ([i][c][j]) -> hi/lo LDS
    {
        int c = tid >> 1, h = tid & 1;
        const float* src = Tf + ((size_t)(p0 >> 9) * 128 + c) * 512 + (p0 & 511) + h * 32;
        float tv[32];
        #pragma unroll
        for (int q8 = 0; q8 < 8; ++q8) {
            float4 f4 = ((const float4*)src)[q8];
            tv[q8 * 4 + 0] = f4.x; tv[q8 * 4 + 1] = f4.y;
            tv[q8 * 4 + 2] = f4.z; tv[q8 * 4 + 3] = f4.w;
        }
        #pragma unroll
        for (int jj = 0; jj < 32; ++jj) {
            ushort hi = f2bf(tv[jj]);
            lAh[(h * 32 + jj) * 136 + c] = hi;
            lAl[(h * 32 + jj) * 136 + c] = f2bf(tv[jj] - bf2f(hi));
        }
    }
    __syncthreads();

    // t-LN stats from hi+lo
    for (int it = 0; it < 16; ++it) {
        int pl = w * 16 + it;
        uint zh = *(const uint*)(lAh + pl * 136 + 2 * lane);
        uint zl = *(const uint*)(lAl + pl * 136 + 2 * lane);
        float x0 = bf2f((ushort)(zh & 0xffff)) + bf2f((ushort)(zl & 0xffff));
        float x1 = bf2f((ushort)(zh >> 16)) + bf2f((ushort)(zl >> 16));
        float s = x0 + x1, s2 = x0 * x0 + x1 * x1;
        #pragma unroll
        for (int m = 32; m >= 1; m >>= 1) { s += __shfl_xor(s, m); s2 += __shfl_xor(s2, m); }
        if (lane == 0) {
            float mean = s * 0.0078125f;
            float var = s2 * 0.0078125f - mean * mean;
            sMean[pl] = mean;
            sRs[pl] = rsqrtf(var + 1e-5f);
        }
    }
    __syncthreads();

    // output GEMM (2-term), W'hi from global
    f32x4 acc[2][4];
    #pragma unroll
    for (int i = 0; i < 2; ++i)
        #pragma unroll
        for (int j = 0; j < 4; ++j) acc[i][j] = zero4;
    #pragma unroll
    for (int ks = 0; ks < 4; ++ks) {
        bf16x8 afh[2], afl[2], bh[4];
        #pragma unroll
        for (int i = 0; i < 2; ++i) {
            afh[i] = *(const bf16x8*)(lAh + (wm * 32 + i * 16 + l15) * 136 + ks * 32 + quad * 8);
            afl[i] = *(const bf16x8*)(lAl + (wm * 32 + i * 16 + l15) * 136 + ks * 32 + quad * 8);
        }
        #pragma unroll
        for (int j = 0; j < 4; ++j)
            bh[j] = *(const bf16x8*)(wzt_h + (wn * 64 + j * 16 + l15) * 128 + ks * 32 + quad * 8);
        #pragma unroll
        for (int i = 0; i < 2; ++i)
            #pragma unroll
            for (int j = 0; j < 4; ++j) {
                acc[i][j] = __builtin_amdgcn_mfma_f32_16x16x32_bf16(afh[i], bh[j], acc[i][j], 0, 0, 0);
                acc[i][j] = __builtin_amdgcn_mfma_f32_16x16x32_bf16(afl[i], bh[j], acc[i][j], 0, 0, 0);
            }
    }

    ushort* outb = (ushort*)out;
    float*  outf = (float*)out;
    #pragma unroll
    for (int i = 0; i < 2; ++i)
        #pragma unroll
        for (int j = 0; j < 4; ++j) {
            int co = wn * 64 + j * 16 + l15;
            float uj = uvec[co], vj = vvec[co];
            int pb = wm * 32 + i * 16 + quad * 4;
            uint2 gpk = *(const uint2*)(Gbuf + (size_t)co * NPOS + p0 + pb);
            float gg[4];
            gg[0] = bf2f((ushort)(gpk.x & 0xffff));
            gg[1] = bf2f((ushort)(gpk.x >> 16));
            gg[2] = bf2f((ushort)(gpk.y & 0xffff));
            gg[3] = bf2f((ushort)(gpk.y >> 16));
            #pragma unroll
            for (int r = 0; r < 4; ++r) {
                int p = pb + r;
                float pre = sRs[p] * (acc[i][j][r] - sMean[p] * uj) + vj;
                float val = gg[r] * pre;
                size_t oidx = (size_t)(p0 + p) * 128 + co;
                if (isbf) outb[oidx] = f2bf(val);
                else      outf[oidx] = val;
            }
        }
}

// ---------------------------------------------------------------------------
// stage3AB (fallback, R14 form): fp32 T; gate computed in-kernel.
// ---------------------------------------------------------------------------
__global__ __launch_bounds__(256, 4)
void stage3ab_kernel(const void* __restrict__ z,
                     const void* __restrict__ ln_iw, const void* __restrict__ ln_ib,
                     const ushort* __restrict__ wt5_h,
                     const void* __restrict__ b_g,
                     const float* __restrict__ Tf, const ushort* __restrict__ wzt_h,
                     const float* __restrict__ uvec, const float* __restrict__ vvec,
                     const int* __restrict__ dflag, void* __restrict__ out)
{
    __shared__ ushort sm[2 * 64 * 136];
    __shared__ float sMean[64], sRs[64];
    ushort* lAh = sm;
    ushort* lAl = sm + 64 * 136;
    const int tid = threadIdx.x, lane = tid & 63, w = tid >> 6;
    const int l15 = lane & 15, quad = lane >> 4;
    const int wm = w >> 1, wn = w & 1;
    const int p0 = blockIdx.x * 64;
    const int isbf = dflag[0];
    const f32x4 zero4 = {0.f, 0.f, 0.f, 0.f};

    float lw0 = loadIn(ln_iw, 2 * lane, isbf), lw1 = loadIn(ln_iw, 2 * lane + 1, isbf);
    float lb0 = loadIn(ln_ib, 2 * lane, isbf), lb1 = loadIn(ln_ib, 2 * lane + 1, isbf);
    for (int it = 0; it < 16; ++it) {
        int pl = w * 16 + it;
        float2 xv = loadIn2(z, (size_t)(p0 + pl) * 128, 2 * lane, isbf);
        float x0 = xv.x, x1 = xv.y;
        float s = x0 + x1, s2 = x0 * x0 + x1 * x1;
        #pragma unroll
        for (int m = 32; m >= 1; m >>= 1) { s += __shfl_xor(s, m); s2 += __shfl_xor(s2, m); }
        float mean = s * 0.0078125f;
        float var = s2 * 0.0078125f - mean * mean;
        float rs = rsqrtf(var + 1e-5f);
        float zn0 = (x0 - mean) * rs * lw0 + lb0;
        float zn1 = (x1 - mean) * rs * lw1 + lb1;
        ushort h0 = f2bf(zn0), h1 = f2bf(zn1);
        ushort o0 = f2bf(zn0 - bf2f(h0)), o1 = f2bf(zn1 - bf2f(h1));
        *(uint*)(lAh + pl * 136 + 2 * lane) = (uint)h0 | ((uint)h1 << 16);
        *(uint*)(lAl + pl * 136 + 2 * lane) = (uint)o0 | ((uint)o1 << 16);
    }
    __syncthreads();

    const ushort* wgh = wt5_h + 4 * 16384;
    f32x4 accG[2][4];
    #pragma unroll
    for (int i = 0; i < 2; ++i)
        #pragma unroll
        for (int j = 0; j < 4; ++j) accG[i][j] = zero4;
    #pragma unroll
    for (int ks = 0; ks < 4; ++ks) {
        bf16x8 afh[2], afl[2], bh[4];
        #pragma unroll
        for (int i = 0; i < 2; ++i) {
            afh[i] = *(const bf16x8*)(lAh + (wm * 32 + i * 16 + l15) * 136 + ks * 32 + quad * 8);
            afl[i] = *(const bf16x8*)(lAl + (wm * 32 + i * 16 + l15) * 136 + ks * 32 + quad * 8);
        }
        #pragma unroll
        for (int j = 0; j < 4; ++j)
            bh[j] = *(const bf16x8*)(wgh + (wn * 64 + j * 16 + l15) * 128 + ks * 32 + quad * 8);
        #pragma unroll
        for (int i = 0; i < 2; ++i)
            #pragma unroll
            for (int j = 0; j < 4; ++j) {
                accG[i][j] = __builtin_amdgcn_mfma_f32_16x16x32_bf16(afh[i], bh[j], accG[i][j], 0, 0, 0);
                accG[i][j] = __builtin_amdgcn_mfma_f32_16x16x32_bf16(afl[i], bh[j], accG[i][j], 0, 0, 0);
            }
    }
    #pragma unroll
    for (int i = 0; i < 2; ++i)
        #pragma unroll
        for (int j = 0; j < 4; ++j) {
            int co = wn * 64 + j * 16 + l15;
            float bgv = loadIn(b_g, co, isbf);
            #pragma unroll
            for (int r = 0; r < 4; ++r)
                accG[i][j][r] = sigm(accG[i][j][r] + bgv);
        }
    __syncthreads();

    {
        int c = tid >> 1, h = tid & 1;
        const float* src = Tf + ((size_t)(p0 >> 9) * 128 + c) * 512 + (p0 & 511) + h * 32;
        float tv[32];
        #pragma unroll
        for (int q8 = 0; q8 < 8; ++q8) {
            float4 f4 = ((const float4*)src)[q8];
            tv[q8 * 4 + 0] = f4.x; tv[q8 * 4 + 1] = f4.y;
            tv[q8 * 4 + 2] = f4.z; tv[q8 * 4 + 3] = f4.w;
        }
        #pragma unroll
        for (int jj = 0; jj < 32; ++jj) {
            ushort hi = f2bf(tv[jj]);
            lAh[(h * 32 + jj) * 136 + c] = hi;
            lAl[(h * 32 + jj) * 136 + c] = f2bf(tv[jj] - bf2f(hi));
        }
    }
    __syncthreads();

    for (int it = 0; it < 16; ++it) {
        int pl = w * 16 + it;
        uint zh = *(const uint*)(lAh + pl * 136 + 2 * lane);
        uint zl = *(const uint*)(lAl + pl * 136 + 2 * lane);
        float x0 = bf2f((ushort)(zh & 0xffff)) + bf2f((ushort)(zl & 0xffff));
        float x1 = bf2f((ushort)(zh >> 16)) + bf2f((ushort)(zl >> 16));
        float s = x0 + x1, s2 = x0 * x0 + x1 * x1;
        #pragma unroll
        for (int m = 32; m >= 1; m >>= 1) { s += __shfl_xor(s, m); s2 += __shfl_xor(s2, m); }
        if (lane == 0) {
            float mean = s * 0.0078125f;
            float var = s2 * 0.0078125f - mean * mean;
            sMean[pl] = mean;
            sRs[pl] = rsqrtf(var + 1e-5f);
        }
    }
    __syncthreads();

    f32x4 acc[2][4];
    #pragma unroll
    for (int i = 0; i < 2; ++i)
        #pragma unroll
        for (int j = 0; j < 4; ++j) acc[i][j] = zero4;
    #pragma unroll
    for (int ks = 0; ks < 4; ++ks) {
        bf16x8 afh[2], afl[2], bh[4];
        #pragma unroll
        for (int i = 0; i < 2; ++i) {
            afh[i] = *(const bf16x8*)(lAh + (wm * 32 + i * 16 + l15) * 136 + ks * 32 + quad * 8);
            afl[i] = *(const bf16x8*)(lAl + (wm * 32 + i * 16 + l15) * 136 + ks * 32 + quad * 8);
        }
        #pragma unroll
        for (int j = 0; j < 4; ++j)
            bh[j] = *(const bf16x8*)(wzt_h + (wn * 64 + j * 16 + l15) * 128 + ks * 32 + quad * 8);
        #pragma unroll
        for (int i = 0; i < 2; ++i)
            #pragma unroll
            for (int j = 0; j < 4; ++j) {
                acc[i][j] = __builtin_amdgcn_mfma_f32_16x16x32_bf16(afh[i], bh[j], acc[i][j], 0, 0, 0);
                acc[i][j] = __builtin_amdgcn_mfma_f32_16x16x32_bf16(afl[i], bh[j], acc[i][j], 0, 0, 0);
            }
    }

    ushort* outb = (ushort*)out;
    float*  outf = (float*)out;
    #pragma unroll
    for (int i = 0; i < 2; ++i)
        #pragma unroll
        for (int j = 0; j < 4; ++j) {
            int co = wn * 64 + j * 16 + l15;
            float uj = uvec[co], vj = vvec[co];
            int pb = wm * 32 + i * 16 + quad * 4;
            #pragma unroll
            for (int r = 0; r < 4; ++r) {
                int p = pb + r;
                float pre = sRs[p] * (acc[i][j][r] - sMean[p] * uj) + vj;
                float val = accG[i][j][r] * pre;
                size_t oidx = (size_t)(p0 + p) * 128 + co;
                if (isbf) outb[oidx] = f2bf(val);
                else      outf[oidx] = val;
            }
        }
}

// ---------------------------------------------------------------------------
extern "C" void kernel_launch(void* const* d_in, const int* in_sizes, int n_in,
                              void* d_out, int out_size, void* d_ws, size_t ws_size,
                              hipStream_t stream)
{
    const void* z     = d_in[0];
    const void* ln_iw = d_in[1];
    const void* ln_ib = d_in[2];
    const void* ln_ow = d_in[3];
    const void* ln_ob = d_in[4];
    const void* w_ap  = d_in[5];
    const void* b_ap  = d_in[6];
    const void* w_ag  = d_in[7];
    const void* b_ag  = d_in[8];
    const void* w_bp  = d_in[9];
    const void* b_bp  = d_in[10];
    const void* w_bg  = d_in[11];
    const void* b_bg  = d_in[12];
    const void* w_g   = d_in[13];
    const void* b_g   = d_in[14];
    const void* w_z   = d_in[15];
    const void* b_z   = d_in[16];

    const size_t MB64 = 67108864;
    const size_t REQ_B = 524288 + MB64 + 2 * MB64;             // 201,850,880
    const size_t REQ_A = REQ_B + MB64;                         // 268,959,744

    char* ws = (char*)d_ws;
    if (ws_size < REQ_B) {
        fill_zero_kernel<<<8192, 256, 0, stream>>>((ushort*)d_out);
        return;
    }
    const int use_g = (ws_size >= REQ_A);

    // prep area
    ushort* wt5_h = (ushort*)(ws);
    ushort* wzt_h = (ushort*)(ws + 163840);
    float*  uvec  = (float*)(ws + 196608);
    float*  vvec  = (float*)(ws + 197120);
    int*    dflag = (int*)(ws + 198144);
    ushort* wt5_l = (ushort*)(ws + 262144);        // unused (store_lo=0)
    ushort* wzt_l = (ushort*)(ws + 262144 + 163840);

    ushort* Ahi  = (ushort*)(ws + 524288);
    ushort* Gbuf = use_g ? (ushort*)(ws + 524288 + MB64) : (ushort*)(ws + 524288);
    void*   Tbuf = use_g ? (void*)(ws + 524288 + 2 * MB64) : (void*)(ws + 524288 + MB64);
    ushort* Bhi  = (ushort*)d_out;

    detect_kernel<<<1, 64, 0, stream>>>((const uint*)z, dflag);
    prep_kernel<<<7, 256, 0, stream>>>(w_ap, w_ag, w_bp, w_bg, w_g, w_z, ln_ow, ln_ob, b_z,
                                       dflag, wt5_h, wt5_l, wzt_h, wzt_l, uvec, vvec, 0);
    stage1_kernel<<<4096, 256, 0, stream>>>(z, ln_iw, ln_ib, wt5_h,
                                            b_ap, b_ag, b_bp, b_bg, b_g, dflag,
                                            Ahi, Bhi, Gbuf, use_g);
    stage2_kernel<<<dim3(16, 128), 256, 0, stream>>>(Ahi, Bhi, dflag, Tbuf, 1);
    if (use_g)
        stage3g_kernel<<<4096, 256, 0, stream>>>((const float*)Tbuf, Gbuf, wzt_h,
                                                 uvec, vvec, dflag, d_out);
    else
        stage3ab_kernel<<<4096, 256, 0, stream>>>(z, ln_iw, ln_ib, wt5_h, b_g,
                                                  (const float*)Tbuf, wzt_h,
                                                  uvec, vvec, dflag, d_out);
}

// Round 17
// 717.441 us; speedup vs baseline: 1.2130x; 1.0416x over previous
//
#include <hip/hip_runtime.h>
#include <hip/hip_bf16.h>

// TriangleMultiplication (outgoing), N=512, C=C_Z=128. Inputs/out fp32
// (runtime-detected; bf16 fallback kept). Internal: bf16 MFMA; zn hi/lo
// split in small GEMMs.
//
// R5 occupancy | R7 swizzle null | R8/R13 stage2 tiling | R9 T layout
// R10-R12 drop A-lo/B-lo (absmax unchanged) | R13 2-term stage3: 769.0
// R14 stage1 LN-once fusion: 759.5 | R15/R16 gate hoisted into stage1: 747.3
// R17: T switched fp32 -> bf16 (tier-C structure, self-consistent t-LN):
//      stage2 writes bf16 (134->67MB), stage3g reads bf16 into ONE LDS
//      plane (35->17KB), t-LN stats from bf16 t, output GEMM 1-term
//      (-50% stage3g MFMA). Dropped t-lo term ~= R13's weight-lo drop.

#define NSEQ 512
#define NPOS 262144

typedef short bf16x8 __attribute__((ext_vector_type(8)));
typedef float f32x4 __attribute__((ext_vector_type(4)));

__device__ __forceinline__ float bf2f(ushort h) {
    union { uint u; float f; } x; x.u = ((uint)h) << 16; return x.f;
}
__device__ __forceinline__ ushort f2bf(float f) {
    union { float f; uint u; } x; x.f = f;
    uint r = x.u + 0x7fffu + ((x.u >> 16) & 1u);
    return (ushort)(r >> 16);
}
__device__ __forceinline__ float sigm(float x) { return 1.f / (1.f + __expf(-x)); }

__device__ __forceinline__ float loadIn(const void* p, size_t idx, int isbf) {
    return isbf ? bf2f(((const ushort*)p)[idx]) : ((const float*)p)[idx];
}
__device__ __forceinline__ float2 loadIn2(const void* p, size_t base, int col2, int isbf) {
    if (isbf) {
        uint zz = *(const uint*)((const ushort*)p + base + col2);
        float2 r; r.x = bf2f((ushort)(zz & 0xffff)); r.y = bf2f((ushort)(zz >> 16)); return r;
    }
    return *(const float2*)((const float*)p + base + col2);
}

// ---------------------------------------------------------------------------
__global__ void detect_kernel(const uint* __restrict__ z32, int* __restrict__ flag)
{
    int t = threadIdx.x;
    int votes = 0;
    #pragma unroll
    for (int i = 0; i < 4; ++i) {
        uint wv = z32[t * 4 + i];
        uint ex = (wv >> 7) & 0xff;
        votes += (ex >= 118 && ex <= 132) ? 1 : 0;
    }
    #pragma unroll
    for (int m = 32; m >= 1; m >>= 1) votes += __shfl_xor(votes, m);
    if (t == 0) flag[0] = (votes >= 128) ? 1 : 0;
}

__global__ void fill_zero_kernel(ushort* __restrict__ out)
{
    size_t i = ((size_t)blockIdx.x * 256 + threadIdx.x) * 16;
    uint4 z4 = {0u, 0u, 0u, 0u};
    *(uint4*)(out + i) = z4;
    *(uint4*)(out + i + 8) = z4;
}

// ---------------------------------------------------------------------------
// prep: wt5_h[g][co][ci] (transposed bf16); wzt_h[co][c] of W' = ln_ow*w_z;
// u,v fp32 affine-fold vectors.
// ---------------------------------------------------------------------------
__global__ void prep_kernel(const void* __restrict__ w_ap, const void* __restrict__ w_ag,
                            const void* __restrict__ w_bp, const void* __restrict__ w_bg,
                            const void* __restrict__ w_g,  const void* __restrict__ w_z,
                            const void* __restrict__ ln_ow, const void* __restrict__ ln_ob,
                            const void* __restrict__ b_z,  const int* __restrict__ dflag,
                            ushort* __restrict__ wt5_h, ushort* __restrict__ wt5_l,
                            ushort* __restrict__ wzt_h, ushort* __restrict__ wzt_l,
                            float* __restrict__ u, float* __restrict__ v, int store_lo)
{
    const int b = blockIdx.x, t = threadIdx.x;
    const int isbf = dflag[0];
    if (b < 5) {
        const void* src = (b == 0) ? w_ap : (b == 1) ? w_ag : (b == 2) ? w_bp : (b == 3) ? w_bg : w_g;
        for (int k = 0; k < 64; ++k) {
            int o = t + k * 256;
            int co = o >> 7, ci = o & 127;
            float wv = loadIn(src, ci * 128 + co, isbf);
            ushort hi = f2bf(wv);
            wt5_h[b * 16384 + o] = hi;
            if (store_lo) wt5_l[b * 16384 + o] = f2bf(wv - bf2f(hi));
        }
    } else if (b == 5) {
        for (int k = 0; k < 64; ++k) {
            int o = t + k * 256;
            int co = o >> 7, c = o & 127;
            float wv = loadIn(ln_ow, c, isbf) * loadIn(w_z, c * 128 + co, isbf);
            ushort hi = f2bf(wv);
            wzt_h[o] = hi;
            if (store_lo) wzt_l[o] = f2bf(wv - bf2f(hi));
        }
    } else {
        if (t < 128) {
            float su = 0.f, sv = 0.f;
            for (int c = 0; c < 128; ++c) {
                float wzv = loadIn(w_z, c * 128 + t, isbf);
                su += loadIn(ln_ow, c, isbf) * wzv;
                sv += loadIn(ln_ob, c, isbf) * wzv;
            }
            u[t] = su;
            v[t] = sv + loadIn(b_z, t, isbf);
        }
    }
}

// ---------------------------------------------------------------------------
// stage1: grid (4096). LN ONCE, then sequential passes: g0 -> a (A_hi),
// g1 -> b (B_hi in d_out), and (do_gate) gate -> Gbuf (sigmoid(zn.w_g+b_g),
// bf16 channel-major). zn hi+lo persists in LDS; tb separate transpose buf.
// ---------------------------------------------------------------------------
__global__ __launch_bounds__(256, 3)
void stage1_kernel(const void* __restrict__ z,
                   const void* __restrict__ ln_iw, const void* __restrict__ ln_ib,
                   const ushort* __restrict__ wt5_h,
                   const void* __restrict__ b_ap, const void* __restrict__ b_ag,
                   const void* __restrict__ b_bp, const void* __restrict__ b_bg,
                   const void* __restrict__ b_g,
                   const int* __restrict__ dflag,
                   ushort* __restrict__ Ahi, ushort* __restrict__ Bhi,
                   ushort* __restrict__ Gbuf, int do_gate)
{
    __shared__ ushort sm[2 * 64 * 136 + 128 * 72];
    ushort* lAh = sm;                    // [64][136] zn hi
    ushort* lAl = sm + 64 * 136;         // [64][136] zn lo
    ushort* tb  = sm + 2 * 64 * 136;     // [128][72] transpose buf (separate)
    const int tid = threadIdx.x, lane = tid & 63, w = tid >> 6;
    const int l15 = lane & 15, quad = lane >> 4;
    const int p0 = blockIdx.x * 64;
    const int isbf = dflag[0];

    float lw0 = loadIn(ln_iw, 2 * lane, isbf), lw1 = loadIn(ln_iw, 2 * lane + 1, isbf);
    float lb0 = loadIn(ln_ib, 2 * lane, isbf), lb1 = loadIn(ln_ib, 2 * lane + 1, isbf);
    for (int it = 0; it < 16; ++it) {
        int pl = w * 16 + it;
        float2 xv = loadIn2(z, (size_t)(p0 + pl) * 128, 2 * lane, isbf);
        float x0 = xv.x, x1 = xv.y;
        float s = x0 + x1, s2 = x0 * x0 + x1 * x1;
        #pragma unroll
        for (int m = 32; m >= 1; m >>= 1) { s += __shfl_xor(s, m); s2 += __shfl_xor(s2, m); }
        float mean = s * 0.0078125f;
        float var = s2 * 0.0078125f - mean * mean;
        float rs = rsqrtf(var + 1e-5f);
        float zn0 = (x0 - mean) * rs * lw0 + lb0;
        float zn1 = (x1 - mean) * rs * lw1 + lb1;
        ushort h0 = f2bf(zn0), h1 = f2bf(zn1);
        ushort o0 = f2bf(zn0 - bf2f(h0)), o1 = f2bf(zn1 - bf2f(h1));
        *(uint*)(lAh + pl * 136 + 2 * lane) = (uint)h0 | ((uint)h1 << 16);
        *(uint*)(lAl + pl * 136 + 2 * lane) = (uint)o0 | ((uint)o1 << 16);
    }
    __syncthreads();

    const int wm = w >> 1, wn = w & 1;
    const f32x4 zero4 = {0.f, 0.f, 0.f, 0.f};

    #pragma unroll 1
    for (int g = 0; g < 2; ++g) {
        const ushort* wG = wt5_h + ((g == 0) ? 1 : 3) * 16384;
        const ushort* wP = wt5_h + ((g == 0) ? 0 : 2) * 16384;

        f32x4 accG[2][4], accP[2][4];
        #pragma unroll
        for (int i = 0; i < 2; ++i)
            #pragma unroll
            for (int j = 0; j < 4; ++j) { accG[i][j] = zero4; accP[i][j] = zero4; }

        #pragma unroll
        for (int ks = 0; ks < 4; ++ks) {
            bf16x8 afh[2], afl[2];
            #pragma unroll
            for (int i = 0; i < 2; ++i) {
                afh[i] = *(const bf16x8*)(lAh + (wm * 32 + i * 16 + l15) * 136 + ks * 32 + quad * 8);
                afl[i] = *(const bf16x8*)(lAl + (wm * 32 + i * 16 + l15) * 136 + ks * 32 + quad * 8);
            }
            {
                bf16x8 bG[4];
                #pragma unroll
                for (int j = 0; j < 4; ++j)
                    bG[j] = *(const bf16x8*)(wG + (wn * 64 + j * 16 + l15) * 128 + ks * 32 + quad * 8);
                #pragma unroll
                for (int i = 0; i < 2; ++i)
                    #pragma unroll
                    for (int j = 0; j < 4; ++j) {
                        accG[i][j] = __builtin_amdgcn_mfma_f32_16x16x32_bf16(afh[i], bG[j], accG[i][j], 0, 0, 0);
                        accG[i][j] = __builtin_amdgcn_mfma_f32_16x16x32_bf16(afl[i], bG[j], accG[i][j], 0, 0, 0);
                    }
            }
            {
                bf16x8 bP[4];
                #pragma unroll
                for (int j = 0; j < 4; ++j)
                    bP[j] = *(const bf16x8*)(wP + (wn * 64 + j * 16 + l15) * 128 + ks * 32 + quad * 8);
                #pragma unroll
                for (int i = 0; i < 2; ++i)
                    #pragma unroll
                    for (int j = 0; j < 4; ++j) {
                        accP[i][j] = __builtin_amdgcn_mfma_f32_16x16x32_bf16(afh[i], bP[j], accP[i][j], 0, 0, 0);
                        accP[i][j] = __builtin_amdgcn_mfma_f32_16x16x32_bf16(afl[i], bP[j], accP[i][j], 0, 0, 0);
                    }
            }
        }

        const void* bgp = (g == 0) ? b_ag : b_bg;
        const void* bpp = (g == 0) ? b_ap : b_bp;
        float av[2][4][4];
        #pragma unroll
        for (int i = 0; i < 2; ++i)
            #pragma unroll
            for (int j = 0; j < 4; ++j) {
                int co = wn * 64 + j * 16 + l15;
                float gv = loadIn(bgp, co, isbf);
                float pv = loadIn(bpp, co, isbf);
                #pragma unroll
                for (int r = 0; r < 4; ++r)
                    av[i][j][r] = sigm(accG[i][j][r] + gv) * (accP[i][j][r] + pv);
            }

        ushort* dst_hi = (g == 0) ? Ahi : Bhi;

        __syncthreads();   // prior tb reads done
        #pragma unroll
        for (int i = 0; i < 2; ++i)
            #pragma unroll
            for (int j = 0; j < 4; ++j) {
                int co = wn * 64 + j * 16 + l15;
                int pb = wm * 32 + i * 16 + quad * 4;
                uint2 pk;
                pk.x = (uint)f2bf(av[i][j][0]) | ((uint)f2bf(av[i][j][1]) << 16);
                pk.y = (uint)f2bf(av[i][j][2]) | ((uint)f2bf(av[i][j][3]) << 16);
                *(uint2*)(tb + co * 72 + pb) = pk;
            }
        __syncthreads();
        #pragma unroll
        for (int q = 0; q < 4; ++q) {
            int vv = q * 256 + tid;
            int co = vv >> 3, off = vv & 7;
            *(uint4*)(dst_hi + (size_t)co * NPOS + p0 + off * 8) = *(const uint4*)(tb + co * 72 + off * 8);
        }
    }

    if (do_gate) {
        // gate pass: acc = zn . w_g (2-term), sigmoid, store channel-major
        const ushort* wGt = wt5_h + 4 * 16384;
        f32x4 acc[2][4];
        #pragma unroll
        for (int i = 0; i < 2; ++i)
            #pragma unroll
            for (int j = 0; j < 4; ++j) acc[i][j] = zero4;
        #pragma unroll
        for (int ks = 0; ks < 4; ++ks) {
            bf16x8 afh[2], afl[2], bh[4];
            #pragma unroll
            for (int i = 0; i < 2; ++i) {
                afh[i] = *(const bf16x8*)(lAh + (wm * 32 + i * 16 + l15) * 136 + ks * 32 + quad * 8);
                afl[i] = *(const bf16x8*)(lAl + (wm * 32 + i * 16 + l15) * 136 + ks * 32 + quad * 8);
            }
            #pragma unroll
            for (int j = 0; j < 4; ++j)
                bh[j] = *(const bf16x8*)(wGt + (wn * 64 + j * 16 + l15) * 128 + ks * 32 + quad * 8);
            #pragma unroll
            for (int i = 0; i < 2; ++i)
                #pragma unroll
                for (int j = 0; j < 4; ++j) {
                    acc[i][j] = __builtin_amdgcn_mfma_f32_16x16x32_bf16(afh[i], bh[j], acc[i][j], 0, 0, 0);
                    acc[i][j] = __builtin_amdgcn_mfma_f32_16x16x32_bf16(afl[i], bh[j], acc[i][j], 0, 0, 0);
                }
        }
        __syncthreads();   // prior store's tb reads done
        #pragma unroll
        for (int i = 0; i < 2; ++i)
            #pragma unroll
            for (int j = 0; j < 4; ++j) {
                int co = wn * 64 + j * 16 + l15;
                float bgv = loadIn(b_g, co, isbf);
                int pb = wm * 32 + i * 16 + quad * 4;
                uint2 pk;
                pk.x = (uint)f2bf(sigm(acc[i][j][0] + bgv)) | ((uint)f2bf(sigm(acc[i][j][1] + bgv)) << 16);
                pk.y = (uint)f2bf(sigm(acc[i][j][2] + bgv)) | ((uint)f2bf(sigm(acc[i][j][3] + bgv)) << 16);
                *(uint2*)(tb + co * 72 + pb) = pk;
            }
        __syncthreads();
        #pragma unroll
        for (int q = 0; q < 4; ++q) {
            int vv = q * 256 + tid;
            int co = vv >> 3, off = vv & 7;
            *(uint4*)(Gbuf + (size_t)co * NPOS + p0 + off * 8) = *(const uint4*)(tb + co * 72 + off * 8);
        }
    }
}

// ---------------------------------------------------------------------------
// stage2: grid (16, 128). T_c = A_c * B_c^T, single hi*hi MFMA term.
// K-tile 64, 2 LDS planes (36864 B, (256,3)); 8 barrier pairs.
// R17: T written bf16 in [i][c][j] layout: idx = (i*128+c)*512+j.
// ---------------------------------------------------------------------------
__global__ __launch_bounds__(256, 3)
void stage2_kernel(const ushort* __restrict__ Ahi, const ushort* __restrict__ Bhi,
                   const int* __restrict__ dflag,
                   ushort* __restrict__ Tbuf)
{
    __shared__ ushort sm[2 * 128 * 72];   // 36864 B
    ushort* lAh = sm;
    ushort* lBh = sm + 128 * 72;
    const int tid = threadIdx.x, lane = tid & 63, w = tid >> 6;
    const int l15 = lane & 15, quad = lane >> 4;
    const int wm = w >> 1, wn = w & 1;
    const int bid = blockIdx.y * 16 + blockIdx.x;          // 0..2047
    const int swz = (bid & 7) * 256 + (bid >> 3);          // bijective
    const int c = swz >> 4;
    const int ti = (swz & 15) >> 2, tj = swz & 3;
    const ushort* Aph = Ahi + (size_t)c * NPOS + (size_t)ti * 128 * NSEQ;
    const ushort* Bph = Bhi + (size_t)c * NPOS + (size_t)tj * 128 * NSEQ;

    const f32x4 zero4 = {0.f, 0.f, 0.f, 0.f};
    f32x4 acc[4][4];
    #pragma unroll
    for (int i = 0; i < 4; ++i)
        #pragma unroll
        for (int j = 0; j < 4; ++j) acc[i][j] = zero4;

    for (int kt = 0; kt < 8; ++kt) {
        #pragma unroll
        for (int q = 0; q < 4; ++q) {
            int vv = q * 256 + tid;
            int row = vv >> 3, off = vv & 7;
            *(uint4*)(lAh + row * 72 + off * 8) = *(const uint4*)(Aph + (size_t)row * NSEQ + kt * 64 + off * 8);
            *(uint4*)(lBh + row * 72 + off * 8) = *(const uint4*)(Bph + (size_t)row * NSEQ + kt * 64 + off * 8);
        }
        __syncthreads();
        #pragma unroll
        for (int ks = 0; ks < 2; ++ks) {
            bf16x8 afh[4], bfh[4];
            #pragma unroll
            for (int i = 0; i < 4; ++i)
                afh[i] = *(const bf16x8*)(lAh + (wm * 64 + i * 16 + l15) * 72 + ks * 32 + quad * 8);
            #pragma unroll
            for (int j = 0; j < 4; ++j)
                bfh[j] = *(const bf16x8*)(lBh + (wn * 64 + j * 16 + l15) * 72 + ks * 32 + quad * 8);
            #pragma unroll
            for (int i = 0; i < 4; ++i)
                #pragma unroll
                for (int j = 0; j < 4; ++j)
                    acc[i][j] = __builtin_amdgcn_mfma_f32_16x16x32_bf16(afh[i], bfh[j], acc[i][j], 0, 0, 0);
        }
        __syncthreads();
    }

    // [i][c][j] layout: idx = ((i)*128 + c)*512 + j, bf16
    ushort* Tp = Tbuf + ((size_t)(ti * 128) * 128 + c) * 512 + tj * 128;
    #pragma unroll
    for (int i = 0; i < 4; ++i)
        #pragma unroll
        for (int j = 0; j < 4; ++j) {
            int jl = wn * 64 + j * 16 + l15;
            int ib = wm * 64 + i * 16 + quad * 4;
            #pragma unroll
            for (int r = 0; r < 4; ++r)
                Tp[(size_t)(ib + r) * 65536 + jl] = f2bf(acc[i][j][r]);
        }
}

// ---------------------------------------------------------------------------
// stage3g: bf16 T ([i][c][j]); g from Gbuf (bf16, channel-major).
// {T load -> single LDS plane -> t-LN stats (bf16 t) -> output GEMM 1-term
//  -> epilogue*g}. Self-consistent tier-C structure: stats and GEMM use the
// same bf16 t.
// ---------------------------------------------------------------------------
__global__ __launch_bounds__(256, 4)
void stage3g_kernel(const ushort* __restrict__ Tb, const ushort* __restrict__ Gbuf,
                    const ushort* __restrict__ wzt_h,
                    const float* __restrict__ uvec, const float* __restrict__ vvec,
                    const int* __restrict__ dflag, void* __restrict__ out)
{
    __shared__ ushort sm[64 * 136];
    __shared__ float sMean[64], sRs[64];
    ushort* lAh = sm;
    const int tid = threadIdx.x, lane = tid & 63, w = tid >> 6;
    const int l15 = lane & 15, quad = lane >> 4;
    const int wm = w >> 1, wn = w & 1;
    const int p0 = blockIdx.x * 64;
    const int isbf = dflag[0];
    const f32x4 zero4 = {0.f, 0.f, 0.f, 0.f};

    // bf16 T ([i][c][j]) -> LDS
    {
        int c = tid >> 1, h = tid & 1;
        const ushort* src = Tb + ((size_t)(p0 >> 9) * 128 + c) * 512 + (p0 & 511) + h * 32;
        union { uint4 q[4]; ushort u[32]; } tmp;
        tmp.q[0] = ((const uint4*)src)[0];
        tmp.q[1] = ((const uint4*)src)[1];
        tmp.q[2] = ((const uint4*)src)[2];
        tmp.q[3] = ((const uint4*)src)[3];
        #pragma unroll
        for (int jj = 0; jj < 32; ++jj)
            lAh[(h * 32 + jj) * 136 + c] = tmp.u[jj];
    }
    __syncthreads();

    // t-LN stats from bf16 t
    for (int it = 0; it < 16; ++it) {
        int pl = w * 16 + it;
        uint zz = *(const uint*)(lAh + pl * 136 + 2 * lane);
        float x0 = bf2f((ushort)(zz & 0xffff)), x1 = bf2f((ushort)(zz >> 16));
        float s = x0 + x1, s2 = x0 * x0 + x1 * x1;
        #pragma unroll
        for (int m = 32; m >= 1; m >>= 1) { s += __shfl_xor(s, m); s2 += __shfl_xor(s2, m); }
        if (lane == 0) {
            float mean = s * 0.0078125f;
            float var = s2 * 0.0078125f - mean * mean;
            sMean[pl] = mean;
            sRs[pl] = rsqrtf(var + 1e-5f);
        }
    }
    __syncthreads();

    // output GEMM (1-term), W'hi from global
    f32x4 acc[2][4];
    #pragma unroll
    for (int i = 0; i < 2; ++i)
        #pragma unroll
        for (int j = 0; j < 4; ++j) acc[i][j] = zero4;
    #pragma unroll
    for (int ks = 0; ks < 4; ++ks) {
        bf16x8 af[2], bh[4];
        #pragma unroll
        for (int i = 0; i < 2; ++i)
            af[i] = *(const bf16x8*)(lAh + (wm * 32 + i * 16 + l15) * 136 + ks * 32 + quad * 8);
        #pragma unroll
        for (int j = 0; j < 4; ++j)
            bh[j] = *(const bf16x8*)(wzt_h + (wn * 64 + j * 16 + l15) * 128 + ks * 32 + quad * 8);
        #pragma unroll
        for (int i = 0; i < 2; ++i)
            #pragma unroll
            for (int j = 0; j < 4; ++j)
                acc[i][j] = __builtin_amdgcn_mfma_f32_16x16x32_bf16(af[i], bh[j], acc[i][j], 0, 0, 0);
    }

    ushort* outb = (ushort*)out;
    float*  outf = (float*)out;
    #pragma unroll
    for (int i = 0; i < 2; ++i)
        #pragma unroll
        for (int j = 0; j < 4; ++j) {
            int co = wn * 64 + j * 16 + l15;
            float uj = uvec[co], vj = vvec[co];
            int pb = wm * 32 + i * 16 + quad * 4;
            uint2 gpk = *(const uint2*)(Gbuf + (size_t)co * NPOS + p0 + pb);
            float gg[4];
            gg[0] = bf2f((ushort)(gpk.x & 0xffff));
            gg[1] = bf2f((ushort)(gpk.x >> 16));
            gg[2] = bf2f((ushort)(gpk.y & 0xffff));
            gg[3] = bf2f((ushort)(gpk.y >> 16));
            #pragma unroll
            for (int r = 0; r < 4; ++r) {
                int p = pb + r;
                float pre = sRs[p] * (acc[i][j][r] - sMean[p] * uj) + vj;
                float val = gg[r] * pre;
                size_t oidx = (size_t)(p0 + p) * 128 + co;
                if (isbf) outb[oidx] = f2bf(val);
                else      outf[oidx] = val;
            }
        }
}

// ---------------------------------------------------------------------------
// stage3AB (fallback, ws < REQ_A): bf16 T; gate computed in-kernel.
// ---------------------------------------------------------------------------
__global__ __launch_bounds__(256, 4)
void stage3ab_kernel(const void* __restrict__ z,
                     const void* __restrict__ ln_iw, const void* __restrict__ ln_ib,
                     const ushort* __restrict__ wt5_h,
                     const void* __restrict__ b_g,
                     const ushort* __restrict__ Tb, const ushort* __restrict__ wzt_h,
                     const float* __restrict__ uvec, const float* __restrict__ vvec,
                     const int* __restrict__ dflag, void* __restrict__ out)
{
    __shared__ ushort sm[2 * 64 * 136];
    __shared__ float sMean[64], sRs[64];
    ushort* lAh = sm;
    ushort* lAl = sm + 64 * 136;
    const int tid = threadIdx.x, lane = tid & 63, w = tid >> 6;
    const int l15 = lane & 15, quad = lane >> 4;
    const int wm = w >> 1, wn = w & 1;
    const int p0 = blockIdx.x * 64;
    const int isbf = dflag[0];
    const f32x4 zero4 = {0.f, 0.f, 0.f, 0.f};

    float lw0 = loadIn(ln_iw, 2 * lane, isbf), lw1 = loadIn(ln_iw, 2 * lane + 1, isbf);
    float lb0 = loadIn(ln_ib, 2 * lane, isbf), lb1 = loadIn(ln_ib, 2 * lane + 1, isbf);
    for (int it = 0; it < 16; ++it) {
        int pl = w * 16 + it;
        float2 xv = loadIn2(z, (size_t)(p0 + pl) * 128, 2 * lane, isbf);
        float x0 = xv.x, x1 = xv.y;
        float s = x0 + x1, s2 = x0 * x0 + x1 * x1;
        #pragma unroll
        for (int m = 32; m >= 1; m >>= 1) { s += __shfl_xor(s, m); s2 += __shfl_xor(s2, m); }
        float mean = s * 0.0078125f;
        float var = s2 * 0.0078125f - mean * mean;
        float rs = rsqrtf(var + 1e-5f);
        float zn0 = (x0 - mean) * rs * lw0 + lb0;
        float zn1 = (x1 - mean) * rs * lw1 + lb1;
        ushort h0 = f2bf(zn0), h1 = f2bf(zn1);
        ushort o0 = f2bf(zn0 - bf2f(h0)), o1 = f2bf(zn1 - bf2f(h1));
        *(uint*)(lAh + pl * 136 + 2 * lane) = (uint)h0 | ((uint)h1 << 16);
        *(uint*)(lAl + pl * 136 + 2 * lane) = (uint)o0 | ((uint)o1 << 16);
    }
    __syncthreads();

    const ushort* wgh = wt5_h + 4 * 16384;
    f32x4 accG[2][4];
    #pragma unroll
    for (int i = 0; i < 2; ++i)
        #pragma unroll
        for (int j = 0; j < 4; ++j) accG[i][j] = zero4;
    #pragma unroll
    for (int ks = 0; ks < 4; ++ks) {
        bf16x8 afh[2], afl[2], bh[4];
        #pragma unroll
        for (int i = 0; i < 2; ++i) {
            afh[i] = *(const bf16x8*)(lAh + (wm * 32 + i * 16 + l15) * 136 + ks * 32 + quad * 8);
            afl[i] = *(const bf16x8*)(lAl + (wm * 32 + i * 16 + l15) * 136 + ks * 32 + quad * 8);
        }
        #pragma unroll
        for (int j = 0; j < 4; ++j)
            bh[j] = *(const bf16x8*)(wgh + (wn * 64 + j * 16 + l15) * 128 + ks * 32 + quad * 8);
        #pragma unroll
        for (int i = 0; i < 2; ++i)
            #pragma unroll
            for (int j = 0; j < 4; ++j) {
                accG[i][j] = __builtin_amdgcn_mfma_f32_16x16x32_bf16(afh[i], bh[j], accG[i][j], 0, 0, 0);
                accG[i][j] = __builtin_amdgcn_mfma_f32_16x16x32_bf16(afl[i], bh[j], accG[i][j], 0, 0, 0);
            }
    }
    #pragma unroll
    for (int i = 0; i < 2; ++i)
        #pragma unroll
        for (int j = 0; j < 4; ++j) {
            int co = wn * 64 + j * 16 + l15;
            float bgv = loadIn(b_g, co, isbf);
            #pragma unroll
            for (int r = 0; r < 4; ++r)
                accG[i][j][r] = sigm(accG[i][j][r] + bgv);
        }
    __syncthreads();

    {
        int c = tid >> 1, h = tid & 1;
        const ushort* src = Tb + ((size_t)(p0 >> 9) * 128 + c) * 512 + (p0 & 511) + h * 32;
        union { uint4 q[4]; ushort u[32]; } tmp;
        tmp.q[0] = ((const uint4*)src)[0];
        tmp.q[1] = ((const uint4*)src)[1];
        tmp.q[2] = ((const uint4*)src)[2];
        tmp.q[3] = ((const uint4*)src)[3];
        #pragma unroll
        for (int jj = 0; jj < 32; ++jj)
            lAh[(h * 32 + jj) * 136 + c] = tmp.u[jj];
    }
    __syncthreads();

    for (int it = 0; it < 16; ++it) {
        int pl = w * 16 + it;
        uint zz = *(const uint*)(lAh + pl * 136 + 2 * lane);
        float x0 = bf2f((ushort)(zz & 0xffff)), x1 = bf2f((ushort)(zz >> 16));
        float s = x0 + x1, s2 = x0 * x0 + x1 * x1;
        #pragma unroll
        for (int m = 32; m >= 1; m >>= 1) { s += __shfl_xor(s, m); s2 += __shfl_xor(s2, m); }
        if (lane == 0) {
            float mean = s * 0.0078125f;
            float var = s2 * 0.0078125f - mean * mean;
            sMean[pl] = mean;
            sRs[pl] = rsqrtf(var + 1e-5f);
        }
    }
    __syncthreads();

    f32x4 acc[2][4];
    #pragma unroll
    for (int i = 0; i < 2; ++i)
        #pragma unroll
        for (int j = 0; j < 4; ++j) acc[i][j] = zero4;
    #pragma unroll
    for (int ks = 0; ks < 4; ++ks) {
        bf16x8 af[2], bh[4];
        #pragma unroll
        for (int i = 0; i < 2; ++i)
            af[i] = *(const bf16x8*)(lAh + (wm * 32 + i * 16 + l15) * 136 + ks * 32 + quad * 8);
        #pragma unroll
        for (int j = 0; j < 4; ++j)
            bh[j] = *(const bf16x8*)(wzt_h + (wn * 64 + j * 16 + l15) * 128 + ks * 32 + quad * 8);
        #pragma unroll
        for (int i = 0; i < 2; ++i)
            #pragma unroll
            for (int j = 0; j < 4; ++j)
                acc[i][j] = __builtin_amdgcn_mfma_f32_16x16x32_bf16(af[i], bh[j], acc[i][j], 0, 0, 0);
    }

    ushort* outb = (ushort*)out;
    float*  outf = (float*)out;
    #pragma unroll
    for (int i = 0; i < 2; ++i)
        #pragma unroll
        for (int j = 0; j < 4; ++j) {
            int co = wn * 64 + j * 16 + l15;
            float uj = uvec[co], vj = vvec[co];
            int pb = wm * 32 + i * 16 + quad * 4;
            #pragma unroll
            for (int r = 0; r < 4; ++r) {
                int p = pb + r;
                float pre = sRs[p] * (acc[i][j][r] - sMean[p] * uj) + vj;
                float val = accG[i][j][r] * pre;
                size_t oidx = (size_t)(p0 + p) * 128 + co;
                if (isbf) outb[oidx] = f2bf(val);
                else      outf[oidx] = val;
            }
        }
}

// ---------------------------------------------------------------------------
extern "C" void kernel_launch(void* const* d_in, const int* in_sizes, int n_in,
                              void* d_out, int out_size, void* d_ws, size_t ws_size,
                              hipStream_t stream)
{
    const void* z     = d_in[0];
    const void* ln_iw = d_in[1];
    const void* ln_ib = d_in[2];
    const void* ln_ow = d_in[3];
    const void* ln_ob = d_in[4];
    const void* w_ap  = d_in[5];
    const void* b_ap  = d_in[6];
    const void* w_ag  = d_in[7];
    const void* b_ag  = d_in[8];
    const void* w_bp  = d_in[9];
    const void* b_bp  = d_in[10];
    const void* w_bg  = d_in[11];
    const void* b_bg  = d_in[12];
    const void* w_g   = d_in[13];
    const void* b_g   = d_in[14];
    const void* w_z   = d_in[15];
    const void* b_z   = d_in[16];

    const size_t MB64 = 67108864;
    const size_t REQ_B = 524288 + MB64 + 2 * MB64;             // 201,850,880
    const size_t REQ_A = REQ_B + MB64;                         // 268,959,744

    char* ws = (char*)d_ws;
    if (ws_size < REQ_B) {
        fill_zero_kernel<<<8192, 256, 0, stream>>>((ushort*)d_out);
        return;
    }
    const int use_g = (ws_size >= REQ_A);

    // prep area
    ushort* wt5_h = (ushort*)(ws);
    ushort* wzt_h = (ushort*)(ws + 163840);
    float*  uvec  = (float*)(ws + 196608);
    float*  vvec  = (float*)(ws + 197120);
    int*    dflag = (int*)(ws + 198144);
    ushort* wt5_l = (ushort*)(ws + 262144);        // unused (store_lo=0)
    ushort* wzt_l = (ushort*)(ws + 262144 + 163840);

    ushort* Ahi  = (ushort*)(ws + 524288);
    ushort* Gbuf = use_g ? (ushort*)(ws + 524288 + MB64) : (ushort*)(ws + 524288);
    ushort* Tbuf = use_g ? (ushort*)(ws + 524288 + 2 * MB64) : (ushort*)(ws + 524288 + MB64);
    ushort* Bhi  = (ushort*)d_out;

    detect_kernel<<<1, 64, 0, stream>>>((const uint*)z, dflag);
    prep_kernel<<<7, 256, 0, stream>>>(w_ap, w_ag, w_bp, w_bg, w_g, w_z, ln_ow, ln_ob, b_z,
                                       dflag, wt5_h, wt5_l, wzt_h, wzt_l, uvec, vvec, 0);
    stage1_kernel<<<4096, 256, 0, stream>>>(z, ln_iw, ln_ib, wt5_h,
                                            b_ap, b_ag, b_bp, b_bg, b_g, dflag,
                                            Ahi, Bhi, Gbuf, use_g);
    stage2_kernel<<<dim3(16, 128), 256, 0, stream>>>(Ahi, Bhi, dflag, Tbuf);
    if (use_g)
        stage3g_kernel<<<4096, 256, 0, stream>>>(Tbuf, Gbuf, wzt_h,
                                                 uvec, vvec, dflag, d_out);
    else
        stage3ab_kernel<<<4096, 256, 0, stream>>>(z, ln_iw, ln_ib, wt5_h, b_g,
                                                  Tbuf, wzt_h,
                                                  uvec, vvec, dflag, d_out);
}